// Round 1
// baseline (1746.256 us; speedup 1.0000x reference)
//
#include <hip/hip_runtime.h>
#include <cmath>

// Problem constants (N=2, S=512, C=512, H=W=50, OUT=7, RATIO=2)
#define NIMG 2
#define SPROP 512
#define NROI 1024          // NIMG*SPROP
#define CCH 512
#define FH 50
#define FW 50
#define K1 25088           // CCH*7*7
#define HID 1024
#define NCLS 21
#define NDET 100
#define IMGSZ 800.0f
#define LOGMAX 4.135166556742356f   // log(1000/16)
#define MCAND 10240        // SPROP*(NCLS-1)

// ---------------------------------------------------------------- ROI align
__global__ __launch_bounds__(256) void roi_kernel(
    const float* __restrict__ feat, const float* __restrict__ props,
    float* __restrict__ X) {
  const int r = blockIdx.x;
  const int n = r >> 9;
  const int tid = threadIdx.x;
  __shared__ int sy0[14], sy1[14], sx0[14], sx1[14];
  __shared__ float sly[14], slx[14], svy[14], svx[14];

  const float p0 = props[r * 4 + 0] * 0.0625f;
  const float p1 = props[r * 4 + 1] * 0.0625f;
  const float p2 = props[r * 4 + 2] * 0.0625f;
  const float p3 = props[r * 4 + 3] * 0.0625f;
  const float rw = fmaxf(p2 - p0, 1.0f);
  const float rh = fmaxf(p3 - p1, 1.0f);
  const float bw = rw / 7.0f;
  const float bh = rh / 7.0f;

  if (tid < 14) {
    const int j = tid;
    const float g = (float)(j >> 1) + ((float)(j & 1) + 0.5f) * 0.5f;
    float y = p1 + g * bh;
    svy[j] = (y > -1.0f && y < (float)FH) ? 1.0f : 0.0f;
    float yc = fminf(fmaxf(y, 0.0f), (float)(FH - 1));
    int y0 = (int)floorf(yc);
    sy0[j] = y0; sy1[j] = min(y0 + 1, FH - 1); sly[j] = yc - (float)y0;
    float x = p0 + g * bw;
    svx[j] = (x > -1.0f && x < (float)FW) ? 1.0f : 0.0f;
    float xc = fminf(fmaxf(x, 0.0f), (float)(FW - 1));
    int x0 = (int)floorf(xc);
    sx0[j] = x0; sx1[j] = min(x0 + 1, FW - 1); slx[j] = xc - (float)x0;
  }
  __syncthreads();

  const float* fb = feat + (size_t)n * CCH * (FH * FW);
  float* xrow = X + (size_t)r * K1;
  for (int k = tid; k < K1; k += 256) {
    const int c = k / 49;
    const int s = k - c * 49;
    const int oy = s / 7, ox = s - (s / 7) * 7;
    const float* fc = fb + (size_t)c * (FH * FW);
    float acc = 0.0f;
#pragma unroll
    for (int sy = 0; sy < 2; ++sy) {
      const int yj = oy * 2 + sy;
      const int y0 = sy0[yj], y1 = sy1[yj];
      const float ly = sly[yj], vy = svy[yj];
#pragma unroll
      for (int sx = 0; sx < 2; ++sx) {
        const int xj = ox * 2 + sx;
        const int x0 = sx0[xj], x1 = sx1[xj];
        const float lx = slx[xj], vx = svx[xj];
        const float f00 = fc[y0 * FW + x0];
        const float f01 = fc[y0 * FW + x1];
        const float f10 = fc[y1 * FW + x0];
        const float f11 = fc[y1 * FW + x1];
        float v = f00 * (1.0f - ly) * (1.0f - lx) + f01 * (1.0f - ly) * lx +
                  f10 * ly * (1.0f - lx) + f11 * ly * lx;
        acc += v * (vy * vx);
      }
    }
    xrow[k] = acc * 0.25f;
  }
}

// ------------------------------------------------------- FC1 (K-split GEMM)
// A: 1024 x 25088, B(w1): 25088 x 1024. grid (16,16,8) -> 64x64 tile, K-chunk 3136
__global__ __launch_bounds__(256) void gemm1_kernel(
    const float* __restrict__ A, const float* __restrict__ B,
    float* __restrict__ CP) {
  __shared__ float As[16][68];
  __shared__ float Bs[16][68];
  const int tid = threadIdx.x;
  const int mTile = blockIdx.y << 6;
  const int nTile = blockIdx.x << 6;
  const int k0 = blockIdx.z * 3136;
  const int ty = tid >> 4, tx = tid & 15;
  const int ar = tid >> 2, ac = (tid & 3) << 2;
  const int br = tid >> 4, bcl = (tid & 15) << 2;
  float acc[4][4] = {};

  for (int kb = k0; kb < k0 + 3136; kb += 16) {
    const float4 av = *(const float4*)(A + (size_t)(mTile + ar) * K1 + kb + ac);
    const float4 bv = *(const float4*)(B + (size_t)(kb + br) * HID + nTile + bcl);
    As[ac + 0][ar] = av.x; As[ac + 1][ar] = av.y;
    As[ac + 2][ar] = av.z; As[ac + 3][ar] = av.w;
    *(float4*)(&Bs[br][bcl]) = bv;
    __syncthreads();
#pragma unroll
    for (int kk = 0; kk < 16; ++kk) {
      const float4 a4 = *(const float4*)(&As[kk][ty << 2]);
      const float4 b4 = *(const float4*)(&Bs[kk][tx << 2]);
      const float aa[4] = {a4.x, a4.y, a4.z, a4.w};
      const float bb4[4] = {b4.x, b4.y, b4.z, b4.w};
#pragma unroll
      for (int i = 0; i < 4; ++i)
#pragma unroll
        for (int j = 0; j < 4; ++j)
          acc[i][j] = fmaf(aa[i], bb4[j], acc[i][j]);
    }
    __syncthreads();
  }
  float* Cp = CP + (size_t)blockIdx.z * (HID * NROI);
#pragma unroll
  for (int i = 0; i < 4; ++i) {
    *(float4*)(Cp + (size_t)(mTile + (ty << 2) + i) * HID + nTile + (tx << 2)) =
        make_float4(acc[i][0], acc[i][1], acc[i][2], acc[i][3]);
  }
}

// reduce 8 K-partials + bias + relu
__global__ __launch_bounds__(256) void bias_relu_kernel(
    const float* __restrict__ CP, const float* __restrict__ b1,
    float* __restrict__ H1) {
  const int idx = blockIdx.x * 256 + threadIdx.x;
  float v = b1[idx & (HID - 1)];
#pragma unroll
  for (int z = 0; z < 8; ++z) v += CP[(size_t)z * (HID * NROI) + idx];
  H1[idx] = fmaxf(v, 0.0f);
}

// ------------------------------------------------------------- FC2 (K=1024)
__global__ __launch_bounds__(256) void gemm2_kernel(
    const float* __restrict__ A, const float* __restrict__ B,
    const float* __restrict__ bias, float* __restrict__ C) {
  __shared__ float As[16][68];
  __shared__ float Bs[16][68];
  const int tid = threadIdx.x;
  const int mTile = blockIdx.y << 6;
  const int nTile = blockIdx.x << 6;
  const int ty = tid >> 4, tx = tid & 15;
  const int ar = tid >> 2, ac = (tid & 3) << 2;
  const int br = tid >> 4, bcl = (tid & 15) << 2;
  float acc[4][4] = {};

  for (int kb = 0; kb < HID; kb += 16) {
    const float4 av = *(const float4*)(A + (size_t)(mTile + ar) * HID + kb + ac);
    const float4 bv = *(const float4*)(B + (size_t)(kb + br) * HID + nTile + bcl);
    As[ac + 0][ar] = av.x; As[ac + 1][ar] = av.y;
    As[ac + 2][ar] = av.z; As[ac + 3][ar] = av.w;
    *(float4*)(&Bs[br][bcl]) = bv;
    __syncthreads();
#pragma unroll
    for (int kk = 0; kk < 16; ++kk) {
      const float4 a4 = *(const float4*)(&As[kk][ty << 2]);
      const float4 b4 = *(const float4*)(&Bs[kk][tx << 2]);
      const float aa[4] = {a4.x, a4.y, a4.z, a4.w};
      const float bb4[4] = {b4.x, b4.y, b4.z, b4.w};
#pragma unroll
      for (int i = 0; i < 4; ++i)
#pragma unroll
        for (int j = 0; j < 4; ++j)
          acc[i][j] = fmaf(aa[i], bb4[j], acc[i][j]);
    }
    __syncthreads();
  }
#pragma unroll
  for (int i = 0; i < 4; ++i) {
#pragma unroll
    for (int j = 0; j < 4; ++j) {
      float v = acc[i][j] + bias[nTile + (tx << 2) + j];
      acc[i][j] = fmaxf(v, 0.0f);
    }
    *(float4*)(C + (size_t)(mTile + (ty << 2) + i) * HID + nTile + (tx << 2)) =
        make_float4(acc[i][0], acc[i][1], acc[i][2], acc[i][3]);
  }
}

// ------------------- heads: cls+box dots, softmax, decode, candidate arrays
__global__ __launch_bounds__(128) void heads_kernel(
    const float* __restrict__ H2m, const float* __restrict__ wc,
    const float* __restrict__ bc, const float* __restrict__ wb,
    const float* __restrict__ bb, const float* __restrict__ props,
    float* __restrict__ BX, float* __restrict__ NB,
    float* __restrict__ AR, float* __restrict__ LV) {
  const int r = blockIdx.x;
  const int tid = threadIdx.x;
  __shared__ float hrow[HID];
  __shared__ float vals[112];
  __shared__ float red[2];

  for (int i = tid; i < HID; i += 128) hrow[i] = H2m[(size_t)r * HID + i];
  __syncthreads();

  if (tid < 105) {
    float acc;
    if (tid < NCLS) {
      acc = bc[tid];
      for (int kk = 0; kk < HID; ++kk) acc = fmaf(hrow[kk], wc[kk * NCLS + tid], acc);
    } else {
      const int j = tid - NCLS;
      acc = bb[j];
      for (int kk = 0; kk < HID; ++kk) acc = fmaf(hrow[kk], wb[kk * (NCLS * 4) + j], acc);
    }
    vals[tid] = acc;
  }
  __syncthreads();

  if (tid == 0) {
    float m = vals[0];
    for (int k = 1; k < NCLS; ++k) m = fmaxf(m, vals[k]);
    float s = 0.0f;
    for (int k = 0; k < NCLS; ++k) s += expf(vals[k] - m);
    red[0] = m;
    red[1] = 1.0f / s;
  }
  __syncthreads();

  if (tid >= 1 && tid <= 20) {
    const int k = tid;
    const float prob = expf(vals[k] - red[0]) * red[1];

    const float px1 = props[r * 4 + 0], py1 = props[r * 4 + 1];
    const float px2 = props[r * 4 + 2], py2 = props[r * 4 + 3];
    const float pw = px2 - px1, ph = py2 - py1;
    const float pcx = px1 + 0.5f * pw, pcy = py1 + 0.5f * ph;

    const float dx = vals[NCLS + k * 4 + 0] / 10.0f;
    const float dy = vals[NCLS + k * 4 + 1] / 10.0f;
    const float dw = fminf(vals[NCLS + k * 4 + 2] / 5.0f, LOGMAX);
    const float dh = fminf(vals[NCLS + k * 4 + 3] / 5.0f, LOGMAX);

    const float cx = dx * pw + pcx, cy = dy * ph + pcy;
    const float w = expf(dw) * pw, h = expf(dh) * ph;
    float b0 = cx - 0.5f * w, b1c = cy - 0.5f * h;
    float b2 = cx + 0.5f * w, b3 = cy + 0.5f * h;
    b0 = fminf(fmaxf(b0, 0.0f), IMGSZ);
    b1c = fminf(fmaxf(b1c, 0.0f), IMGSZ);
    b2 = fminf(fmaxf(b2, 0.0f), IMGSZ);
    b3 = fminf(fmaxf(b3, 0.0f), IMGSZ);

    const float wv = b2 - b0, hv = b3 - b1c;
    const bool valid = (prob > 0.05f) && (wv >= 0.01f) && (hv >= 0.01f);

    const int n = r >> 9, s = r & 511;
    const int cand = s * 20 + (k - 1);
    const size_t bi = (size_t)n * MCAND + cand;
    const float off = (float)k * (IMGSZ + 1.0f);

    BX[bi * 4 + 0] = b0; BX[bi * 4 + 1] = b1c;
    BX[bi * 4 + 2] = b2; BX[bi * 4 + 3] = b3;
    const float n0 = b0 + off, n1 = b1c + off, n2 = b2 + off, n3 = b3 + off;
    NB[bi * 4 + 0] = n0; NB[bi * 4 + 1] = n1;
    NB[bi * 4 + 2] = n2; NB[bi * 4 + 3] = n3;
    AR[bi] = (n2 - n0) * (n3 - n1);
    LV[bi] = valid ? prob : -1.0f;
  }
}

// ------------------------------------------------------ greedy NMS per image
__global__ __launch_bounds__(1024) void nms_kernel(
    const float* __restrict__ BX, const float* __restrict__ NB,
    const float* __restrict__ AR, const float* __restrict__ LV,
    float* __restrict__ out) {
  const int n = blockIdx.x;
  const int tid = threadIdx.x;
  __shared__ float rv[16];
  __shared__ int ri[16];
  __shared__ float selb[5];
  const size_t base = (size_t)n * MCAND;

  float lv[10], nb0[10], nb1[10], nb2[10], nb3[10], ar[10];
#pragma unroll
  for (int i = 0; i < 10; ++i) {
    const int idx = tid + (i << 10);
    lv[i] = LV[base + idx];
    const float4 b = *(const float4*)(NB + (base + idx) * 4);
    nb0[i] = b.x; nb1[i] = b.y; nb2[i] = b.z; nb3[i] = b.w;
    ar[i] = AR[base + idx];
  }

  for (int d = 0; d < NDET; ++d) {
    // local argmax (first-max tie-break: idx grows with i, so strict > is stable)
    float bv = -2.0f;
    int bi = 1 << 30;
#pragma unroll
    for (int i = 0; i < 10; ++i) {
      const int idx = tid + (i << 10);
      if (lv[i] > bv) { bv = lv[i]; bi = idx; }
    }
    // wave reduce (64 lanes)
#pragma unroll
    for (int off = 32; off > 0; off >>= 1) {
      const float ov = __shfl_down(bv, off);
      const int oi = __shfl_down(bi, off);
      if (ov > bv || (ov == bv && oi < bi)) { bv = ov; bi = oi; }
    }
    if ((tid & 63) == 0) { rv[tid >> 6] = bv; ri[tid >> 6] = bi; }
    __syncthreads();
    if (tid == 0) {
      float sv = rv[0];
      int si = ri[0];
      for (int wq = 1; wq < 16; ++wq) {
        if (rv[wq] > sv || (rv[wq] == sv && ri[wq] < si)) { sv = rv[wq]; si = ri[wq]; }
      }
      const bool keep = sv > 0.05f;
      const float4 bx4 = *(const float4*)(BX + (base + si) * 4);
      const float4 nb4 = *(const float4*)(NB + (base + si) * 4);
      out[(n * NDET + d) * 4 + 0] = keep ? bx4.x : 0.0f;
      out[(n * NDET + d) * 4 + 1] = keep ? bx4.y : 0.0f;
      out[(n * NDET + d) * 4 + 2] = keep ? bx4.z : 0.0f;
      out[(n * NDET + d) * 4 + 3] = keep ? bx4.w : 0.0f;
      out[NIMG * NDET * 4 + n * NDET + d] = keep ? sv : 0.0f;
      out[NIMG * NDET * 4 + NIMG * NDET + n * NDET + d] =
          keep ? (float)(1 + (si % 20)) : 0.0f;
      selb[0] = nb4.x; selb[1] = nb4.y; selb[2] = nb4.z; selb[3] = nb4.w;
      selb[4] = AR[base + si];
    }
    __syncthreads();
    const float s0 = selb[0], s1 = selb[1], s2 = selb[2], s3 = selb[3], sa = selb[4];
#pragma unroll
    for (int i = 0; i < 10; ++i) {
      const float xx1 = fmaxf(s0, nb0[i]);
      const float yy1 = fmaxf(s1, nb1[i]);
      const float xx2 = fminf(s2, nb2[i]);
      const float yy2 = fminf(s3, nb3[i]);
      const float inter = fmaxf(xx2 - xx1, 0.0f) * fmaxf(yy2 - yy1, 0.0f);
      const float iou = inter / (sa + ar[i] - inter + 1e-9f);
      if (iou > 0.5f) lv[i] = -1.0f;
    }
  }
}

// ---------------------------------------------------------------- launcher
extern "C" void kernel_launch(void* const* d_in, const int* in_sizes, int n_in,
                              void* d_out, int out_size, void* d_ws, size_t ws_size,
                              hipStream_t stream) {
  const float* features  = (const float*)d_in[0];
  const float* proposals = (const float*)d_in[1];
  const float* w1 = (const float*)d_in[2];
  const float* b1 = (const float*)d_in[3];
  const float* w2 = (const float*)d_in[4];
  const float* b2 = (const float*)d_in[5];
  const float* wc = (const float*)d_in[6];
  const float* bc = (const float*)d_in[7];
  const float* wb = (const float*)d_in[8];
  const float* bb = (const float*)d_in[9];

  float* ws = (float*)d_ws;
  float* X   = ws;                                   // 1024*25088
  float* CP  = X + (size_t)NROI * K1;                // 8 * 1024*1024 partials
  float* H1  = CP + (size_t)8 * NROI * HID;          // 1024*1024
  float* H2  = H1 + (size_t)NROI * HID;              // 1024*1024
  float* BXc = H2 + (size_t)NROI * HID;              // 2*10240*4
  float* NBc = BXc + (size_t)NIMG * MCAND * 4;       // 2*10240*4
  float* ARc = NBc + (size_t)NIMG * MCAND * 4;       // 2*10240
  float* LVc = ARc + (size_t)NIMG * MCAND;           // 2*10240

  roi_kernel<<<NROI, 256, 0, stream>>>(features, proposals, X);
  gemm1_kernel<<<dim3(16, 16, 8), 256, 0, stream>>>(X, w1, CP);
  bias_relu_kernel<<<(NROI * HID) / 256, 256, 0, stream>>>(CP, b1, H1);
  gemm2_kernel<<<dim3(16, 16), 256, 0, stream>>>(H1, w2, b2, H2);
  heads_kernel<<<NROI, 128, 0, stream>>>(H2, wc, bc, wb, bb, proposals,
                                         BXc, NBc, ARc, LVc);
  nms_kernel<<<NIMG, 1024, 0, stream>>>(BXc, NBc, ARc, LVc, (float*)d_out);
}

// Round 2
// 1166.717 us; speedup vs baseline: 1.4967x; 1.4967x over previous
//
#include <hip/hip_runtime.h>
#include <cmath>

// Problem constants (N=2, S=512, C=512, H=W=50, OUT=7, RATIO=2)
#define NIMG 2
#define SPROP 512
#define NROI 1024          // NIMG*SPROP
#define CCH 512
#define FH 50
#define FW 50
#define K1 25088           // CCH*7*7
#define HID 1024
#define NCLS 21
#define NDET 100
#define IMGSZ 800.0f
#define LOGMAX 4.135166556742356f   // log(1000/16)
#define MCAND 10240        // SPROP*(NCLS-1)
#define ZSPLIT 8
#define KCHUNK 3136        // K1/ZSPLIT

typedef unsigned short u16;
typedef __attribute__((ext_vector_type(8))) short short8;
typedef __attribute__((ext_vector_type(4))) float f32x4;

__device__ __forceinline__ u16 f2bf(float x) {        // RTNE fp32 -> bf16
  unsigned int u = __float_as_uint(x);
  u += 0x7fffu + ((u >> 16) & 1u);
  return (u16)(u >> 16);
}
__device__ __forceinline__ float bf2f(u16 h) {
  return __uint_as_float(((unsigned int)h) << 16);
}

// ------------------------------------------------------------ ROI align
// Per-block = 1 ROI. Stage a 16x16 pixel bounding box per 32-channel chunk
// into LDS (row-contiguous loads), bilinear from LDS. Writes X either as
// fp32 (fallback) or as bf16 hi/lo planes (MFMA path).
template <bool BF16OUT>
__global__ __launch_bounds__(256) void roi_kernel(
    const float* __restrict__ feat, const float* __restrict__ props,
    float* __restrict__ X, u16* __restrict__ Xhi, u16* __restrict__ Xlo) {
  const int r = blockIdx.x;
  const int n = r >> 9;
  const int tid = threadIdx.x;
  __shared__ float tile[32][256];   // 32 ch x (16x16 px) = 32 KB
  __shared__ int sy0[14], sy1[14], sx0[14], sx1[14];
  __shared__ float sly[14], slx[14], svy[14], svx[14];

  const float p0 = props[r * 4 + 0] * 0.0625f;
  const float p1 = props[r * 4 + 1] * 0.0625f;
  const float p2 = props[r * 4 + 2] * 0.0625f;
  const float p3 = props[r * 4 + 3] * 0.0625f;
  const float bw = fmaxf(p2 - p0, 1.0f) / 7.0f;
  const float bh = fmaxf(p3 - p1, 1.0f) / 7.0f;

  if (tid < 14) {
    const int j = tid;
    const float g = (float)(j >> 1) + ((float)(j & 1) + 0.5f) * 0.5f;
    float y = p1 + g * bh;
    svy[j] = (y > -1.0f && y < (float)FH) ? 1.0f : 0.0f;
    float yc = fminf(fmaxf(y, 0.0f), (float)(FH - 1));
    int y0 = (int)floorf(yc);
    sy0[j] = y0; sy1[j] = min(y0 + 1, FH - 1); sly[j] = yc - (float)y0;
    float x = p0 + g * bw;
    svx[j] = (x > -1.0f && x < (float)FW) ? 1.0f : 0.0f;
    float xc = fminf(fmaxf(x, 0.0f), (float)(FW - 1));
    int x0 = (int)floorf(xc);
    sx0[j] = x0; sx1[j] = min(x0 + 1, FW - 1); slx[j] = xc - (float)x0;
  }
  __syncthreads();
  // ys/xs are monotonically increasing (bh,bw > 0); extent <= 14 < 16.
  const int ymin = sy0[0], xmin = sx0[0];
  const float* fb = feat + (size_t)n * CCH * (FH * FW);

  for (int cc = 0; cc < 16; ++cc) {
    const int c0 = cc * 32;
#pragma unroll
    for (int e = 0; e < 32; ++e) {
      const int idx = tid + e * 256;
      const int c = idx >> 8, p = idx & 255;
      const int gy = min(ymin + (p >> 4), FH - 1);
      const int gx = min(xmin + (p & 15), FW - 1);
      tile[c][p] = fb[(size_t)(c0 + c) * (FH * FW) + gy * FW + gx];
    }
    __syncthreads();
#pragma unroll
    for (int e = 0; e < 7; ++e) {
      const int idx = tid + e * 256;
      if (idx < 1568) {
        const int c = idx / 49;
        const int s = idx - c * 49;
        const int oy = s / 7, ox = s - (s / 7) * 7;
        float acc = 0.0f;
#pragma unroll
        for (int sy = 0; sy < 2; ++sy) {
          const int yj = oy * 2 + sy;
          const int py0 = sy0[yj] - ymin, py1 = sy1[yj] - ymin;
          const float ly = sly[yj], vy = svy[yj];
#pragma unroll
          for (int sx = 0; sx < 2; ++sx) {
            const int xj = ox * 2 + sx;
            const int px0 = sx0[xj] - xmin, px1 = sx1[xj] - xmin;
            const float lx = slx[xj], vx = svx[xj];
            const float f00 = tile[c][py0 * 16 + px0];
            const float f01 = tile[c][py0 * 16 + px1];
            const float f10 = tile[c][py1 * 16 + px0];
            const float f11 = tile[c][py1 * 16 + px1];
            float v = f00 * (1.0f - ly) * (1.0f - lx) + f01 * (1.0f - ly) * lx +
                      f10 * ly * (1.0f - lx) + f11 * ly * lx;
            acc += v * (vy * vx);
          }
        }
        const float v = acc * 0.25f;
        const size_t k = (size_t)r * K1 + (size_t)(c0 + c) * 49 + s;
        if (BF16OUT) {
          const u16 h = f2bf(v);
          Xhi[k] = h;
          Xlo[k] = f2bf(v - bf2f(h));
        } else {
          X[k] = v;
        }
      }
    }
    __syncthreads();
  }
}

// ------------------------- w1 (25088x1024 f32) -> hi/lo bf16, TRANSPOSED to
// [n][k] (k-contig) so GEMM B-frags are vector LDS loads.
__global__ __launch_bounds__(256) void convw1_kernel(
    const float* __restrict__ w1, u16* __restrict__ Wh, u16* __restrict__ Wl) {
  __shared__ u16 sh[64][65], sl[64][65];
  const int k0 = blockIdx.x * 64;
  const int n0 = blockIdx.y * 64;
  const int t = threadIdx.x;
#pragma unroll
  for (int e = 0; e < 16; ++e) {
    const int idx = t + e * 256;
    const int kl = idx >> 6, nl = idx & 63;
    const float v = w1[(size_t)(k0 + kl) * HID + n0 + nl];
    const u16 h = f2bf(v);
    sh[kl][nl] = h;
    sl[kl][nl] = f2bf(v - bf2f(h));
  }
  __syncthreads();
#pragma unroll
  for (int e = 0; e < 16; ++e) {
    const int idx = t + e * 256;
    const int nl = idx >> 6, kl = idx & 63;
    Wh[(size_t)(n0 + nl) * K1 + k0 + kl] = sh[kl][nl];
    Wl[(size_t)(n0 + nl) * K1 + k0 + kl] = sl[kl][nl];
  }
}

// ------------------------------- FC1: split-bf16 MFMA GEMM, K-split z=8
// C(1024x1024) = X(1024x25088) @ w1(25088x1024), 3-term split:
//   Ahi*Bhi + Ahi*Blo + Alo*Bhi   (fp32 MFMA accumulators)
// 128x128 tile, BK=32, 4 waves of 64x64 (4x4 mfma_16x16x32 tiles).
__global__ __launch_bounds__(256, 2) void gemm1_mfma(
    const u16* __restrict__ Ahg, const u16* __restrict__ Alg,
    const u16* __restrict__ Bhg, const u16* __restrict__ Blg,
    float* __restrict__ CP) {
  // rows padded to 40 bf16 (80 B): frag ds_read_b128 lands 2-deep/bank (free)
  __shared__ u16 Ah[128][40], Al[128][40], Bh[128][40], Bl[128][40];
  const int tid = threadIdx.x;
  const int lane = tid & 63;
  const int wv = tid >> 6;
  const int wm = (wv >> 1) * 64;
  const int wn = (wv & 1) * 64;
  const int mT = blockIdx.y << 7;
  const int nT = blockIdx.x << 7;
  const int kz = blockIdx.z * KCHUNK;

  const int r0 = tid >> 2, q0 = (tid & 3) << 3;
  const int r1 = r0 + 64;                       // second chunk: (tid+256)

  f32x4 acc[4][4];
  const f32x4 zz = {0.0f, 0.0f, 0.0f, 0.0f};
#pragma unroll
  for (int i = 0; i < 4; ++i)
#pragma unroll
    for (int j = 0; j < 4; ++j) acc[i][j] = zz;

  const size_t a0off = (size_t)(mT + r0) * K1 + q0;
  const size_t a1off = (size_t)(mT + r1) * K1 + q0;
  const size_t b0off = (size_t)(nT + r0) * K1 + q0;
  const size_t b1off = (size_t)(nT + r1) * K1 + q0;

  const int fm = lane & 15;          // m (A) / n (B) within 16-tile
  const int fq = (lane >> 4) << 3;   // k-quad * 8

  for (int kb = kz; kb < kz + KCHUNK; kb += 32) {
    const uint4 va0 = *(const uint4*)(Ahg + a0off + kb);
    const uint4 va1 = *(const uint4*)(Ahg + a1off + kb);
    const uint4 vl0 = *(const uint4*)(Alg + a0off + kb);
    const uint4 vl1 = *(const uint4*)(Alg + a1off + kb);
    const uint4 vb0 = *(const uint4*)(Bhg + b0off + kb);
    const uint4 vb1 = *(const uint4*)(Bhg + b1off + kb);
    const uint4 vm0 = *(const uint4*)(Blg + b0off + kb);
    const uint4 vm1 = *(const uint4*)(Blg + b1off + kb);
    *(uint4*)(&Ah[r0][q0]) = va0;
    *(uint4*)(&Ah[r1][q0]) = va1;
    *(uint4*)(&Al[r0][q0]) = vl0;
    *(uint4*)(&Al[r1][q0]) = vl1;
    *(uint4*)(&Bh[r0][q0]) = vb0;
    *(uint4*)(&Bh[r1][q0]) = vb1;
    *(uint4*)(&Bl[r0][q0]) = vm0;
    *(uint4*)(&Bl[r1][q0]) = vm1;
    __syncthreads();

    short8 fah[4], fal[4], fbh[4], fbl[4];
#pragma unroll
    for (int t = 0; t < 4; ++t) {
      fah[t] = *(const short8*)(&Ah[wm + t * 16 + fm][fq]);
      fal[t] = *(const short8*)(&Al[wm + t * 16 + fm][fq]);
      fbh[t] = *(const short8*)(&Bh[wn + t * 16 + fm][fq]);
      fbl[t] = *(const short8*)(&Bl[wn + t * 16 + fm][fq]);
    }
#pragma unroll
    for (int ti = 0; ti < 4; ++ti)
#pragma unroll
      for (int tj = 0; tj < 4; ++tj) {
        acc[ti][tj] = __builtin_amdgcn_mfma_f32_16x16x32_bf16(
            fah[ti], fbh[tj], acc[ti][tj], 0, 0, 0);
        acc[ti][tj] = __builtin_amdgcn_mfma_f32_16x16x32_bf16(
            fah[ti], fbl[tj], acc[ti][tj], 0, 0, 0);
        acc[ti][tj] = __builtin_amdgcn_mfma_f32_16x16x32_bf16(
            fal[ti], fbh[tj], acc[ti][tj], 0, 0, 0);
      }
    __syncthreads();
  }

  // C/D layout: col = lane&15, row = (lane>>4)*4 + reg   [m89-verified]
  float* Cp = CP + (size_t)blockIdx.z * ((size_t)NROI * HID);
  const int crow = mT + wm + (lane >> 4) * 4;
  const int ccol = nT + wn + fm;
#pragma unroll
  for (int ti = 0; ti < 4; ++ti)
#pragma unroll
    for (int tj = 0; tj < 4; ++tj)
#pragma unroll
      for (int rr = 0; rr < 4; ++rr)
        Cp[(size_t)(crow + ti * 16 + rr) * HID + ccol + tj * 16] =
            acc[ti][tj][rr];
}

// ------------------------------------------------------- FC1 fallback (fp32)
__global__ __launch_bounds__(256) void gemm1_kernel(
    const float* __restrict__ A, const float* __restrict__ B,
    float* __restrict__ CP) {
  __shared__ float As[16][68];
  __shared__ float Bs[16][68];
  const int tid = threadIdx.x;
  const int mTile = blockIdx.y << 6;
  const int nTile = blockIdx.x << 6;
  const int k0 = blockIdx.z * KCHUNK;
  const int ty = tid >> 4, tx = tid & 15;
  const int ar = tid >> 2, ac = (tid & 3) << 2;
  const int br = tid >> 4, bcl = (tid & 15) << 2;
  float acc[4][4] = {};

  for (int kb = k0; kb < k0 + KCHUNK; kb += 16) {
    const float4 av = *(const float4*)(A + (size_t)(mTile + ar) * K1 + kb + ac);
    const float4 bv = *(const float4*)(B + (size_t)(kb + br) * HID + nTile + bcl);
    As[ac + 0][ar] = av.x; As[ac + 1][ar] = av.y;
    As[ac + 2][ar] = av.z; As[ac + 3][ar] = av.w;
    *(float4*)(&Bs[br][bcl]) = bv;
    __syncthreads();
#pragma unroll
    for (int kk = 0; kk < 16; ++kk) {
      const float4 a4 = *(const float4*)(&As[kk][ty << 2]);
      const float4 b4 = *(const float4*)(&Bs[kk][tx << 2]);
      const float aa[4] = {a4.x, a4.y, a4.z, a4.w};
      const float bb4[4] = {b4.x, b4.y, b4.z, b4.w};
#pragma unroll
      for (int i = 0; i < 4; ++i)
#pragma unroll
        for (int j = 0; j < 4; ++j)
          acc[i][j] = fmaf(aa[i], bb4[j], acc[i][j]);
    }
    __syncthreads();
  }
  float* Cp = CP + (size_t)blockIdx.z * (HID * NROI);
#pragma unroll
  for (int i = 0; i < 4; ++i) {
    *(float4*)(Cp + (size_t)(mTile + (ty << 2) + i) * HID + nTile + (tx << 2)) =
        make_float4(acc[i][0], acc[i][1], acc[i][2], acc[i][3]);
  }
}

// reduce 8 K-partials + bias + relu
__global__ __launch_bounds__(256) void bias_relu_kernel(
    const float* __restrict__ CP, const float* __restrict__ b1,
    float* __restrict__ H1) {
  const int idx = blockIdx.x * 256 + threadIdx.x;
  float v = b1[idx & (HID - 1)];
#pragma unroll
  for (int z = 0; z < ZSPLIT; ++z) v += CP[(size_t)z * (HID * NROI) + idx];
  H1[idx] = fmaxf(v, 0.0f);
}

// ------------------------------------------------------------- FC2 (K=1024)
__global__ __launch_bounds__(256) void gemm2_kernel(
    const float* __restrict__ A, const float* __restrict__ B,
    const float* __restrict__ bias, float* __restrict__ C) {
  __shared__ float As[16][68];
  __shared__ float Bs[16][68];
  const int tid = threadIdx.x;
  const int mTile = blockIdx.y << 6;
  const int nTile = blockIdx.x << 6;
  const int ty = tid >> 4, tx = tid & 15;
  const int ar = tid >> 2, ac = (tid & 3) << 2;
  const int br = tid >> 4, bcl = (tid & 15) << 2;
  float acc[4][4] = {};

  for (int kb = 0; kb < HID; kb += 16) {
    const float4 av = *(const float4*)(A + (size_t)(mTile + ar) * HID + kb + ac);
    const float4 bv = *(const float4*)(B + (size_t)(kb + br) * HID + nTile + bcl);
    As[ac + 0][ar] = av.x; As[ac + 1][ar] = av.y;
    As[ac + 2][ar] = av.z; As[ac + 3][ar] = av.w;
    *(float4*)(&Bs[br][bcl]) = bv;
    __syncthreads();
#pragma unroll
    for (int kk = 0; kk < 16; ++kk) {
      const float4 a4 = *(const float4*)(&As[kk][ty << 2]);
      const float4 b4 = *(const float4*)(&Bs[kk][tx << 2]);
      const float aa[4] = {a4.x, a4.y, a4.z, a4.w};
      const float bb4[4] = {b4.x, b4.y, b4.z, b4.w};
#pragma unroll
      for (int i = 0; i < 4; ++i)
#pragma unroll
        for (int j = 0; j < 4; ++j)
          acc[i][j] = fmaf(aa[i], bb4[j], acc[i][j]);
    }
    __syncthreads();
  }
#pragma unroll
  for (int i = 0; i < 4; ++i) {
#pragma unroll
    for (int j = 0; j < 4; ++j) {
      float v = acc[i][j] + bias[nTile + (tx << 2) + j];
      acc[i][j] = fmaxf(v, 0.0f);
    }
    *(float4*)(C + (size_t)(mTile + (ty << 2) + i) * HID + nTile + (tx << 2)) =
        make_float4(acc[i][0], acc[i][1], acc[i][2], acc[i][3]);
  }
}

// ------------------- heads: cls+box dots, softmax, decode, candidate arrays
__global__ __launch_bounds__(128) void heads_kernel(
    const float* __restrict__ H2m, const float* __restrict__ wc,
    const float* __restrict__ bc, const float* __restrict__ wb,
    const float* __restrict__ bb, const float* __restrict__ props,
    float* __restrict__ BX, float* __restrict__ NB,
    float* __restrict__ AR, float* __restrict__ LV) {
  const int r = blockIdx.x;
  const int tid = threadIdx.x;
  __shared__ float hrow[HID];
  __shared__ float vals[112];
  __shared__ float red[2];

  for (int i = tid; i < HID; i += 128) hrow[i] = H2m[(size_t)r * HID + i];
  __syncthreads();

  if (tid < 105) {
    float acc;
    if (tid < NCLS) {
      acc = bc[tid];
      for (int kk = 0; kk < HID; ++kk) acc = fmaf(hrow[kk], wc[kk * NCLS + tid], acc);
    } else {
      const int j = tid - NCLS;
      acc = bb[j];
      for (int kk = 0; kk < HID; ++kk) acc = fmaf(hrow[kk], wb[kk * (NCLS * 4) + j], acc);
    }
    vals[tid] = acc;
  }
  __syncthreads();

  if (tid == 0) {
    float m = vals[0];
    for (int k = 1; k < NCLS; ++k) m = fmaxf(m, vals[k]);
    float s = 0.0f;
    for (int k = 0; k < NCLS; ++k) s += expf(vals[k] - m);
    red[0] = m;
    red[1] = 1.0f / s;
  }
  __syncthreads();

  if (tid >= 1 && tid <= 20) {
    const int k = tid;
    const float prob = expf(vals[k] - red[0]) * red[1];

    const float px1 = props[r * 4 + 0], py1 = props[r * 4 + 1];
    const float px2 = props[r * 4 + 2], py2 = props[r * 4 + 3];
    const float pw = px2 - px1, ph = py2 - py1;
    const float pcx = px1 + 0.5f * pw, pcy = py1 + 0.5f * ph;

    const float dx = vals[NCLS + k * 4 + 0] / 10.0f;
    const float dy = vals[NCLS + k * 4 + 1] / 10.0f;
    const float dw = fminf(vals[NCLS + k * 4 + 2] / 5.0f, LOGMAX);
    const float dh = fminf(vals[NCLS + k * 4 + 3] / 5.0f, LOGMAX);

    const float cx = dx * pw + pcx, cy = dy * ph + pcy;
    const float w = expf(dw) * pw, h = expf(dh) * ph;
    float b0 = cx - 0.5f * w, b1c = cy - 0.5f * h;
    float b2 = cx + 0.5f * w, b3 = cy + 0.5f * h;
    b0 = fminf(fmaxf(b0, 0.0f), IMGSZ);
    b1c = fminf(fmaxf(b1c, 0.0f), IMGSZ);
    b2 = fminf(fmaxf(b2, 0.0f), IMGSZ);
    b3 = fminf(fmaxf(b3, 0.0f), IMGSZ);

    const float wv = b2 - b0, hv = b3 - b1c;
    const bool valid = (prob > 0.05f) && (wv >= 0.01f) && (hv >= 0.01f);

    const int n = r >> 9, s = r & 511;
    const int cand = s * 20 + (k - 1);
    const size_t bi = (size_t)n * MCAND + cand;
    const float off = (float)k * (IMGSZ + 1.0f);

    BX[bi * 4 + 0] = b0; BX[bi * 4 + 1] = b1c;
    BX[bi * 4 + 2] = b2; BX[bi * 4 + 3] = b3;
    const float n0 = b0 + off, n1 = b1c + off, n2 = b2 + off, n3 = b3 + off;
    NB[bi * 4 + 0] = n0; NB[bi * 4 + 1] = n1;
    NB[bi * 4 + 2] = n2; NB[bi * 4 + 3] = n3;
    AR[bi] = (n2 - n0) * (n3 - n1);
    LV[bi] = valid ? prob : -1.0f;
  }
}

// ------------------------------------------------------ greedy NMS per image
__global__ __launch_bounds__(1024) void nms_kernel(
    const float* __restrict__ BX, const float* __restrict__ NB,
    const float* __restrict__ AR, const float* __restrict__ LV,
    float* __restrict__ out) {
  const int n = blockIdx.x;
  const int tid = threadIdx.x;
  __shared__ float rv[16];
  __shared__ int ri[16];
  __shared__ float selb[5];
  const size_t base = (size_t)n * MCAND;

  float lv[10], nb0[10], nb1[10], nb2[10], nb3[10], ar[10];
#pragma unroll
  for (int i = 0; i < 10; ++i) {
    const int idx = tid + (i << 10);
    lv[i] = LV[base + idx];
    const float4 b = *(const float4*)(NB + (base + idx) * 4);
    nb0[i] = b.x; nb1[i] = b.y; nb2[i] = b.z; nb3[i] = b.w;
    ar[i] = AR[base + idx];
  }

  for (int d = 0; d < NDET; ++d) {
    float bv = -2.0f;
    int bi = 1 << 30;
#pragma unroll
    for (int i = 0; i < 10; ++i) {
      const int idx = tid + (i << 10);
      if (lv[i] > bv) { bv = lv[i]; bi = idx; }
    }
#pragma unroll
    for (int off = 32; off > 0; off >>= 1) {
      const float ov = __shfl_down(bv, off);
      const int oi = __shfl_down(bi, off);
      if (ov > bv || (ov == bv && oi < bi)) { bv = ov; bi = oi; }
    }
    if ((tid & 63) == 0) { rv[tid >> 6] = bv; ri[tid >> 6] = bi; }
    __syncthreads();
    if (tid == 0) {
      float sv = rv[0];
      int si = ri[0];
      for (int wq = 1; wq < 16; ++wq) {
        if (rv[wq] > sv || (rv[wq] == sv && ri[wq] < si)) { sv = rv[wq]; si = ri[wq]; }
      }
      const bool keep = sv > 0.05f;
      const float4 bx4 = *(const float4*)(BX + (base + si) * 4);
      const float4 nb4 = *(const float4*)(NB + (base + si) * 4);
      out[(n * NDET + d) * 4 + 0] = keep ? bx4.x : 0.0f;
      out[(n * NDET + d) * 4 + 1] = keep ? bx4.y : 0.0f;
      out[(n * NDET + d) * 4 + 2] = keep ? bx4.z : 0.0f;
      out[(n * NDET + d) * 4 + 3] = keep ? bx4.w : 0.0f;
      out[NIMG * NDET * 4 + n * NDET + d] = keep ? sv : 0.0f;
      out[NIMG * NDET * 4 + NIMG * NDET + n * NDET + d] =
          keep ? (float)(1 + (si % 20)) : 0.0f;
      selb[0] = nb4.x; selb[1] = nb4.y; selb[2] = nb4.z; selb[3] = nb4.w;
      selb[4] = AR[base + si];
    }
    __syncthreads();
    const float s0 = selb[0], s1 = selb[1], s2 = selb[2], s3 = selb[3], sa = selb[4];
#pragma unroll
    for (int i = 0; i < 10; ++i) {
      const float xx1 = fmaxf(s0, nb0[i]);
      const float yy1 = fmaxf(s1, nb1[i]);
      const float xx2 = fminf(s2, nb2[i]);
      const float yy2 = fminf(s3, nb3[i]);
      const float inter = fmaxf(xx2 - xx1, 0.0f) * fmaxf(yy2 - yy1, 0.0f);
      const float iou = inter / (sa + ar[i] - inter + 1e-9f);
      if (iou > 0.5f) lv[i] = -1.0f;
    }
  }
}

// ---------------------------------------------------------------- launcher
extern "C" void kernel_launch(void* const* d_in, const int* in_sizes, int n_in,
                              void* d_out, int out_size, void* d_ws, size_t ws_size,
                              hipStream_t stream) {
  const float* features  = (const float*)d_in[0];
  const float* proposals = (const float*)d_in[1];
  const float* w1 = (const float*)d_in[2];
  const float* b1 = (const float*)d_in[3];
  const float* w2 = (const float*)d_in[4];
  const float* b2 = (const float*)d_in[5];
  const float* wc = (const float*)d_in[6];
  const float* bc = (const float*)d_in[7];
  const float* wb = (const float*)d_in[8];
  const float* bb = (const float*)d_in[9];

  const size_t XE = (size_t)NROI * K1;   // 25,690,112 elements
  const size_t WE = (size_t)K1 * HID;    // 25,690,112 elements
  const size_t FLOATS_TAIL =
      (size_t)ZSPLIT * NROI * HID + 2 * (size_t)NROI * HID + (size_t)NIMG * MCAND * 10;
  const size_t NEED = (XE * 2 + WE * 2) * sizeof(u16) + FLOATS_TAIL * sizeof(float);

  if (ws_size >= NEED) {
    // --- split-bf16 MFMA path (~248.3 MB of ws) ---
    u16* Xhi = (u16*)d_ws;
    u16* Xlo = Xhi + XE;
    u16* Wh  = Xlo + XE;
    u16* Wl  = Wh + WE;
    float* CP  = (float*)(Wl + WE);
    float* H1  = CP + (size_t)ZSPLIT * NROI * HID;
    float* H2  = H1 + (size_t)NROI * HID;
    float* BXc = H2 + (size_t)NROI * HID;
    float* NBc = BXc + (size_t)NIMG * MCAND * 4;
    float* ARc = NBc + (size_t)NIMG * MCAND * 4;
    float* LVc = ARc + (size_t)NIMG * MCAND;

    convw1_kernel<<<dim3(K1 / 64, HID / 64), 256, 0, stream>>>(w1, Wh, Wl);
    roi_kernel<true><<<NROI, 256, 0, stream>>>(features, proposals, nullptr, Xhi, Xlo);
    gemm1_mfma<<<dim3(8, 8, ZSPLIT), 256, 0, stream>>>(Xhi, Xlo, Wh, Wl, CP);
    bias_relu_kernel<<<(NROI * HID) / 256, 256, 0, stream>>>(CP, b1, H1);
    gemm2_kernel<<<dim3(16, 16), 256, 0, stream>>>(H1, w2, b2, H2);
    heads_kernel<<<NROI, 128, 0, stream>>>(H2, wc, bc, wb, bb, proposals,
                                           BXc, NBc, ARc, LVc);
    nms_kernel<<<NIMG, 1024, 0, stream>>>(BXc, NBc, ARc, LVc, (float*)d_out);
  } else {
    // --- fp32 fallback path (~145 MB of ws, round-1 proven) ---
    float* ws = (float*)d_ws;
    float* X   = ws;
    float* CP  = X + XE;
    float* H1  = CP + (size_t)ZSPLIT * NROI * HID;
    float* H2  = H1 + (size_t)NROI * HID;
    float* BXc = H2 + (size_t)NROI * HID;
    float* NBc = BXc + (size_t)NIMG * MCAND * 4;
    float* ARc = NBc + (size_t)NIMG * MCAND * 4;
    float* LVc = ARc + (size_t)NIMG * MCAND;

    roi_kernel<false><<<NROI, 256, 0, stream>>>(features, proposals, X, nullptr, nullptr);
    gemm1_kernel<<<dim3(16, 16, ZSPLIT), 256, 0, stream>>>(X, w1, CP);
    bias_relu_kernel<<<(NROI * HID) / 256, 256, 0, stream>>>(CP, b1, H1);
    gemm2_kernel<<<dim3(16, 16), 256, 0, stream>>>(H1, w2, b2, H2);
    heads_kernel<<<NROI, 128, 0, stream>>>(H2, wc, bc, wb, bb, proposals,
                                           BXc, NBc, ARc, LVc);
    nms_kernel<<<NIMG, 1024, 0, stream>>>(BXc, NBc, ARc, LVc, (float*)d_out);
  }
}

// Round 3
// 1130.279 us; speedup vs baseline: 1.5450x; 1.0322x over previous
//
#include <hip/hip_runtime.h>
#include <cmath>

// Problem constants (N=2, S=512, C=512, H=W=50, OUT=7, RATIO=2)
#define NIMG 2
#define SPROP 512
#define NROI 1024          // NIMG*SPROP
#define CCH 512
#define FH 50
#define FW 50
#define K1 25088           // CCH*7*7
#define HID 1024
#define NCLS 21
#define NDET 100
#define IMGSZ 800.0f
#define LOGMAX 4.135166556742356f   // log(1000/16)
#define MCAND 10240        // SPROP*(NCLS-1)
#define ZSPLIT 8
#define KCHUNK 3136        // K1/ZSPLIT

typedef unsigned short u16;
typedef __attribute__((ext_vector_type(8))) short short8;
typedef __attribute__((ext_vector_type(4))) float f32x4;

__device__ __forceinline__ u16 f2bf(float x) {        // RTNE fp32 -> bf16
  unsigned int u = __float_as_uint(x);
  u += 0x7fffu + ((u >> 16) & 1u);
  return (u16)(u >> 16);
}
__device__ __forceinline__ float bf2f(u16 h) {
  return __uint_as_float(((unsigned int)h) << 16);
}

// ------------------------------------------------------------ ROI align
template <bool BF16OUT>
__global__ __launch_bounds__(256) void roi_kernel(
    const float* __restrict__ feat, const float* __restrict__ props,
    float* __restrict__ X, u16* __restrict__ Xhi, u16* __restrict__ Xlo) {
  const int r = blockIdx.x;
  const int n = r >> 9;
  const int tid = threadIdx.x;
  __shared__ float tile[32][256];   // 32 ch x (16x16 px) = 32 KB
  __shared__ int sy0[14], sy1[14], sx0[14], sx1[14];
  __shared__ float sly[14], slx[14], svy[14], svx[14];

  const float p0 = props[r * 4 + 0] * 0.0625f;
  const float p1 = props[r * 4 + 1] * 0.0625f;
  const float p2 = props[r * 4 + 2] * 0.0625f;
  const float p3 = props[r * 4 + 3] * 0.0625f;
  const float bw = fmaxf(p2 - p0, 1.0f) / 7.0f;
  const float bh = fmaxf(p3 - p1, 1.0f) / 7.0f;

  if (tid < 14) {
    const int j = tid;
    const float g = (float)(j >> 1) + ((float)(j & 1) + 0.5f) * 0.5f;
    float y = p1 + g * bh;
    svy[j] = (y > -1.0f && y < (float)FH) ? 1.0f : 0.0f;
    float yc = fminf(fmaxf(y, 0.0f), (float)(FH - 1));
    int y0 = (int)floorf(yc);
    sy0[j] = y0; sy1[j] = min(y0 + 1, FH - 1); sly[j] = yc - (float)y0;
    float x = p0 + g * bw;
    svx[j] = (x > -1.0f && x < (float)FW) ? 1.0f : 0.0f;
    float xc = fminf(fmaxf(x, 0.0f), (float)(FW - 1));
    int x0 = (int)floorf(xc);
    sx0[j] = x0; sx1[j] = min(x0 + 1, FW - 1); slx[j] = xc - (float)x0;
  }
  __syncthreads();
  const int ymin = sy0[0], xmin = sx0[0];
  const float* fb = feat + (size_t)n * CCH * (FH * FW);

  for (int cc = 0; cc < 16; ++cc) {
    const int c0 = cc * 32;
#pragma unroll
    for (int e = 0; e < 32; ++e) {
      const int idx = tid + e * 256;
      const int c = idx >> 8, p = idx & 255;
      const int gy = min(ymin + (p >> 4), FH - 1);
      const int gx = min(xmin + (p & 15), FW - 1);
      tile[c][p] = fb[(size_t)(c0 + c) * (FH * FW) + gy * FW + gx];
    }
    __syncthreads();
#pragma unroll
    for (int e = 0; e < 7; ++e) {
      const int idx = tid + e * 256;
      if (idx < 1568) {
        const int c = idx / 49;
        const int s = idx - c * 49;
        const int oy = s / 7, ox = s - (s / 7) * 7;
        float acc = 0.0f;
#pragma unroll
        for (int sy = 0; sy < 2; ++sy) {
          const int yj = oy * 2 + sy;
          const int py0 = sy0[yj] - ymin, py1 = sy1[yj] - ymin;
          const float ly = sly[yj], vy = svy[yj];
#pragma unroll
          for (int sx = 0; sx < 2; ++sx) {
            const int xj = ox * 2 + sx;
            const int px0 = sx0[xj] - xmin, px1 = sx1[xj] - xmin;
            const float lx = slx[xj], vx = svx[xj];
            const float f00 = tile[c][py0 * 16 + px0];
            const float f01 = tile[c][py0 * 16 + px1];
            const float f10 = tile[c][py1 * 16 + px0];
            const float f11 = tile[c][py1 * 16 + px1];
            float v = f00 * (1.0f - ly) * (1.0f - lx) + f01 * (1.0f - ly) * lx +
                      f10 * ly * (1.0f - lx) + f11 * ly * lx;
            acc += v * (vy * vx);
          }
        }
        const float v = acc * 0.25f;
        const size_t k = (size_t)r * K1 + (size_t)(c0 + c) * 49 + s;
        if (BF16OUT) {
          const u16 h = f2bf(v);
          Xhi[k] = h;
          Xlo[k] = f2bf(v - bf2f(h));
        } else {
          X[k] = v;
        }
      }
    }
    __syncthreads();
  }
}

// ------------------------- w1 -> hi/lo bf16, transposed to [n][k]
__global__ __launch_bounds__(256) void convw1_kernel(
    const float* __restrict__ w1, u16* __restrict__ Wh, u16* __restrict__ Wl) {
  __shared__ u16 sh[64][65], sl[64][65];
  const int k0 = blockIdx.x * 64;
  const int n0 = blockIdx.y * 64;
  const int t = threadIdx.x;
#pragma unroll
  for (int e = 0; e < 16; ++e) {
    const int idx = t + e * 256;
    const int kl = idx >> 6, nl = idx & 63;
    const float v = w1[(size_t)(k0 + kl) * HID + n0 + nl];
    const u16 h = f2bf(v);
    sh[kl][nl] = h;
    sl[kl][nl] = f2bf(v - bf2f(h));
  }
  __syncthreads();
#pragma unroll
  for (int e = 0; e < 16; ++e) {
    const int idx = t + e * 256;
    const int nl = idx >> 6, kl = idx & 63;
    Wh[(size_t)(n0 + nl) * K1 + k0 + kl] = sh[kl][nl];
    Wl[(size_t)(n0 + nl) * K1 + k0 + kl] = sl[kl][nl];
  }
}

// ------------------------------- FC1: split-bf16 MFMA GEMM, K-split z=8
__global__ __launch_bounds__(256, 2) void gemm1_mfma(
    const u16* __restrict__ Ahg, const u16* __restrict__ Alg,
    const u16* __restrict__ Bhg, const u16* __restrict__ Blg,
    float* __restrict__ CP) {
  __shared__ u16 Ah[128][40], Al[128][40], Bh[128][40], Bl[128][40];
  const int tid = threadIdx.x;
  const int lane = tid & 63;
  const int wv = tid >> 6;
  const int wm = (wv >> 1) * 64;
  const int wn = (wv & 1) * 64;
  const int mT = blockIdx.y << 7;
  const int nT = blockIdx.x << 7;
  const int kz = blockIdx.z * KCHUNK;

  const int r0 = tid >> 2, q0 = (tid & 3) << 3;
  const int r1 = r0 + 64;

  f32x4 acc[4][4];
  const f32x4 zz = {0.0f, 0.0f, 0.0f, 0.0f};
#pragma unroll
  for (int i = 0; i < 4; ++i)
#pragma unroll
    for (int j = 0; j < 4; ++j) acc[i][j] = zz;

  const size_t a0off = (size_t)(mT + r0) * K1 + q0;
  const size_t a1off = (size_t)(mT + r1) * K1 + q0;
  const size_t b0off = (size_t)(nT + r0) * K1 + q0;
  const size_t b1off = (size_t)(nT + r1) * K1 + q0;

  const int fm = lane & 15;
  const int fq = (lane >> 4) << 3;

  for (int kb = kz; kb < kz + KCHUNK; kb += 32) {
    const uint4 va0 = *(const uint4*)(Ahg + a0off + kb);
    const uint4 va1 = *(const uint4*)(Ahg + a1off + kb);
    const uint4 vl0 = *(const uint4*)(Alg + a0off + kb);
    const uint4 vl1 = *(const uint4*)(Alg + a1off + kb);
    const uint4 vb0 = *(const uint4*)(Bhg + b0off + kb);
    const uint4 vb1 = *(const uint4*)(Bhg + b1off + kb);
    const uint4 vm0 = *(const uint4*)(Blg + b0off + kb);
    const uint4 vm1 = *(const uint4*)(Blg + b1off + kb);
    *(uint4*)(&Ah[r0][q0]) = va0;
    *(uint4*)(&Ah[r1][q0]) = va1;
    *(uint4*)(&Al[r0][q0]) = vl0;
    *(uint4*)(&Al[r1][q0]) = vl1;
    *(uint4*)(&Bh[r0][q0]) = vb0;
    *(uint4*)(&Bh[r1][q0]) = vb1;
    *(uint4*)(&Bl[r0][q0]) = vm0;
    *(uint4*)(&Bl[r1][q0]) = vm1;
    __syncthreads();

    short8 fah[4], fal[4], fbh[4], fbl[4];
#pragma unroll
    for (int t = 0; t < 4; ++t) {
      fah[t] = *(const short8*)(&Ah[wm + t * 16 + fm][fq]);
      fal[t] = *(const short8*)(&Al[wm + t * 16 + fm][fq]);
      fbh[t] = *(const short8*)(&Bh[wn + t * 16 + fm][fq]);
      fbl[t] = *(const short8*)(&Bl[wn + t * 16 + fm][fq]);
    }
#pragma unroll
    for (int ti = 0; ti < 4; ++ti)
#pragma unroll
      for (int tj = 0; tj < 4; ++tj) {
        acc[ti][tj] = __builtin_amdgcn_mfma_f32_16x16x32_bf16(
            fah[ti], fbh[tj], acc[ti][tj], 0, 0, 0);
        acc[ti][tj] = __builtin_amdgcn_mfma_f32_16x16x32_bf16(
            fah[ti], fbl[tj], acc[ti][tj], 0, 0, 0);
        acc[ti][tj] = __builtin_amdgcn_mfma_f32_16x16x32_bf16(
            fal[ti], fbh[tj], acc[ti][tj], 0, 0, 0);
      }
    __syncthreads();
  }

  float* Cp = CP + (size_t)blockIdx.z * ((size_t)NROI * HID);
  const int crow = mT + wm + (lane >> 4) * 4;
  const int ccol = nT + wn + fm;
#pragma unroll
  for (int ti = 0; ti < 4; ++ti)
#pragma unroll
    for (int tj = 0; tj < 4; ++tj)
#pragma unroll
      for (int rr = 0; rr < 4; ++rr)
        Cp[(size_t)(crow + ti * 16 + rr) * HID + ccol + tj * 16] =
            acc[ti][tj][rr];
}

// ------------------------------------------------------- FC1 fallback (fp32)
__global__ __launch_bounds__(256) void gemm1_kernel(
    const float* __restrict__ A, const float* __restrict__ B,
    float* __restrict__ CP) {
  __shared__ float As[16][68];
  __shared__ float Bs[16][68];
  const int tid = threadIdx.x;
  const int mTile = blockIdx.y << 6;
  const int nTile = blockIdx.x << 6;
  const int k0 = blockIdx.z * KCHUNK;
  const int ty = tid >> 4, tx = tid & 15;
  const int ar = tid >> 2, ac = (tid & 3) << 2;
  const int br = tid >> 4, bcl = (tid & 15) << 2;
  float acc[4][4] = {};

  for (int kb = k0; kb < k0 + KCHUNK; kb += 16) {
    const float4 av = *(const float4*)(A + (size_t)(mTile + ar) * K1 + kb + ac);
    const float4 bv = *(const float4*)(B + (size_t)(kb + br) * HID + nTile + bcl);
    As[ac + 0][ar] = av.x; As[ac + 1][ar] = av.y;
    As[ac + 2][ar] = av.z; As[ac + 3][ar] = av.w;
    *(float4*)(&Bs[br][bcl]) = bv;
    __syncthreads();
#pragma unroll
    for (int kk = 0; kk < 16; ++kk) {
      const float4 a4 = *(const float4*)(&As[kk][ty << 2]);
      const float4 b4 = *(const float4*)(&Bs[kk][tx << 2]);
      const float aa[4] = {a4.x, a4.y, a4.z, a4.w};
      const float bb4[4] = {b4.x, b4.y, b4.z, b4.w};
#pragma unroll
      for (int i = 0; i < 4; ++i)
#pragma unroll
        for (int j = 0; j < 4; ++j)
          acc[i][j] = fmaf(aa[i], bb4[j], acc[i][j]);
    }
    __syncthreads();
  }
  float* Cp = CP + (size_t)blockIdx.z * (HID * NROI);
#pragma unroll
  for (int i = 0; i < 4; ++i) {
    *(float4*)(Cp + (size_t)(mTile + (ty << 2) + i) * HID + nTile + (tx << 2)) =
        make_float4(acc[i][0], acc[i][1], acc[i][2], acc[i][3]);
  }
}

// reduce 8 K-partials + bias + relu
__global__ __launch_bounds__(256) void bias_relu_kernel(
    const float* __restrict__ CP, const float* __restrict__ b1,
    float* __restrict__ H1) {
  const int idx = blockIdx.x * 256 + threadIdx.x;
  float v = b1[idx & (HID - 1)];
#pragma unroll
  for (int z = 0; z < ZSPLIT; ++z) v += CP[(size_t)z * (HID * NROI) + idx];
  H1[idx] = fmaxf(v, 0.0f);
}

// ------------------------------------------------------------- FC2 (K=1024)
__global__ __launch_bounds__(256) void gemm2_kernel(
    const float* __restrict__ A, const float* __restrict__ B,
    const float* __restrict__ bias, float* __restrict__ C) {
  __shared__ float As[16][68];
  __shared__ float Bs[16][68];
  const int tid = threadIdx.x;
  const int mTile = blockIdx.y << 6;
  const int nTile = blockIdx.x << 6;
  const int ty = tid >> 4, tx = tid & 15;
  const int ar = tid >> 2, ac = (tid & 3) << 2;
  const int br = tid >> 4, bcl = (tid & 15) << 2;
  float acc[4][4] = {};

  for (int kb = 0; kb < HID; kb += 16) {
    const float4 av = *(const float4*)(A + (size_t)(mTile + ar) * HID + kb + ac);
    const float4 bv = *(const float4*)(B + (size_t)(kb + br) * HID + nTile + bcl);
    As[ac + 0][ar] = av.x; As[ac + 1][ar] = av.y;
    As[ac + 2][ar] = av.z; As[ac + 3][ar] = av.w;
    *(float4*)(&Bs[br][bcl]) = bv;
    __syncthreads();
#pragma unroll
    for (int kk = 0; kk < 16; ++kk) {
      const float4 a4 = *(const float4*)(&As[kk][ty << 2]);
      const float4 b4 = *(const float4*)(&Bs[kk][tx << 2]);
      const float aa[4] = {a4.x, a4.y, a4.z, a4.w};
      const float bb4[4] = {b4.x, b4.y, b4.z, b4.w};
#pragma unroll
      for (int i = 0; i < 4; ++i)
#pragma unroll
        for (int j = 0; j < 4; ++j)
          acc[i][j] = fmaf(aa[i], bb4[j], acc[i][j]);
    }
    __syncthreads();
  }
#pragma unroll
  for (int i = 0; i < 4; ++i) {
#pragma unroll
    for (int j = 0; j < 4; ++j) {
      float v = acc[i][j] + bias[nTile + (tx << 2) + j];
      acc[i][j] = fmaxf(v, 0.0f);
    }
    *(float4*)(C + (size_t)(mTile + (ty << 2) + i) * HID + nTile + (tx << 2)) =
        make_float4(acc[i][0], acc[i][1], acc[i][2], acc[i][3]);
  }
}

// ------------------- heads: cls+box dots, softmax, decode, candidate arrays
__global__ __launch_bounds__(128) void heads_kernel(
    const float* __restrict__ H2m, const float* __restrict__ wc,
    const float* __restrict__ bc, const float* __restrict__ wb,
    const float* __restrict__ bb, const float* __restrict__ props,
    float* __restrict__ BX, float* __restrict__ NB,
    float* __restrict__ AR, float* __restrict__ LV) {
  const int r = blockIdx.x;
  const int tid = threadIdx.x;
  __shared__ float hrow[HID];
  __shared__ float vals[112];
  __shared__ float red[2];

  for (int i = tid; i < HID; i += 128) hrow[i] = H2m[(size_t)r * HID + i];
  __syncthreads();

  if (tid < 105) {
    float acc;
    if (tid < NCLS) {
      acc = bc[tid];
      for (int kk = 0; kk < HID; ++kk) acc = fmaf(hrow[kk], wc[kk * NCLS + tid], acc);
    } else {
      const int j = tid - NCLS;
      acc = bb[j];
      for (int kk = 0; kk < HID; ++kk) acc = fmaf(hrow[kk], wb[kk * (NCLS * 4) + j], acc);
    }
    vals[tid] = acc;
  }
  __syncthreads();

  if (tid == 0) {
    float m = vals[0];
    for (int k = 1; k < NCLS; ++k) m = fmaxf(m, vals[k]);
    float s = 0.0f;
    for (int k = 0; k < NCLS; ++k) s += expf(vals[k] - m);
    red[0] = m;
    red[1] = 1.0f / s;
  }
  __syncthreads();

  if (tid >= 1 && tid <= 20) {
    const int k = tid;
    const float prob = expf(vals[k] - red[0]) * red[1];

    const float px1 = props[r * 4 + 0], py1 = props[r * 4 + 1];
    const float px2 = props[r * 4 + 2], py2 = props[r * 4 + 3];
    const float pw = px2 - px1, ph = py2 - py1;
    const float pcx = px1 + 0.5f * pw, pcy = py1 + 0.5f * ph;

    const float dx = vals[NCLS + k * 4 + 0] / 10.0f;
    const float dy = vals[NCLS + k * 4 + 1] / 10.0f;
    const float dw = fminf(vals[NCLS + k * 4 + 2] / 5.0f, LOGMAX);
    const float dh = fminf(vals[NCLS + k * 4 + 3] / 5.0f, LOGMAX);

    const float cx = dx * pw + pcx, cy = dy * ph + pcy;
    const float w = expf(dw) * pw, h = expf(dh) * ph;
    float b0 = cx - 0.5f * w, b1c = cy - 0.5f * h;
    float b2 = cx + 0.5f * w, b3 = cy + 0.5f * h;
    b0 = fminf(fmaxf(b0, 0.0f), IMGSZ);
    b1c = fminf(fmaxf(b1c, 0.0f), IMGSZ);
    b2 = fminf(fmaxf(b2, 0.0f), IMGSZ);
    b3 = fminf(fmaxf(b3, 0.0f), IMGSZ);

    const float wv = b2 - b0, hv = b3 - b1c;
    const bool valid = (prob > 0.05f) && (wv >= 0.01f) && (hv >= 0.01f);

    const int n = r >> 9, s = r & 511;
    const int cand = s * 20 + (k - 1);
    const size_t bi = (size_t)n * MCAND + cand;
    const float off = (float)k * (IMGSZ + 1.0f);

    BX[bi * 4 + 0] = b0; BX[bi * 4 + 1] = b1c;
    BX[bi * 4 + 2] = b2; BX[bi * 4 + 3] = b3;
    const float n0 = b0 + off, n1 = b1c + off, n2 = b2 + off, n3 = b3 + off;
    NB[bi * 4 + 0] = n0; NB[bi * 4 + 1] = n1;
    NB[bi * 4 + 2] = n2; NB[bi * 4 + 3] = n3;
    AR[bi] = (n2 - n0) * (n3 - n1);
    LV[bi] = valid ? prob : -1.0f;
  }
}

// ------------------------------------------------------ greedy NMS per image
// 512 threads / 8 waves, 20 candidates per thread in registers.
// Per iteration: local argmax carrying box tuple -> DPP wave reduce ->
// lane63 publishes wave winner to parity-double-buffered LDS -> ONE barrier ->
// all threads reduce 8 wave entries + read winner box -> suppress.
// Outputs recorded in LDS, written once at the end. Early exit when max<=0.05.

template <int CTRL>
__device__ __forceinline__ void red_step(float& v, int& ix, float& a0, float& a1,
                                         float& a2, float& a3, float& aa) {
  const float tv = __int_as_float(__builtin_amdgcn_update_dpp(
      (int)0xC0000000, __float_as_int(v), CTRL, 0xf, 0xf, false));
  const int ti = __builtin_amdgcn_update_dpp(0x7fffffff, ix, CTRL, 0xf, 0xf, false);
  const float t0 = __int_as_float(__builtin_amdgcn_update_dpp(0, __float_as_int(a0), CTRL, 0xf, 0xf, false));
  const float t1 = __int_as_float(__builtin_amdgcn_update_dpp(0, __float_as_int(a1), CTRL, 0xf, 0xf, false));
  const float t2 = __int_as_float(__builtin_amdgcn_update_dpp(0, __float_as_int(a2), CTRL, 0xf, 0xf, false));
  const float t3 = __int_as_float(__builtin_amdgcn_update_dpp(0, __float_as_int(a3), CTRL, 0xf, 0xf, false));
  const float ta = __int_as_float(__builtin_amdgcn_update_dpp(0, __float_as_int(aa), CTRL, 0xf, 0xf, false));
  const bool take = (tv > v) || (tv == v && ti < ix);
  if (take) { v = tv; ix = ti; a0 = t0; a1 = t1; a2 = t2; a3 = t3; aa = ta; }
}

__global__ __launch_bounds__(512) void nms_kernel(
    const float* __restrict__ BX, const float* __restrict__ NB,
    const float* __restrict__ AR, const float* __restrict__ LV,
    float* __restrict__ out) {
  const int n = blockIdx.x;
  const int tid = threadIdx.x;          // 0..511
  const int wave = tid >> 6;            // 0..7
  const int lane = tid & 63;
  __shared__ float went[2][8][8];       // [parity][wave][b0,b1,b2,b3,val,idx,area,pad]
  __shared__ float svals[NDET];
  __shared__ int   sidx[NDET];
  const size_t base = (size_t)n * MCAND;
  const int cbase = tid * 20;

  float lv[20], nb0[20], nb1[20], nb2[20], nb3[20], ar[20];
#pragma unroll
  for (int j = 0; j < 20; ++j) {
    const int idx = cbase + j;
    lv[j] = LV[base + idx];
    const float4 b = *(const float4*)(NB + (base + idx) * 4);
    nb0[j] = b.x; nb1[j] = b.y; nb2[j] = b.z; nb3[j] = b.w;
    ar[j] = AR[base + idx];
  }

  int dend = NDET;
  for (int d = 0; d < NDET; ++d) {
    // --- local argmax over 20 register candidates, carrying the box tuple
    float bv = lv[0];
    int bj = 0;
    float c0 = nb0[0], c1 = nb1[0], c2 = nb2[0], c3 = nb3[0], ca = ar[0];
#pragma unroll
    for (int j = 1; j < 20; ++j) {
      if (lv[j] > bv) {
        bv = lv[j]; bj = j;
        c0 = nb0[j]; c1 = nb1[j]; c2 = nb2[j]; c3 = nb3[j]; ca = ar[j];
      }
    }
    int gix = cbase + bj;

    // --- intra-wave DPP reduce of (val, idx, box4, area)
    red_step<0x111>(bv, gix, c0, c1, c2, c3, ca);  // row_shr:1
    red_step<0x112>(bv, gix, c0, c1, c2, c3, ca);  // row_shr:2
    red_step<0x114>(bv, gix, c0, c1, c2, c3, ca);  // row_shr:4
    red_step<0x118>(bv, gix, c0, c1, c2, c3, ca);  // row_shr:8
    red_step<0x142>(bv, gix, c0, c1, c2, c3, ca);  // row_bcast:15
    red_step<0x143>(bv, gix, c0, c1, c2, c3, ca);  // row_bcast:31  -> lane 63

    const int par = d & 1;
    if (lane == 63) {
      *(float4*)(&went[par][wave][0]) = make_float4(c0, c1, c2, c3);
      *(float4*)(&went[par][wave][4]) =
          make_float4(bv, __int_as_float(gix), ca, 0.0f);
    }
    __syncthreads();

    // --- every thread reduces the 8 wave winners
    float wvv = -2.0f;
    int wjj = 0x7fffffff, ww = 0;
#pragma unroll
    for (int w = 0; w < 8; ++w) {
      const float2 p = *(const float2*)(&went[par][w][4]);
      const int ti = __float_as_int(p.y);
      if (p.x > wvv || (p.x == wvv && ti < wjj)) { wvv = p.x; wjj = ti; ww = w; }
    }
    if (tid == 0) { svals[d] = wvv; sidx[d] = wjj; }
    if (wvv <= 0.05f) { dend = d; break; }   // uniform: all-live == -1 hereafter

    const float4 wb4 = *(const float4*)(&went[par][ww][0]);
    const float wa = went[par][ww][6];

    // --- suppression (bit-identical IoU arithmetic to the reference)
#pragma unroll
    for (int j = 0; j < 20; ++j) {
      const float xx1 = fmaxf(wb4.x, nb0[j]);
      const float yy1 = fmaxf(wb4.y, nb1[j]);
      const float xx2 = fminf(wb4.z, nb2[j]);
      const float yy2 = fminf(wb4.w, nb3[j]);
      const float inter = fmaxf(xx2 - xx1, 0.0f) * fmaxf(yy2 - yy1, 0.0f);
      const float iou = inter / (wa + ar[j] - inter + 1e-9f);
      if (iou > 0.5f) lv[j] = -1.0f;
    }
  }

  __syncthreads();
  if (tid < NDET) {
    const int i = tid;
    float sv = 0.0f;
    int si = 0;
    if (i < dend) { sv = svals[i]; si = sidx[i]; }
    const bool keep = sv > 0.05f;
    float4 bx4 = make_float4(0.0f, 0.0f, 0.0f, 0.0f);
    if (keep) bx4 = *(const float4*)(BX + (base + si) * 4);
    out[(n * NDET + i) * 4 + 0] = bx4.x;
    out[(n * NDET + i) * 4 + 1] = bx4.y;
    out[(n * NDET + i) * 4 + 2] = bx4.z;
    out[(n * NDET + i) * 4 + 3] = bx4.w;
    out[NIMG * NDET * 4 + n * NDET + i] = keep ? sv : 0.0f;
    out[NIMG * NDET * 4 + NIMG * NDET + n * NDET + i] =
        keep ? (float)(1 + (si % 20)) : 0.0f;
  }
}

// ---------------------------------------------------------------- launcher
extern "C" void kernel_launch(void* const* d_in, const int* in_sizes, int n_in,
                              void* d_out, int out_size, void* d_ws, size_t ws_size,
                              hipStream_t stream) {
  const float* features  = (const float*)d_in[0];
  const float* proposals = (const float*)d_in[1];
  const float* w1 = (const float*)d_in[2];
  const float* b1 = (const float*)d_in[3];
  const float* w2 = (const float*)d_in[4];
  const float* b2 = (const float*)d_in[5];
  const float* wc = (const float*)d_in[6];
  const float* bc = (const float*)d_in[7];
  const float* wb = (const float*)d_in[8];
  const float* bb = (const float*)d_in[9];

  const size_t XE = (size_t)NROI * K1;
  const size_t WE = (size_t)K1 * HID;
  const size_t FLOATS_TAIL =
      (size_t)ZSPLIT * NROI * HID + 2 * (size_t)NROI * HID + (size_t)NIMG * MCAND * 10;
  const size_t NEED = (XE * 2 + WE * 2) * sizeof(u16) + FLOATS_TAIL * sizeof(float);

  if (ws_size >= NEED) {
    u16* Xhi = (u16*)d_ws;
    u16* Xlo = Xhi + XE;
    u16* Wh  = Xlo + XE;
    u16* Wl  = Wh + WE;
    float* CP  = (float*)(Wl + WE);
    float* H1  = CP + (size_t)ZSPLIT * NROI * HID;
    float* H2  = H1 + (size_t)NROI * HID;
    float* BXc = H2 + (size_t)NROI * HID;
    float* NBc = BXc + (size_t)NIMG * MCAND * 4;
    float* ARc = NBc + (size_t)NIMG * MCAND * 4;
    float* LVc = ARc + (size_t)NIMG * MCAND;

    convw1_kernel<<<dim3(K1 / 64, HID / 64), 256, 0, stream>>>(w1, Wh, Wl);
    roi_kernel<true><<<NROI, 256, 0, stream>>>(features, proposals, nullptr, Xhi, Xlo);
    gemm1_mfma<<<dim3(8, 8, ZSPLIT), 256, 0, stream>>>(Xhi, Xlo, Wh, Wl, CP);
    bias_relu_kernel<<<(NROI * HID) / 256, 256, 0, stream>>>(CP, b1, H1);
    gemm2_kernel<<<dim3(16, 16), 256, 0, stream>>>(H1, w2, b2, H2);
    heads_kernel<<<NROI, 128, 0, stream>>>(H2, wc, bc, wb, bb, proposals,
                                           BXc, NBc, ARc, LVc);
    nms_kernel<<<NIMG, 512, 0, stream>>>(BXc, NBc, ARc, LVc, (float*)d_out);
  } else {
    float* ws = (float*)d_ws;
    float* X   = ws;
    float* CP  = X + XE;
    float* H1  = CP + (size_t)ZSPLIT * NROI * HID;
    float* H2  = H1 + (size_t)NROI * HID;
    float* BXc = H2 + (size_t)NROI * HID;
    float* NBc = BXc + (size_t)NIMG * MCAND * 4;
    float* ARc = NBc + (size_t)NIMG * MCAND * 4;
    float* LVc = ARc + (size_t)NIMG * MCAND;

    roi_kernel<false><<<NROI, 256, 0, stream>>>(features, proposals, X, nullptr, nullptr);
    gemm1_kernel<<<dim3(16, 16, ZSPLIT), 256, 0, stream>>>(X, w1, CP);
    bias_relu_kernel<<<(NROI * HID) / 256, 256, 0, stream>>>(CP, b1, H1);
    gemm2_kernel<<<dim3(16, 16), 256, 0, stream>>>(H1, w2, b2, H2);
    heads_kernel<<<NROI, 128, 0, stream>>>(H2, wc, bc, wb, bb, proposals,
                                           BXc, NBc, ARc, LVc);
    nms_kernel<<<NIMG, 512, 0, stream>>>(BXc, NBc, ARc, LVc, (float*)d_out);
  }
}

// Round 5
// 1041.155 us; speedup vs baseline: 1.6772x; 1.0856x over previous
//
#include <hip/hip_runtime.h>
#include <cmath>

// Problem constants (N=2, S=512, C=512, H=W=50, OUT=7, RATIO=2)
#define NIMG 2
#define SPROP 512
#define NROI 1024          // NIMG*SPROP
#define CCH 512
#define FH 50
#define FW 50
#define K1 25088           // CCH*7*7
#define HID 1024
#define NCLS 21
#define NDET 100
#define IMGSZ 800.0f
#define LOGMAX 4.135166556742356f   // log(1000/16)
#define MCAND 10240        // SPROP*(NCLS-1)
#define ZSPLIT 8
#define KCHUNK 3136        // K1/ZSPLIT
#define BCAP 4096          // boxes kept in LDS; i>=BCAP falls back to global

typedef unsigned short u16;
typedef __attribute__((ext_vector_type(8))) short short8;
typedef __attribute__((ext_vector_type(4))) float f32x4;

__device__ __forceinline__ u16 f2bf(float x) {        // RTNE fp32 -> bf16
  unsigned int u = __float_as_uint(x);
  u += 0x7fffu + ((u >> 16) & 1u);
  return (u16)(u >> 16);
}
__device__ __forceinline__ float bf2f(u16 h) {
  return __uint_as_float(((unsigned int)h) << 16);
}

// ------------------------------------------------------------ ROI align
template <bool BF16OUT>
__global__ __launch_bounds__(256) void roi_kernel(
    const float* __restrict__ feat, const float* __restrict__ props,
    float* __restrict__ X, u16* __restrict__ Xhi, u16* __restrict__ Xlo) {
  const int r = blockIdx.x;
  const int n = r >> 9;
  const int tid = threadIdx.x;
  __shared__ float tile[32][256];   // 32 ch x (16x16 px) = 32 KB
  __shared__ int sy0[14], sy1[14], sx0[14], sx1[14];
  __shared__ float sly[14], slx[14], svy[14], svx[14];

  const float p0 = props[r * 4 + 0] * 0.0625f;
  const float p1 = props[r * 4 + 1] * 0.0625f;
  const float p2 = props[r * 4 + 2] * 0.0625f;
  const float p3 = props[r * 4 + 3] * 0.0625f;
  const float bw = fmaxf(p2 - p0, 1.0f) / 7.0f;
  const float bh = fmaxf(p3 - p1, 1.0f) / 7.0f;

  if (tid < 14) {
    const int j = tid;
    const float g = (float)(j >> 1) + ((float)(j & 1) + 0.5f) * 0.5f;
    float y = p1 + g * bh;
    svy[j] = (y > -1.0f && y < (float)FH) ? 1.0f : 0.0f;
    float yc = fminf(fmaxf(y, 0.0f), (float)(FH - 1));
    int y0 = (int)floorf(yc);
    sy0[j] = y0; sy1[j] = min(y0 + 1, FH - 1); sly[j] = yc - (float)y0;
    float x = p0 + g * bw;
    svx[j] = (x > -1.0f && x < (float)FW) ? 1.0f : 0.0f;
    float xc = fminf(fmaxf(x, 0.0f), (float)(FW - 1));
    int x0 = (int)floorf(xc);
    sx0[j] = x0; sx1[j] = min(x0 + 1, FW - 1); slx[j] = xc - (float)x0;
  }
  __syncthreads();
  const int ymin = sy0[0], xmin = sx0[0];
  const float* fb = feat + (size_t)n * CCH * (FH * FW);

  for (int cc = 0; cc < 16; ++cc) {
    const int c0 = cc * 32;
#pragma unroll
    for (int e = 0; e < 32; ++e) {
      const int idx = tid + e * 256;
      const int c = idx >> 8, p = idx & 255;
      const int gy = min(ymin + (p >> 4), FH - 1);
      const int gx = min(xmin + (p & 15), FW - 1);
      tile[c][p] = fb[(size_t)(c0 + c) * (FH * FW) + gy * FW + gx];
    }
    __syncthreads();
#pragma unroll
    for (int e = 0; e < 7; ++e) {
      const int idx = tid + e * 256;
      if (idx < 1568) {
        const int c = idx / 49;
        const int s = idx - c * 49;
        const int oy = s / 7, ox = s - (s / 7) * 7;
        float acc = 0.0f;
#pragma unroll
        for (int sy = 0; sy < 2; ++sy) {
          const int yj = oy * 2 + sy;
          const int py0 = sy0[yj] - ymin, py1 = sy1[yj] - ymin;
          const float ly = sly[yj], vy = svy[yj];
#pragma unroll
          for (int sx = 0; sx < 2; ++sx) {
            const int xj = ox * 2 + sx;
            const int px0 = sx0[xj] - xmin, px1 = sx1[xj] - xmin;
            const float lx = slx[xj], vx = svx[xj];
            const float f00 = tile[c][py0 * 16 + px0];
            const float f01 = tile[c][py0 * 16 + px1];
            const float f10 = tile[c][py1 * 16 + px0];
            const float f11 = tile[c][py1 * 16 + px1];
            float v = f00 * (1.0f - ly) * (1.0f - lx) + f01 * (1.0f - ly) * lx +
                      f10 * ly * (1.0f - lx) + f11 * ly * lx;
            acc += v * (vy * vx);
          }
        }
        const float v = acc * 0.25f;
        const size_t k = (size_t)r * K1 + (size_t)(c0 + c) * 49 + s;
        if (BF16OUT) {
          const u16 h = f2bf(v);
          Xhi[k] = h;
          Xlo[k] = f2bf(v - bf2f(h));
        } else {
          X[k] = v;
        }
      }
    }
    __syncthreads();
  }
}

// ------------------------- w1 -> hi/lo bf16, transposed to [n][k]
__global__ __launch_bounds__(256) void convw1_kernel(
    const float* __restrict__ w1, u16* __restrict__ Wh, u16* __restrict__ Wl) {
  __shared__ u16 sh[64][65], sl[64][65];
  const int k0 = blockIdx.x * 64;
  const int n0 = blockIdx.y * 64;
  const int t = threadIdx.x;
#pragma unroll
  for (int e = 0; e < 16; ++e) {
    const int idx = t + e * 256;
    const int kl = idx >> 6, nl = idx & 63;
    const float v = w1[(size_t)(k0 + kl) * HID + n0 + nl];
    const u16 h = f2bf(v);
    sh[kl][nl] = h;
    sl[kl][nl] = f2bf(v - bf2f(h));
  }
  __syncthreads();
#pragma unroll
  for (int e = 0; e < 16; ++e) {
    const int idx = t + e * 256;
    const int nl = idx >> 6, kl = idx & 63;
    Wh[(size_t)(n0 + nl) * K1 + k0 + kl] = sh[kl][nl];
    Wl[(size_t)(n0 + nl) * K1 + k0 + kl] = sl[kl][nl];
  }
}

// ------------------------------- FC1: split-bf16 MFMA GEMM, K-split z=8
__global__ __launch_bounds__(256, 2) void gemm1_mfma(
    const u16* __restrict__ Ahg, const u16* __restrict__ Alg,
    const u16* __restrict__ Bhg, const u16* __restrict__ Blg,
    float* __restrict__ CP) {
  __shared__ u16 Ah[128][40], Al[128][40], Bh[128][40], Bl[128][40];
  const int tid = threadIdx.x;
  const int lane = tid & 63;
  const int wv = tid >> 6;
  const int wm = (wv >> 1) * 64;
  const int wn = (wv & 1) * 64;
  const int mT = blockIdx.y << 7;
  const int nT = blockIdx.x << 7;
  const int kz = blockIdx.z * KCHUNK;

  const int r0 = tid >> 2, q0 = (tid & 3) << 3;
  const int r1 = r0 + 64;

  f32x4 acc[4][4];
  const f32x4 zz = {0.0f, 0.0f, 0.0f, 0.0f};
#pragma unroll
  for (int i = 0; i < 4; ++i)
#pragma unroll
    for (int j = 0; j < 4; ++j) acc[i][j] = zz;

  const size_t a0off = (size_t)(mT + r0) * K1 + q0;
  const size_t a1off = (size_t)(mT + r1) * K1 + q0;
  const size_t b0off = (size_t)(nT + r0) * K1 + q0;
  const size_t b1off = (size_t)(nT + r1) * K1 + q0;

  const int fm = lane & 15;
  const int fq = (lane >> 4) << 3;

  for (int kb = kz; kb < kz + KCHUNK; kb += 32) {
    const uint4 va0 = *(const uint4*)(Ahg + a0off + kb);
    const uint4 va1 = *(const uint4*)(Ahg + a1off + kb);
    const uint4 vl0 = *(const uint4*)(Alg + a0off + kb);
    const uint4 vl1 = *(const uint4*)(Alg + a1off + kb);
    const uint4 vb0 = *(const uint4*)(Bhg + b0off + kb);
    const uint4 vb1 = *(const uint4*)(Bhg + b1off + kb);
    const uint4 vm0 = *(const uint4*)(Blg + b0off + kb);
    const uint4 vm1 = *(const uint4*)(Blg + b1off + kb);
    *(uint4*)(&Ah[r0][q0]) = va0;
    *(uint4*)(&Ah[r1][q0]) = va1;
    *(uint4*)(&Al[r0][q0]) = vl0;
    *(uint4*)(&Al[r1][q0]) = vl1;
    *(uint4*)(&Bh[r0][q0]) = vb0;
    *(uint4*)(&Bh[r1][q0]) = vb1;
    *(uint4*)(&Bl[r0][q0]) = vm0;
    *(uint4*)(&Bl[r1][q0]) = vm1;
    __syncthreads();

    short8 fah[4], fal[4], fbh[4], fbl[4];
#pragma unroll
    for (int t = 0; t < 4; ++t) {
      fah[t] = *(const short8*)(&Ah[wm + t * 16 + fm][fq]);
      fal[t] = *(const short8*)(&Al[wm + t * 16 + fm][fq]);
      fbh[t] = *(const short8*)(&Bh[wn + t * 16 + fm][fq]);
      fbl[t] = *(const short8*)(&Bl[wn + t * 16 + fm][fq]);
    }
#pragma unroll
    for (int ti = 0; ti < 4; ++ti)
#pragma unroll
      for (int tj = 0; tj < 4; ++tj) {
        acc[ti][tj] = __builtin_amdgcn_mfma_f32_16x16x32_bf16(
            fah[ti], fbh[tj], acc[ti][tj], 0, 0, 0);
        acc[ti][tj] = __builtin_amdgcn_mfma_f32_16x16x32_bf16(
            fah[ti], fbl[tj], acc[ti][tj], 0, 0, 0);
        acc[ti][tj] = __builtin_amdgcn_mfma_f32_16x16x32_bf16(
            fal[ti], fbh[tj], acc[ti][tj], 0, 0, 0);
      }
    __syncthreads();
  }

  float* Cp = CP + (size_t)blockIdx.z * ((size_t)NROI * HID);
  const int crow = mT + wm + (lane >> 4) * 4;
  const int ccol = nT + wn + fm;
#pragma unroll
  for (int ti = 0; ti < 4; ++ti)
#pragma unroll
    for (int tj = 0; tj < 4; ++tj)
#pragma unroll
      for (int rr = 0; rr < 4; ++rr)
        Cp[(size_t)(crow + ti * 16 + rr) * HID + ccol + tj * 16] =
            acc[ti][tj][rr];
}

// ------------------------------------------------------- FC1 fallback (fp32)
__global__ __launch_bounds__(256) void gemm1_kernel(
    const float* __restrict__ A, const float* __restrict__ B,
    float* __restrict__ CP) {
  __shared__ float As[16][68];
  __shared__ float Bs[16][68];
  const int tid = threadIdx.x;
  const int mTile = blockIdx.y << 6;
  const int nTile = blockIdx.x << 6;
  const int k0 = blockIdx.z * KCHUNK;
  const int ty = tid >> 4, tx = tid & 15;
  const int ar = tid >> 2, ac = (tid & 3) << 2;
  const int br = tid >> 4, bcl = (tid & 15) << 2;
  float acc[4][4] = {};

  for (int kb = k0; kb < k0 + KCHUNK; kb += 16) {
    const float4 av = *(const float4*)(A + (size_t)(mTile + ar) * K1 + kb + ac);
    const float4 bv = *(const float4*)(B + (size_t)(kb + br) * HID + nTile + bcl);
    As[ac + 0][ar] = av.x; As[ac + 1][ar] = av.y;
    As[ac + 2][ar] = av.z; As[ac + 3][ar] = av.w;
    *(float4*)(&Bs[br][bcl]) = bv;
    __syncthreads();
#pragma unroll
    for (int kk = 0; kk < 16; ++kk) {
      const float4 a4 = *(const float4*)(&As[kk][ty << 2]);
      const float4 b4 = *(const float4*)(&Bs[kk][tx << 2]);
      const float aa[4] = {a4.x, a4.y, a4.z, a4.w};
      const float bb4[4] = {b4.x, b4.y, b4.z, b4.w};
#pragma unroll
      for (int i = 0; i < 4; ++i)
#pragma unroll
        for (int j = 0; j < 4; ++j)
          acc[i][j] = fmaf(aa[i], bb4[j], acc[i][j]);
    }
    __syncthreads();
  }
  float* Cp = CP + (size_t)blockIdx.z * (HID * NROI);
#pragma unroll
  for (int i = 0; i < 4; ++i) {
    *(float4*)(Cp + (size_t)(mTile + (ty << 2) + i) * HID + nTile + (tx << 2)) =
        make_float4(acc[i][0], acc[i][1], acc[i][2], acc[i][3]);
  }
}

// reduce 8 K-partials + bias + relu
__global__ __launch_bounds__(256) void bias_relu_kernel(
    const float* __restrict__ CP, const float* __restrict__ b1,
    float* __restrict__ H1) {
  const int idx = blockIdx.x * 256 + threadIdx.x;
  float v = b1[idx & (HID - 1)];
#pragma unroll
  for (int z = 0; z < ZSPLIT; ++z) v += CP[(size_t)z * (HID * NROI) + idx];
  H1[idx] = fmaxf(v, 0.0f);
}

// ------------------------------------------------------------- FC2 (K=1024)
__global__ __launch_bounds__(256) void gemm2_kernel(
    const float* __restrict__ A, const float* __restrict__ B,
    const float* __restrict__ bias, float* __restrict__ C) {
  __shared__ float As[16][68];
  __shared__ float Bs[16][68];
  const int tid = threadIdx.x;
  const int mTile = blockIdx.y << 6;
  const int nTile = blockIdx.x << 6;
  const int ty = tid >> 4, tx = tid & 15;
  const int ar = tid >> 2, ac = (tid & 3) << 2;
  const int br = tid >> 4, bcl = (tid & 15) << 2;
  float acc[4][4] = {};

  for (int kb = 0; kb < HID; kb += 16) {
    const float4 av = *(const float4*)(A + (size_t)(mTile + ar) * HID + kb + ac);
    const float4 bv = *(const float4*)(B + (size_t)(kb + br) * HID + nTile + bcl);
    As[ac + 0][ar] = av.x; As[ac + 1][ar] = av.y;
    As[ac + 2][ar] = av.z; As[ac + 3][ar] = av.w;
    *(float4*)(&Bs[br][bcl]) = bv;
    __syncthreads();
#pragma unroll
    for (int kk = 0; kk < 16; ++kk) {
      const float4 a4 = *(const float4*)(&As[kk][ty << 2]);
      const float4 b4 = *(const float4*)(&Bs[kk][tx << 2]);
      const float aa[4] = {a4.x, a4.y, a4.z, a4.w};
      const float bb4[4] = {b4.x, b4.y, b4.z, b4.w};
#pragma unroll
      for (int i = 0; i < 4; ++i)
#pragma unroll
        for (int j = 0; j < 4; ++j)
          acc[i][j] = fmaf(aa[i], bb4[j], acc[i][j]);
    }
    __syncthreads();
  }
#pragma unroll
  for (int i = 0; i < 4; ++i) {
#pragma unroll
    for (int j = 0; j < 4; ++j) {
      float v = acc[i][j] + bias[nTile + (tx << 2) + j];
      acc[i][j] = fmaxf(v, 0.0f);
    }
    *(float4*)(C + (size_t)(mTile + (ty << 2) + i) * HID + nTile + (tx << 2)) =
        make_float4(acc[i][0], acc[i][1], acc[i][2], acc[i][3]);
  }
}

// ------------------- heads: cls+box dots, softmax, decode, candidate arrays
__global__ __launch_bounds__(128) void heads_kernel(
    const float* __restrict__ H2m, const float* __restrict__ wc,
    const float* __restrict__ bc, const float* __restrict__ wb,
    const float* __restrict__ bb, const float* __restrict__ props,
    float* __restrict__ BX, float* __restrict__ NB,
    float* __restrict__ AR, float* __restrict__ LV) {
  const int r = blockIdx.x;
  const int tid = threadIdx.x;
  __shared__ float hrow[HID];
  __shared__ float vals[112];
  __shared__ float red[2];

  for (int i = tid; i < HID; i += 128) hrow[i] = H2m[(size_t)r * HID + i];
  __syncthreads();

  if (tid < 105) {
    float acc;
    if (tid < NCLS) {
      acc = bc[tid];
      for (int kk = 0; kk < HID; ++kk) acc = fmaf(hrow[kk], wc[kk * NCLS + tid], acc);
    } else {
      const int j = tid - NCLS;
      acc = bb[j];
      for (int kk = 0; kk < HID; ++kk) acc = fmaf(hrow[kk], wb[kk * (NCLS * 4) + j], acc);
    }
    vals[tid] = acc;
  }
  __syncthreads();

  if (tid == 0) {
    float m = vals[0];
    for (int k = 1; k < NCLS; ++k) m = fmaxf(m, vals[k]);
    float s = 0.0f;
    for (int k = 0; k < NCLS; ++k) s += expf(vals[k] - m);
    red[0] = m;
    red[1] = 1.0f / s;
  }
  __syncthreads();

  if (tid >= 1 && tid <= 20) {
    const int k = tid;
    const float prob = expf(vals[k] - red[0]) * red[1];

    const float px1 = props[r * 4 + 0], py1 = props[r * 4 + 1];
    const float px2 = props[r * 4 + 2], py2 = props[r * 4 + 3];
    const float pw = px2 - px1, ph = py2 - py1;
    const float pcx = px1 + 0.5f * pw, pcy = py1 + 0.5f * ph;

    const float dx = vals[NCLS + k * 4 + 0] / 10.0f;
    const float dy = vals[NCLS + k * 4 + 1] / 10.0f;
    const float dw = fminf(vals[NCLS + k * 4 + 2] / 5.0f, LOGMAX);
    const float dh = fminf(vals[NCLS + k * 4 + 3] / 5.0f, LOGMAX);

    const float cx = dx * pw + pcx, cy = dy * ph + pcy;
    const float w = expf(dw) * pw, h = expf(dh) * ph;
    float b0 = cx - 0.5f * w, b1c = cy - 0.5f * h;
    float b2 = cx + 0.5f * w, b3 = cy + 0.5f * h;
    b0 = fminf(fmaxf(b0, 0.0f), IMGSZ);
    b1c = fminf(fmaxf(b1c, 0.0f), IMGSZ);
    b2 = fminf(fmaxf(b2, 0.0f), IMGSZ);
    b3 = fminf(fmaxf(b3, 0.0f), IMGSZ);

    const float wv = b2 - b0, hv = b3 - b1c;
    const bool valid = (prob > 0.05f) && (wv >= 0.01f) && (hv >= 0.01f);

    const int n = r >> 9, s = r & 511;
    const int cand = s * 20 + (k - 1);
    const size_t bi = (size_t)n * MCAND + cand;
    const float off = (float)k * (IMGSZ + 1.0f);

    BX[bi * 4 + 0] = b0; BX[bi * 4 + 1] = b1c;
    BX[bi * 4 + 2] = b2; BX[bi * 4 + 3] = b3;
    const float n0 = b0 + off, n1 = b1c + off, n2 = b2 + off, n3 = b3 + off;
    NB[bi * 4 + 0] = n0; NB[bi * 4 + 1] = n1;
    NB[bi * 4 + 2] = n2; NB[bi * 4 + 3] = n3;
    AR[bi] = (n2 - n0) * (n3 - n1);
    LV[bi] = valid ? prob : -1.0f;
  }
}

// ------------------------------------------------------ greedy NMS per image
// v4 (defensive rewrite of v3):
//  - compaction of valid candidates into LDS (order-preserving, same tie-break)
//  - FIXED 100 iterations, no break/early-exit, svals/sidx written every iter
//  - act-guard: when block winner <= 0.05 nothing dereferences wp (no OOB);
//    suppression skipped (provably no effect on outputs: max is non-increasing)
//  - wave reduce via __shfl_down (round-2-proven idiom), lane0 publishes
__global__ __launch_bounds__(1024) void nms_kernel(
    const float* __restrict__ BX, const float* __restrict__ NB,
    const float* __restrict__ AR, const float* __restrict__ LV,
    float* __restrict__ out) {
  const int n = blockIdx.x;
  const int tid = threadIdx.x;          // 0..1023
  const int wave = tid >> 6;            // 0..15
  const int lane = tid & 63;
  __shared__ float  cs[MCAND];          // 40 KB compacted scores (-1 = dead)
  __shared__ float4 cb[BCAP];           // 64 KB compacted boxes
  __shared__ u16    cidx[MCAND];        // 20 KB original indices
  __shared__ float  wredv[16];
  __shared__ int    wredp[16];
  __shared__ int    wtot[16];
  __shared__ float  svals[NDET];
  __shared__ int    sidx[NDET];
  const size_t base = (size_t)n * MCAND;
  const int cbase = tid * 10;

  // ---- phase 1: stable compaction (order preserved => same tie-break)
  float slv[10];
  int cnt = 0;
#pragma unroll
  for (int j = 0; j < 10; ++j) {
    slv[j] = LV[base + cbase + j];
    cnt += (slv[j] > 0.0f) ? 1 : 0;
  }
  int inc = cnt;
#pragma unroll
  for (int off = 1; off < 64; off <<= 1) {
    const int u = __shfl_up(inc, off);
    if (lane >= off) inc += u;
  }
  if (lane == 63) wtot[wave] = inc;
  __syncthreads();
  int wbase = 0, V = 0;
#pragma unroll
  for (int w = 0; w < 16; ++w) {
    const int t = wtot[w];
    if (w < wave) wbase += t;
    V += t;
  }
  int pos = wbase + (inc - cnt);
#pragma unroll
  for (int j = 0; j < 10; ++j) {
    if (slv[j] > 0.0f) {
      cs[pos] = slv[j];
      cidx[pos] = (u16)(cbase + j);
      if (pos < BCAP) cb[pos] = *(const float4*)(NB + (base + cbase + j) * 4);
      ++pos;
    }
  }
  __syncthreads();

  // ---- greedy loop: fixed NDET iterations
  for (int d = 0; d < NDET; ++d) {
    // local argmax over strided subset (strict > keeps smallest pos)
    float bv = -2.0f;
    int bp = 0x7fffffff;
    for (int i = tid; i < V; i += 1024) {
      const float s = cs[i];
      if (s > bv) { bv = s; bp = i; }
    }
    // wave reduce (winner -> lane 0)
#pragma unroll
    for (int off = 32; off > 0; off >>= 1) {
      const float ov = __shfl_down(bv, off);
      const int op = __shfl_down(bp, off);
      if (ov > bv || (ov == bv && op < bp)) { bv = ov; bp = op; }
    }
    if (lane == 0) { wredv[wave] = bv; wredp[wave] = bp; }
    __syncthreads();

    // block winner (computed redundantly by all threads; uniform)
    float wv = -2.0f;
    int wp = 0x7fffffff;
#pragma unroll
    for (int w = 0; w < 16; ++w) {
      const float v = wredv[w];
      const int p = wredp[w];
      if (v > wv || (v == wv && p < wp)) { wv = v; wp = p; }
    }
    const bool act = wv > 0.05f;   // uniform; when false, wp is NOT dereferenced

    if (tid == 0) {
      svals[d] = act ? wv : -1.0f;
      sidx[d] = act ? (int)cidx[wp] : 0;
    }

    if (act) {
      // wp < V guaranteed: any score > 0.05 lives at a real compacted pos
      float4 wb;
      if (wp < BCAP) wb = cb[wp];
      else wb = *(const float4*)(NB + (base + (int)cidx[wp]) * 4);
      const float wa = (wb.z - wb.x) * (wb.w - wb.y);

      for (int i = tid; i < V; i += 1024) {
        const float4 b = (i < BCAP)
            ? cb[i]
            : *(const float4*)(NB + (base + (int)cidx[i]) * 4);
        const float xx1 = fmaxf(wb.x, b.x);
        const float yy1 = fmaxf(wb.y, b.y);
        const float xx2 = fminf(wb.z, b.z);
        const float yy2 = fminf(wb.w, b.w);
        const float inter = fmaxf(xx2 - xx1, 0.0f) * fmaxf(yy2 - yy1, 0.0f);
        const float ar_i = (b.z - b.x) * (b.w - b.y);
        const float iou = inter / (wa + ar_i - inter + 1e-9f);
        if (iou > 0.5f) cs[i] = -1.0f;
      }
    }
    __syncthreads();
  }

  // ---- writeout (svals/sidx fully written for all d)
  if (tid < NDET) {
    const int i = tid;
    const float sv = svals[i];
    const int si = sidx[i];
    const bool keep = sv > 0.05f;
    float4 bx4 = make_float4(0.0f, 0.0f, 0.0f, 0.0f);
    if (keep) bx4 = *(const float4*)(BX + (base + si) * 4);
    out[(n * NDET + i) * 4 + 0] = bx4.x;
    out[(n * NDET + i) * 4 + 1] = bx4.y;
    out[(n * NDET + i) * 4 + 2] = bx4.z;
    out[(n * NDET + i) * 4 + 3] = bx4.w;
    out[NIMG * NDET * 4 + n * NDET + i] = keep ? sv : 0.0f;
    out[NIMG * NDET * 4 + NIMG * NDET + n * NDET + i] =
        keep ? (float)(1 + (si % 20)) : 0.0f;
  }
}

// ---------------------------------------------------------------- launcher
extern "C" void kernel_launch(void* const* d_in, const int* in_sizes, int n_in,
                              void* d_out, int out_size, void* d_ws, size_t ws_size,
                              hipStream_t stream) {
  const float* features  = (const float*)d_in[0];
  const float* proposals = (const float*)d_in[1];
  const float* w1 = (const float*)d_in[2];
  const float* b1 = (const float*)d_in[3];
  const float* w2 = (const float*)d_in[4];
  const float* b2 = (const float*)d_in[5];
  const float* wc = (const float*)d_in[6];
  const float* bc = (const float*)d_in[7];
  const float* wb = (const float*)d_in[8];
  const float* bb = (const float*)d_in[9];

  const size_t XE = (size_t)NROI * K1;
  const size_t WE = (size_t)K1 * HID;
  const size_t FLOATS_TAIL =
      (size_t)ZSPLIT * NROI * HID + 2 * (size_t)NROI * HID + (size_t)NIMG * MCAND * 10;
  const size_t NEED = (XE * 2 + WE * 2) * sizeof(u16) + FLOATS_TAIL * sizeof(float);

  if (ws_size >= NEED) {
    u16* Xhi = (u16*)d_ws;
    u16* Xlo = Xhi + XE;
    u16* Wh  = Xlo + XE;
    u16* Wl  = Wh + WE;
    float* CP  = (float*)(Wl + WE);
    float* H1  = CP + (size_t)ZSPLIT * NROI * HID;
    float* H2  = H1 + (size_t)NROI * HID;
    float* BXc = H2 + (size_t)NROI * HID;
    float* NBc = BXc + (size_t)NIMG * MCAND * 4;
    float* ARc = NBc + (size_t)NIMG * MCAND * 4;
    float* LVc = ARc + (size_t)NIMG * MCAND;

    convw1_kernel<<<dim3(K1 / 64, HID / 64), 256, 0, stream>>>(w1, Wh, Wl);
    roi_kernel<true><<<NROI, 256, 0, stream>>>(features, proposals, nullptr, Xhi, Xlo);
    gemm1_mfma<<<dim3(8, 8, ZSPLIT), 256, 0, stream>>>(Xhi, Xlo, Wh, Wl, CP);
    bias_relu_kernel<<<(NROI * HID) / 256, 256, 0, stream>>>(CP, b1, H1);
    gemm2_kernel<<<dim3(16, 16), 256, 0, stream>>>(H1, w2, b2, H2);
    heads_kernel<<<NROI, 128, 0, stream>>>(H2, wc, bc, wb, bb, proposals,
                                           BXc, NBc, ARc, LVc);
    nms_kernel<<<NIMG, 1024, 0, stream>>>(BXc, NBc, ARc, LVc, (float*)d_out);
  } else {
    float* ws = (float*)d_ws;
    float* X   = ws;
    float* CP  = X + XE;
    float* H1  = CP + (size_t)ZSPLIT * NROI * HID;
    float* H2  = H1 + (size_t)NROI * HID;
    float* BXc = H2 + (size_t)NROI * HID;
    float* NBc = BXc + (size_t)NIMG * MCAND * 4;
    float* ARc = NBc + (size_t)NIMG * MCAND * 4;
    float* LVc = ARc + (size_t)NIMG * MCAND;

    roi_kernel<false><<<NROI, 256, 0, stream>>>(features, proposals, X, nullptr, nullptr);
    gemm1_kernel<<<dim3(16, 16, ZSPLIT), 256, 0, stream>>>(X, w1, CP);
    bias_relu_kernel<<<(NROI * HID) / 256, 256, 0, stream>>>(CP, b1, H1);
    gemm2_kernel<<<dim3(16, 16), 256, 0, stream>>>(H1, w2, b2, H2);
    heads_kernel<<<NROI, 128, 0, stream>>>(H2, wc, bc, wb, bb, proposals,
                                           BXc, NBc, ARc, LVc);
    nms_kernel<<<NIMG, 1024, 0, stream>>>(BXc, NBc, ARc, LVc, (float*)d_out);
  }
}

// Round 6
// 997.242 us; speedup vs baseline: 1.7511x; 1.0440x over previous
//
#include <hip/hip_runtime.h>
#include <cmath>

// Problem constants (N=2, S=512, C=512, H=W=50, OUT=7, RATIO=2)
#define NIMG 2
#define SPROP 512
#define NROI 1024          // NIMG*SPROP
#define CCH 512
#define FH 50
#define FW 50
#define K1 25088           // CCH*7*7
#define HID 1024
#define NCLS 21
#define NDET 100
#define IMGSZ 800.0f
#define LOGMAX 4.135166556742356f   // log(1000/16)
#define MCAND 10240        // SPROP*(NCLS-1)
#define ZSPLIT 8
#define KCHUNK 3136        // K1/ZSPLIT
#define BCAP 4096          // boxes kept in LDS; pos>=BCAP falls back to global

typedef unsigned short u16;
typedef __attribute__((ext_vector_type(8))) short short8;
typedef __attribute__((ext_vector_type(4))) float f32x4;

__device__ __forceinline__ u16 f2bf(float x) {        // RTNE fp32 -> bf16
  unsigned int u = __float_as_uint(x);
  u += 0x7fffu + ((u >> 16) & 1u);
  return (u16)(u >> 16);
}
__device__ __forceinline__ float bf2f(u16 h) {
  return __uint_as_float(((unsigned int)h) << 16);
}

// ------------------------------------------------------------ ROI align
template <bool BF16OUT>
__global__ __launch_bounds__(256) void roi_kernel(
    const float* __restrict__ feat, const float* __restrict__ props,
    float* __restrict__ X, u16* __restrict__ Xhi, u16* __restrict__ Xlo) {
  const int r = blockIdx.x;
  const int n = r >> 9;
  const int tid = threadIdx.x;
  __shared__ float tile[32][256];   // 32 ch x (16x16 px) = 32 KB
  __shared__ int sy0[14], sy1[14], sx0[14], sx1[14];
  __shared__ float sly[14], slx[14], svy[14], svx[14];

  const float p0 = props[r * 4 + 0] * 0.0625f;
  const float p1 = props[r * 4 + 1] * 0.0625f;
  const float p2 = props[r * 4 + 2] * 0.0625f;
  const float p3 = props[r * 4 + 3] * 0.0625f;
  const float bw = fmaxf(p2 - p0, 1.0f) / 7.0f;
  const float bh = fmaxf(p3 - p1, 1.0f) / 7.0f;

  if (tid < 14) {
    const int j = tid;
    const float g = (float)(j >> 1) + ((float)(j & 1) + 0.5f) * 0.5f;
    float y = p1 + g * bh;
    svy[j] = (y > -1.0f && y < (float)FH) ? 1.0f : 0.0f;
    float yc = fminf(fmaxf(y, 0.0f), (float)(FH - 1));
    int y0 = (int)floorf(yc);
    sy0[j] = y0; sy1[j] = min(y0 + 1, FH - 1); sly[j] = yc - (float)y0;
    float x = p0 + g * bw;
    svx[j] = (x > -1.0f && x < (float)FW) ? 1.0f : 0.0f;
    float xc = fminf(fmaxf(x, 0.0f), (float)(FW - 1));
    int x0 = (int)floorf(xc);
    sx0[j] = x0; sx1[j] = min(x0 + 1, FW - 1); slx[j] = xc - (float)x0;
  }
  __syncthreads();
  const int ymin = sy0[0], xmin = sx0[0];
  const float* fb = feat + (size_t)n * CCH * (FH * FW);

  for (int cc = 0; cc < 16; ++cc) {
    const int c0 = cc * 32;
#pragma unroll
    for (int e = 0; e < 32; ++e) {
      const int idx = tid + e * 256;
      const int c = idx >> 8, p = idx & 255;
      const int gy = min(ymin + (p >> 4), FH - 1);
      const int gx = min(xmin + (p & 15), FW - 1);
      tile[c][p] = fb[(size_t)(c0 + c) * (FH * FW) + gy * FW + gx];
    }
    __syncthreads();
#pragma unroll
    for (int e = 0; e < 7; ++e) {
      const int idx = tid + e * 256;
      if (idx < 1568) {
        const int c = idx / 49;
        const int s = idx - c * 49;
        const int oy = s / 7, ox = s - (s / 7) * 7;
        float acc = 0.0f;
#pragma unroll
        for (int sy = 0; sy < 2; ++sy) {
          const int yj = oy * 2 + sy;
          const int py0 = sy0[yj] - ymin, py1 = sy1[yj] - ymin;
          const float ly = sly[yj], vy = svy[yj];
#pragma unroll
          for (int sx = 0; sx < 2; ++sx) {
            const int xj = ox * 2 + sx;
            const int px0 = sx0[xj] - xmin, px1 = sx1[xj] - xmin;
            const float lx = slx[xj], vx = svx[xj];
            const float f00 = tile[c][py0 * 16 + px0];
            const float f01 = tile[c][py0 * 16 + px1];
            const float f10 = tile[c][py1 * 16 + px0];
            const float f11 = tile[c][py1 * 16 + px1];
            float v = f00 * (1.0f - ly) * (1.0f - lx) + f01 * (1.0f - ly) * lx +
                      f10 * ly * (1.0f - lx) + f11 * ly * lx;
            acc += v * (vy * vx);
          }
        }
        const float v = acc * 0.25f;
        const size_t k = (size_t)r * K1 + (size_t)(c0 + c) * 49 + s;
        if (BF16OUT) {
          const u16 h = f2bf(v);
          Xhi[k] = h;
          Xlo[k] = f2bf(v - bf2f(h));
        } else {
          X[k] = v;
        }
      }
    }
    __syncthreads();
  }
}

// ------------------------- w1 -> hi/lo bf16, transposed to [n][k]
__global__ __launch_bounds__(256) void convw1_kernel(
    const float* __restrict__ w1, u16* __restrict__ Wh, u16* __restrict__ Wl) {
  __shared__ u16 sh[64][65], sl[64][65];
  const int k0 = blockIdx.x * 64;
  const int n0 = blockIdx.y * 64;
  const int t = threadIdx.x;
#pragma unroll
  for (int e = 0; e < 16; ++e) {
    const int idx = t + e * 256;
    const int kl = idx >> 6, nl = idx & 63;
    const float v = w1[(size_t)(k0 + kl) * HID + n0 + nl];
    const u16 h = f2bf(v);
    sh[kl][nl] = h;
    sl[kl][nl] = f2bf(v - bf2f(h));
  }
  __syncthreads();
#pragma unroll
  for (int e = 0; e < 16; ++e) {
    const int idx = t + e * 256;
    const int nl = idx >> 6, kl = idx & 63;
    Wh[(size_t)(n0 + nl) * K1 + k0 + kl] = sh[kl][nl];
    Wl[(size_t)(n0 + nl) * K1 + k0 + kl] = sl[kl][nl];
  }
}

// ------------------------------- FC1: split-bf16 MFMA GEMM, K-split z=8
__global__ __launch_bounds__(256, 2) void gemm1_mfma(
    const u16* __restrict__ Ahg, const u16* __restrict__ Alg,
    const u16* __restrict__ Bhg, const u16* __restrict__ Blg,
    float* __restrict__ CP) {
  __shared__ u16 Ah[128][40], Al[128][40], Bh[128][40], Bl[128][40];
  const int tid = threadIdx.x;
  const int lane = tid & 63;
  const int wv = tid >> 6;
  const int wm = (wv >> 1) * 64;
  const int wn = (wv & 1) * 64;
  const int mT = blockIdx.y << 7;
  const int nT = blockIdx.x << 7;
  const int kz = blockIdx.z * KCHUNK;

  const int r0 = tid >> 2, q0 = (tid & 3) << 3;
  const int r1 = r0 + 64;

  f32x4 acc[4][4];
  const f32x4 zz = {0.0f, 0.0f, 0.0f, 0.0f};
#pragma unroll
  for (int i = 0; i < 4; ++i)
#pragma unroll
    for (int j = 0; j < 4; ++j) acc[i][j] = zz;

  const size_t a0off = (size_t)(mT + r0) * K1 + q0;
  const size_t a1off = (size_t)(mT + r1) * K1 + q0;
  const size_t b0off = (size_t)(nT + r0) * K1 + q0;
  const size_t b1off = (size_t)(nT + r1) * K1 + q0;

  const int fm = lane & 15;
  const int fq = (lane >> 4) << 3;

  for (int kb = kz; kb < kz + KCHUNK; kb += 32) {
    const uint4 va0 = *(const uint4*)(Ahg + a0off + kb);
    const uint4 va1 = *(const uint4*)(Ahg + a1off + kb);
    const uint4 vl0 = *(const uint4*)(Alg + a0off + kb);
    const uint4 vl1 = *(const uint4*)(Alg + a1off + kb);
    const uint4 vb0 = *(const uint4*)(Bhg + b0off + kb);
    const uint4 vb1 = *(const uint4*)(Bhg + b1off + kb);
    const uint4 vm0 = *(const uint4*)(Blg + b0off + kb);
    const uint4 vm1 = *(const uint4*)(Blg + b1off + kb);
    *(uint4*)(&Ah[r0][q0]) = va0;
    *(uint4*)(&Ah[r1][q0]) = va1;
    *(uint4*)(&Al[r0][q0]) = vl0;
    *(uint4*)(&Al[r1][q0]) = vl1;
    *(uint4*)(&Bh[r0][q0]) = vb0;
    *(uint4*)(&Bh[r1][q0]) = vb1;
    *(uint4*)(&Bl[r0][q0]) = vm0;
    *(uint4*)(&Bl[r1][q0]) = vm1;
    __syncthreads();

    short8 fah[4], fal[4], fbh[4], fbl[4];
#pragma unroll
    for (int t = 0; t < 4; ++t) {
      fah[t] = *(const short8*)(&Ah[wm + t * 16 + fm][fq]);
      fal[t] = *(const short8*)(&Al[wm + t * 16 + fm][fq]);
      fbh[t] = *(const short8*)(&Bh[wn + t * 16 + fm][fq]);
      fbl[t] = *(const short8*)(&Bl[wn + t * 16 + fm][fq]);
    }
#pragma unroll
    for (int ti = 0; ti < 4; ++ti)
#pragma unroll
      for (int tj = 0; tj < 4; ++tj) {
        acc[ti][tj] = __builtin_amdgcn_mfma_f32_16x16x32_bf16(
            fah[ti], fbh[tj], acc[ti][tj], 0, 0, 0);
        acc[ti][tj] = __builtin_amdgcn_mfma_f32_16x16x32_bf16(
            fah[ti], fbl[tj], acc[ti][tj], 0, 0, 0);
        acc[ti][tj] = __builtin_amdgcn_mfma_f32_16x16x32_bf16(
            fal[ti], fbh[tj], acc[ti][tj], 0, 0, 0);
      }
    __syncthreads();
  }

  float* Cp = CP + (size_t)blockIdx.z * ((size_t)NROI * HID);
  const int crow = mT + wm + (lane >> 4) * 4;
  const int ccol = nT + wn + fm;
#pragma unroll
  for (int ti = 0; ti < 4; ++ti)
#pragma unroll
    for (int tj = 0; tj < 4; ++tj)
#pragma unroll
      for (int rr = 0; rr < 4; ++rr)
        Cp[(size_t)(crow + ti * 16 + rr) * HID + ccol + tj * 16] =
            acc[ti][tj][rr];
}

// ------------------------------------------------------- FC1 fallback (fp32)
__global__ __launch_bounds__(256) void gemm1_kernel(
    const float* __restrict__ A, const float* __restrict__ B,
    float* __restrict__ CP) {
  __shared__ float As[16][68];
  __shared__ float Bs[16][68];
  const int tid = threadIdx.x;
  const int mTile = blockIdx.y << 6;
  const int nTile = blockIdx.x << 6;
  const int k0 = blockIdx.z * KCHUNK;
  const int ty = tid >> 4, tx = tid & 15;
  const int ar = tid >> 2, ac = (tid & 3) << 2;
  const int br = tid >> 4, bcl = (tid & 15) << 2;
  float acc[4][4] = {};

  for (int kb = k0; kb < k0 + KCHUNK; kb += 16) {
    const float4 av = *(const float4*)(A + (size_t)(mTile + ar) * K1 + kb + ac);
    const float4 bv = *(const float4*)(B + (size_t)(kb + br) * HID + nTile + bcl);
    As[ac + 0][ar] = av.x; As[ac + 1][ar] = av.y;
    As[ac + 2][ar] = av.z; As[ac + 3][ar] = av.w;
    *(float4*)(&Bs[br][bcl]) = bv;
    __syncthreads();
#pragma unroll
    for (int kk = 0; kk < 16; ++kk) {
      const float4 a4 = *(const float4*)(&As[kk][ty << 2]);
      const float4 b4 = *(const float4*)(&Bs[kk][tx << 2]);
      const float aa[4] = {a4.x, a4.y, a4.z, a4.w};
      const float bb4[4] = {b4.x, b4.y, b4.z, b4.w};
#pragma unroll
      for (int i = 0; i < 4; ++i)
#pragma unroll
        for (int j = 0; j < 4; ++j)
          acc[i][j] = fmaf(aa[i], bb4[j], acc[i][j]);
    }
    __syncthreads();
  }
  float* Cp = CP + (size_t)blockIdx.z * (HID * NROI);
#pragma unroll
  for (int i = 0; i < 4; ++i) {
    *(float4*)(Cp + (size_t)(mTile + (ty << 2) + i) * HID + nTile + (tx << 2)) =
        make_float4(acc[i][0], acc[i][1], acc[i][2], acc[i][3]);
  }
}

// reduce 8 K-partials + bias + relu
__global__ __launch_bounds__(256) void bias_relu_kernel(
    const float* __restrict__ CP, const float* __restrict__ b1,
    float* __restrict__ H1) {
  const int idx = blockIdx.x * 256 + threadIdx.x;
  float v = b1[idx & (HID - 1)];
#pragma unroll
  for (int z = 0; z < ZSPLIT; ++z) v += CP[(size_t)z * (HID * NROI) + idx];
  H1[idx] = fmaxf(v, 0.0f);
}

// ------------------------------------------------------------- FC2 (K=1024)
__global__ __launch_bounds__(256) void gemm2_kernel(
    const float* __restrict__ A, const float* __restrict__ B,
    const float* __restrict__ bias, float* __restrict__ C) {
  __shared__ float As[16][68];
  __shared__ float Bs[16][68];
  const int tid = threadIdx.x;
  const int mTile = blockIdx.y << 6;
  const int nTile = blockIdx.x << 6;
  const int ty = tid >> 4, tx = tid & 15;
  const int ar = tid >> 2, ac = (tid & 3) << 2;
  const int br = tid >> 4, bcl = (tid & 15) << 2;
  float acc[4][4] = {};

  for (int kb = 0; kb < HID; kb += 16) {
    const float4 av = *(const float4*)(A + (size_t)(mTile + ar) * HID + kb + ac);
    const float4 bv = *(const float4*)(B + (size_t)(kb + br) * HID + nTile + bcl);
    As[ac + 0][ar] = av.x; As[ac + 1][ar] = av.y;
    As[ac + 2][ar] = av.z; As[ac + 3][ar] = av.w;
    *(float4*)(&Bs[br][bcl]) = bv;
    __syncthreads();
#pragma unroll
    for (int kk = 0; kk < 16; ++kk) {
      const float4 a4 = *(const float4*)(&As[kk][ty << 2]);
      const float4 b4 = *(const float4*)(&Bs[kk][tx << 2]);
      const float aa[4] = {a4.x, a4.y, a4.z, a4.w};
      const float bb4[4] = {b4.x, b4.y, b4.z, b4.w};
#pragma unroll
      for (int i = 0; i < 4; ++i)
#pragma unroll
        for (int j = 0; j < 4; ++j)
          acc[i][j] = fmaf(aa[i], bb4[j], acc[i][j]);
    }
    __syncthreads();
  }
#pragma unroll
  for (int i = 0; i < 4; ++i) {
#pragma unroll
    for (int j = 0; j < 4; ++j) {
      float v = acc[i][j] + bias[nTile + (tx << 2) + j];
      acc[i][j] = fmaxf(v, 0.0f);
    }
    *(float4*)(C + (size_t)(mTile + (ty << 2) + i) * HID + nTile + (tx << 2)) =
        make_float4(acc[i][0], acc[i][1], acc[i][2], acc[i][3]);
  }
}

// ------------------- heads: cls+box dots, softmax, decode, candidate arrays
__global__ __launch_bounds__(128) void heads_kernel(
    const float* __restrict__ H2m, const float* __restrict__ wc,
    const float* __restrict__ bc, const float* __restrict__ wb,
    const float* __restrict__ bb, const float* __restrict__ props,
    float* __restrict__ BX, float* __restrict__ NB,
    float* __restrict__ AR, float* __restrict__ LV) {
  const int r = blockIdx.x;
  const int tid = threadIdx.x;
  __shared__ float hrow[HID];
  __shared__ float vals[112];
  __shared__ float red[2];

  for (int i = tid; i < HID; i += 128) hrow[i] = H2m[(size_t)r * HID + i];
  __syncthreads();

  if (tid < 105) {
    float acc;
    if (tid < NCLS) {
      acc = bc[tid];
      for (int kk = 0; kk < HID; ++kk) acc = fmaf(hrow[kk], wc[kk * NCLS + tid], acc);
    } else {
      const int j = tid - NCLS;
      acc = bb[j];
      for (int kk = 0; kk < HID; ++kk) acc = fmaf(hrow[kk], wb[kk * (NCLS * 4) + j], acc);
    }
    vals[tid] = acc;
  }
  __syncthreads();

  if (tid == 0) {
    float m = vals[0];
    for (int k = 1; k < NCLS; ++k) m = fmaxf(m, vals[k]);
    float s = 0.0f;
    for (int k = 0; k < NCLS; ++k) s += expf(vals[k] - m);
    red[0] = m;
    red[1] = 1.0f / s;
  }
  __syncthreads();

  if (tid >= 1 && tid <= 20) {
    const int k = tid;
    const float prob = expf(vals[k] - red[0]) * red[1];

    const float px1 = props[r * 4 + 0], py1 = props[r * 4 + 1];
    const float px2 = props[r * 4 + 2], py2 = props[r * 4 + 3];
    const float pw = px2 - px1, ph = py2 - py1;
    const float pcx = px1 + 0.5f * pw, pcy = py1 + 0.5f * ph;

    const float dx = vals[NCLS + k * 4 + 0] / 10.0f;
    const float dy = vals[NCLS + k * 4 + 1] / 10.0f;
    const float dw = fminf(vals[NCLS + k * 4 + 2] / 5.0f, LOGMAX);
    const float dh = fminf(vals[NCLS + k * 4 + 3] / 5.0f, LOGMAX);

    const float cx = dx * pw + pcx, cy = dy * ph + pcy;
    const float w = expf(dw) * pw, h = expf(dh) * ph;
    float b0 = cx - 0.5f * w, b1c = cy - 0.5f * h;
    float b2 = cx + 0.5f * w, b3 = cy + 0.5f * h;
    b0 = fminf(fmaxf(b0, 0.0f), IMGSZ);
    b1c = fminf(fmaxf(b1c, 0.0f), IMGSZ);
    b2 = fminf(fmaxf(b2, 0.0f), IMGSZ);
    b3 = fminf(fmaxf(b3, 0.0f), IMGSZ);

    const float wv = b2 - b0, hv = b3 - b1c;
    const bool valid = (prob > 0.05f) && (wv >= 0.01f) && (hv >= 0.01f);

    const int n = r >> 9, s = r & 511;
    const int cand = s * 20 + (k - 1);
    const size_t bi = (size_t)n * MCAND + cand;
    const float off = (float)k * (IMGSZ + 1.0f);

    BX[bi * 4 + 0] = b0; BX[bi * 4 + 1] = b1c;
    BX[bi * 4 + 2] = b2; BX[bi * 4 + 3] = b3;
    const float n0 = b0 + off, n1 = b1c + off, n2 = b2 + off, n3 = b3 + off;
    NB[bi * 4 + 0] = n0; NB[bi * 4 + 1] = n1;
    NB[bi * 4 + 2] = n2; NB[bi * 4 + 3] = n3;
    AR[bi] = (n2 - n0) * (n3 - n1);
    LV[bi] = valid ? prob : -1.0f;
  }
}

// ------------------------------------------------------ greedy NMS per image
// v5: class-bucketed incremental NMS.
//  Cross-class IoU is mathematically 0 (class offsets 801*k make intervals
//  disjoint), so suppression only affects the winner's class — same kills as
//  the reference (whose cross-class IoUs are all 0 < 0.5).
//  Phase 1: stable per-class compaction (ballot-rank; within class, compacted
//           order = original-index order) + per-class maxima.
//  Loop:    winner = reduce over 20 class maxima with (score desc, orig-idx
//           asc) — identical tie-break to global argmax; suppress only the
//           winner's class segment; wave 0 recomputes that class max.
//  v4 safety kept: fixed 100 iters, uniform act-guard (no deref when max <=
//  0.05), svals/sidx written every iter, bit-identical IoU arithmetic.

template <int CTRL>
__device__ __forceinline__ void red2(float& v, int& ix) {
  const float tv = __int_as_float(__builtin_amdgcn_update_dpp(
      (int)0xC0000000, __float_as_int(v), CTRL, 0xf, 0xf, false));
  const int ti = __builtin_amdgcn_update_dpp(0x7fffffff, ix, CTRL, 0xf, 0xf, false);
  if (tv > v || (tv == v && ti < ix)) { v = tv; ix = ti; }
}
__device__ __forceinline__ void wave_red2(float& v, int& ix) {
  red2<0x111>(v, ix);  // row_shr:1
  red2<0x112>(v, ix);  // row_shr:2
  red2<0x114>(v, ix);  // row_shr:4
  red2<0x118>(v, ix);  // row_shr:8
  red2<0x142>(v, ix);  // row_bcast:15
  red2<0x143>(v, ix);  // row_bcast:31 -> lane 63 holds winner
}

__global__ __launch_bounds__(1024) void nms_kernel(
    const float* __restrict__ BX, const float* __restrict__ NB,
    const float* __restrict__ AR, const float* __restrict__ LV,
    float* __restrict__ out) {
  const int n = blockIdx.x;
  const int tid = threadIdx.x;          // 0..1023
  const int wave = tid >> 6;            // 0..15
  const int lane = tid & 63;
  __shared__ float  cs[MCAND];          // 40 KB compacted scores (-1 = dead)
  __shared__ float4 cb[BCAP];           // 64 KB compacted boxes
  __shared__ u16    corig[MCAND];       // 20 KB original candidate indices
  __shared__ int    wcls[8][20];        // per-wave per-class valid counts
  __shared__ int    ccnt_s[20];         // per-class totals
  __shared__ int    cbase_s[20];        // per-class segment bases
  __shared__ float  cmax[20];           // per-class current max score
  __shared__ int    cmaxpos[20];        // compacted pos of class max
  __shared__ int    cmaxidx[20];        // original idx of class max
  __shared__ float  svals[NDET];
  __shared__ int    sidx[NDET];
  const size_t base = (size_t)n * MCAND;

  // ---- phase 1a: load scores, ballot-rank per class (threads 0..511 = ROIs)
  float sc[20];
  int rank_[20];
  if (tid < 512) {
    const int s = tid;
#pragma unroll
    for (int c = 0; c < 20; ++c) sc[c] = LV[base + s * 20 + c];
#pragma unroll
    for (int c = 0; c < 20; ++c) {
      const unsigned long long m = __ballot(sc[c] > 0.0f);
      if (lane == 0) wcls[wave][c] = (int)__popcll(m);
      rank_[c] = (int)__popcll(m & ((1ull << lane) - 1ull));
    }
  }
  __syncthreads();

  // ---- phase 1b: totals + bases
  if (tid < 20) {
    int t = 0;
#pragma unroll
    for (int w = 0; w < 8; ++w) t += wcls[w][tid];
    ccnt_s[tid] = t;
  }
  __syncthreads();
  if (tid == 0) {
    int acc = 0;
    for (int c = 0; c < 20; ++c) { cbase_s[c] = acc; acc += ccnt_s[c]; }
  }
  __syncthreads();

  // ---- phase 1c: stable scatter into class segments
  if (tid < 512) {
    const int s = tid;
#pragma unroll
    for (int c = 0; c < 20; ++c) {
      if (sc[c] > 0.0f) {
        int wb_ = 0;
#pragma unroll
        for (int w = 0; w < 8; ++w)
          if (w < wave) wb_ += wcls[w][c];
        const int pos = cbase_s[c] + wb_ + rank_[c];
        cs[pos] = sc[c];
        corig[pos] = (u16)(s * 20 + c);
        if (pos < BCAP) cb[pos] = *(const float4*)(NB + (base + s * 20 + c) * 4);
      }
    }
  }
  __syncthreads();

  // ---- phase 1d: initial per-class maxima (wave w handles class w, w+16)
  for (int c = wave; c < 20; c += 16) {
    const int st = cbase_s[c], cnt = ccnt_s[c];
    float bv = -2.0f;
    int bp = 0x7fffffff;
    for (int i = st + lane; i < st + cnt; i += 64) {
      const float v = cs[i];
      if (v > bv) { bv = v; bp = i; }
    }
    wave_red2(bv, bp);
    if (lane == 63) {
      if (cnt == 0 || bp == 0x7fffffff) {
        cmax[c] = -1e30f; cmaxpos[c] = 0; cmaxidx[c] = 0;
      } else {
        cmax[c] = bv; cmaxpos[c] = bp; cmaxidx[c] = (int)corig[bp];
      }
    }
  }
  __syncthreads();

  // ---- greedy loop: fixed NDET iterations
  for (int d = 0; d < NDET; ++d) {
    // winner over 20 class maxima (redundant in every thread; uniform)
    float wv = -1e30f;
    int widx = 0x7fffffff, wk = 0;
#pragma unroll
    for (int c = 0; c < 20; ++c) {
      const float v = cmax[c];
      const int id = cmaxidx[c];
      if (v > wv || (v == wv && id < widx)) { wv = v; widx = id; wk = c; }
    }
    const bool act = wv > 0.05f;   // uniform; when false nothing is dereferenced

    if (tid == 0) {
      svals[d] = act ? wv : -1.0f;
      sidx[d] = act ? widx : 0;
    }

    if (act) {
      const int wpos = cmaxpos[wk];
      float4 wb;
      if (wpos < BCAP) wb = cb[wpos];
      else wb = *(const float4*)(NB + (base + widx) * 4);
      const float wa = (wb.z - wb.x) * (wb.w - wb.y);
      const int st = cbase_s[wk], cnt = ccnt_s[wk];

      for (int i = st + tid; i < st + cnt; i += 1024) {
        const float4 b = (i < BCAP)
            ? cb[i]
            : *(const float4*)(NB + (base + (int)corig[i]) * 4);
        const float xx1 = fmaxf(wb.x, b.x);
        const float yy1 = fmaxf(wb.y, b.y);
        const float xx2 = fminf(wb.z, b.z);
        const float yy2 = fminf(wb.w, b.w);
        const float inter = fmaxf(xx2 - xx1, 0.0f) * fmaxf(yy2 - yy1, 0.0f);
        const float ar_i = (b.z - b.x) * (b.w - b.y);
        const float iou = inter / (wa + ar_i - inter + 1e-9f);
        if (iou > 0.5f) cs[i] = -1.0f;
      }
      __syncthreads();   // uniform branch: all threads reach this

      if (wave == 0) {   // recompute the one changed class max
        float bv = -2.0f;
        int bp = 0x7fffffff;
        for (int i = st + lane; i < st + cnt; i += 64) {
          const float v = cs[i];
          if (v > bv) { bv = v; bp = i; }
        }
        wave_red2(bv, bp);
        if (lane == 63) {
          if (bp == 0x7fffffff) {
            cmax[wk] = -1e30f; cmaxpos[wk] = 0; cmaxidx[wk] = 0;
          } else {
            cmax[wk] = bv; cmaxpos[wk] = bp; cmaxidx[wk] = (int)corig[bp];
          }
        }
      }
    }
    __syncthreads();
  }

  // ---- writeout
  if (tid < NDET) {
    const int i = tid;
    const float sv = svals[i];
    const int si = sidx[i];
    const bool keep = sv > 0.05f;
    float4 bx4 = make_float4(0.0f, 0.0f, 0.0f, 0.0f);
    if (keep) bx4 = *(const float4*)(BX + (base + si) * 4);
    out[(n * NDET + i) * 4 + 0] = bx4.x;
    out[(n * NDET + i) * 4 + 1] = bx4.y;
    out[(n * NDET + i) * 4 + 2] = bx4.z;
    out[(n * NDET + i) * 4 + 3] = bx4.w;
    out[NIMG * NDET * 4 + n * NDET + i] = keep ? sv : 0.0f;
    out[NIMG * NDET * 4 + NIMG * NDET + n * NDET + i] =
        keep ? (float)(1 + (si % 20)) : 0.0f;
  }
}

// ---------------------------------------------------------------- launcher
extern "C" void kernel_launch(void* const* d_in, const int* in_sizes, int n_in,
                              void* d_out, int out_size, void* d_ws, size_t ws_size,
                              hipStream_t stream) {
  const float* features  = (const float*)d_in[0];
  const float* proposals = (const float*)d_in[1];
  const float* w1 = (const float*)d_in[2];
  const float* b1 = (const float*)d_in[3];
  const float* w2 = (const float*)d_in[4];
  const float* b2 = (const float*)d_in[5];
  const float* wc = (const float*)d_in[6];
  const float* bc = (const float*)d_in[7];
  const float* wb = (const float*)d_in[8];
  const float* bb = (const float*)d_in[9];

  const size_t XE = (size_t)NROI * K1;
  const size_t WE = (size_t)K1 * HID;
  const size_t FLOATS_TAIL =
      (size_t)ZSPLIT * NROI * HID + 2 * (size_t)NROI * HID + (size_t)NIMG * MCAND * 10;
  const size_t NEED = (XE * 2 + WE * 2) * sizeof(u16) + FLOATS_TAIL * sizeof(float);

  if (ws_size >= NEED) {
    u16* Xhi = (u16*)d_ws;
    u16* Xlo = Xhi + XE;
    u16* Wh  = Xlo + XE;
    u16* Wl  = Wh + WE;
    float* CP  = (float*)(Wl + WE);
    float* H1  = CP + (size_t)ZSPLIT * NROI * HID;
    float* H2  = H1 + (size_t)NROI * HID;
    float* BXc = H2 + (size_t)NROI * HID;
    float* NBc = BXc + (size_t)NIMG * MCAND * 4;
    float* ARc = NBc + (size_t)NIMG * MCAND * 4;
    float* LVc = ARc + (size_t)NIMG * MCAND;

    convw1_kernel<<<dim3(K1 / 64, HID / 64), 256, 0, stream>>>(w1, Wh, Wl);
    roi_kernel<true><<<NROI, 256, 0, stream>>>(features, proposals, nullptr, Xhi, Xlo);
    gemm1_mfma<<<dim3(8, 8, ZSPLIT), 256, 0, stream>>>(Xhi, Xlo, Wh, Wl, CP);
    bias_relu_kernel<<<(NROI * HID) / 256, 256, 0, stream>>>(CP, b1, H1);
    gemm2_kernel<<<dim3(16, 16), 256, 0, stream>>>(H1, w2, b2, H2);
    heads_kernel<<<NROI, 128, 0, stream>>>(H2, wc, bc, wb, bb, proposals,
                                           BXc, NBc, ARc, LVc);
    nms_kernel<<<NIMG, 1024, 0, stream>>>(BXc, NBc, ARc, LVc, (float*)d_out);
  } else {
    float* ws = (float*)d_ws;
    float* X   = ws;
    float* CP  = X + XE;
    float* H1  = CP + (size_t)ZSPLIT * NROI * HID;
    float* H2  = H1 + (size_t)NROI * HID;
    float* BXc = H2 + (size_t)NROI * HID;
    float* NBc = BXc + (size_t)NIMG * MCAND * 4;
    float* ARc = NBc + (size_t)NIMG * MCAND * 4;
    float* LVc = ARc + (size_t)NIMG * MCAND;

    roi_kernel<false><<<NROI, 256, 0, stream>>>(features, proposals, X, nullptr, nullptr);
    gemm1_kernel<<<dim3(16, 16, ZSPLIT), 256, 0, stream>>>(X, w1, CP);
    bias_relu_kernel<<<(NROI * HID) / 256, 256, 0, stream>>>(CP, b1, H1);
    gemm2_kernel<<<dim3(16, 16), 256, 0, stream>>>(H1, w2, b2, H2);
    heads_kernel<<<NROI, 128, 0, stream>>>(H2, wc, bc, wb, bb, proposals,
                                           BXc, NBc, ARc, LVc);
    nms_kernel<<<NIMG, 1024, 0, stream>>>(BXc, NBc, ARc, LVc, (float*)d_out);
  }
}

// Round 7
// 906.724 us; speedup vs baseline: 1.9259x; 1.0998x over previous
//
#include <hip/hip_runtime.h>
#include <cmath>

// Problem constants (N=2, S=512, C=512, H=W=50, OUT=7, RATIO=2)
#define NIMG 2
#define SPROP 512
#define NROI 1024          // NIMG*SPROP
#define CCH 512
#define FH 50
#define FW 50
#define K1 25088           // CCH*7*7
#define HID 1024
#define NCLS 21
#define NDET 100
#define IMGSZ 800.0f
#define LOGMAX 4.135166556742356f   // log(1000/16)
#define MCAND 10240        // SPROP*(NCLS-1)
#define ZSPLIT 8
#define KCHUNK 3136        // K1/ZSPLIT

typedef unsigned short u16;
typedef __attribute__((ext_vector_type(8))) short short8;
typedef __attribute__((ext_vector_type(4))) float f32x4;

__device__ __forceinline__ u16 f2bf(float x) {        // RTNE fp32 -> bf16
  unsigned int u = __float_as_uint(x);
  u += 0x7fffu + ((u >> 16) & 1u);
  return (u16)(u >> 16);
}
__device__ __forceinline__ float bf2f(u16 h) {
  return __uint_as_float(((unsigned int)h) << 16);
}

// ------------------------------------------------------------ ROI align
template <bool BF16OUT>
__global__ __launch_bounds__(256) void roi_kernel(
    const float* __restrict__ feat, const float* __restrict__ props,
    float* __restrict__ X, u16* __restrict__ Xhi, u16* __restrict__ Xlo) {
  const int r = blockIdx.x;
  const int n = r >> 9;
  const int tid = threadIdx.x;
  __shared__ float tile[32][256];   // 32 ch x (16x16 px) = 32 KB
  __shared__ int sy0[14], sy1[14], sx0[14], sx1[14];
  __shared__ float sly[14], slx[14], svy[14], svx[14];

  const float p0 = props[r * 4 + 0] * 0.0625f;
  const float p1 = props[r * 4 + 1] * 0.0625f;
  const float p2 = props[r * 4 + 2] * 0.0625f;
  const float p3 = props[r * 4 + 3] * 0.0625f;
  const float bw = fmaxf(p2 - p0, 1.0f) / 7.0f;
  const float bh = fmaxf(p3 - p1, 1.0f) / 7.0f;

  if (tid < 14) {
    const int j = tid;
    const float g = (float)(j >> 1) + ((float)(j & 1) + 0.5f) * 0.5f;
    float y = p1 + g * bh;
    svy[j] = (y > -1.0f && y < (float)FH) ? 1.0f : 0.0f;
    float yc = fminf(fmaxf(y, 0.0f), (float)(FH - 1));
    int y0 = (int)floorf(yc);
    sy0[j] = y0; sy1[j] = min(y0 + 1, FH - 1); sly[j] = yc - (float)y0;
    float x = p0 + g * bw;
    svx[j] = (x > -1.0f && x < (float)FW) ? 1.0f : 0.0f;
    float xc = fminf(fmaxf(x, 0.0f), (float)(FW - 1));
    int x0 = (int)floorf(xc);
    sx0[j] = x0; sx1[j] = min(x0 + 1, FW - 1); slx[j] = xc - (float)x0;
  }
  __syncthreads();
  const int ymin = sy0[0], xmin = sx0[0];
  const float* fb = feat + (size_t)n * CCH * (FH * FW);

  for (int cc = 0; cc < 16; ++cc) {
    const int c0 = cc * 32;
#pragma unroll
    for (int e = 0; e < 32; ++e) {
      const int idx = tid + e * 256;
      const int c = idx >> 8, p = idx & 255;
      const int gy = min(ymin + (p >> 4), FH - 1);
      const int gx = min(xmin + (p & 15), FW - 1);
      tile[c][p] = fb[(size_t)(c0 + c) * (FH * FW) + gy * FW + gx];
    }
    __syncthreads();
#pragma unroll
    for (int e = 0; e < 7; ++e) {
      const int idx = tid + e * 256;
      if (idx < 1568) {
        const int c = idx / 49;
        const int s = idx - c * 49;
        const int oy = s / 7, ox = s - (s / 7) * 7;
        float acc = 0.0f;
#pragma unroll
        for (int sy = 0; sy < 2; ++sy) {
          const int yj = oy * 2 + sy;
          const int py0 = sy0[yj] - ymin, py1 = sy1[yj] - ymin;
          const float ly = sly[yj], vy = svy[yj];
#pragma unroll
          for (int sx = 0; sx < 2; ++sx) {
            const int xj = ox * 2 + sx;
            const int px0 = sx0[xj] - xmin, px1 = sx1[xj] - xmin;
            const float lx = slx[xj], vx = svx[xj];
            const float f00 = tile[c][py0 * 16 + px0];
            const float f01 = tile[c][py0 * 16 + px1];
            const float f10 = tile[c][py1 * 16 + px0];
            const float f11 = tile[c][py1 * 16 + px1];
            float v = f00 * (1.0f - ly) * (1.0f - lx) + f01 * (1.0f - ly) * lx +
                      f10 * ly * (1.0f - lx) + f11 * ly * lx;
            acc += v * (vy * vx);
          }
        }
        const float v = acc * 0.25f;
        const size_t k = (size_t)r * K1 + (size_t)(c0 + c) * 49 + s;
        if (BF16OUT) {
          const u16 h = f2bf(v);
          Xhi[k] = h;
          Xlo[k] = f2bf(v - bf2f(h));
        } else {
          X[k] = v;
        }
      }
    }
    __syncthreads();
  }
}

// ------------------------- w1 -> hi/lo bf16, transposed to [n][k]
__global__ __launch_bounds__(256) void convw1_kernel(
    const float* __restrict__ w1, u16* __restrict__ Wh, u16* __restrict__ Wl) {
  __shared__ u16 sh[64][65], sl[64][65];
  const int k0 = blockIdx.x * 64;
  const int n0 = blockIdx.y * 64;
  const int t = threadIdx.x;
#pragma unroll
  for (int e = 0; e < 16; ++e) {
    const int idx = t + e * 256;
    const int kl = idx >> 6, nl = idx & 63;
    const float v = w1[(size_t)(k0 + kl) * HID + n0 + nl];
    const u16 h = f2bf(v);
    sh[kl][nl] = h;
    sl[kl][nl] = f2bf(v - bf2f(h));
  }
  __syncthreads();
#pragma unroll
  for (int e = 0; e < 16; ++e) {
    const int idx = t + e * 256;
    const int nl = idx >> 6, kl = idx & 63;
    Wh[(size_t)(n0 + nl) * K1 + k0 + kl] = sh[kl][nl];
    Wl[(size_t)(n0 + nl) * K1 + k0 + kl] = sl[kl][nl];
  }
}

// ------------------------------- FC1: split-bf16 MFMA GEMM, K-split z=8
__global__ __launch_bounds__(256, 2) void gemm1_mfma(
    const u16* __restrict__ Ahg, const u16* __restrict__ Alg,
    const u16* __restrict__ Bhg, const u16* __restrict__ Blg,
    float* __restrict__ CP) {
  __shared__ u16 Ah[128][40], Al[128][40], Bh[128][40], Bl[128][40];
  const int tid = threadIdx.x;
  const int lane = tid & 63;
  const int wv = tid >> 6;
  const int wm = (wv >> 1) * 64;
  const int wn = (wv & 1) * 64;
  const int mT = blockIdx.y << 7;
  const int nT = blockIdx.x << 7;
  const int kz = blockIdx.z * KCHUNK;

  const int r0 = tid >> 2, q0 = (tid & 3) << 3;
  const int r1 = r0 + 64;

  f32x4 acc[4][4];
  const f32x4 zz = {0.0f, 0.0f, 0.0f, 0.0f};
#pragma unroll
  for (int i = 0; i < 4; ++i)
#pragma unroll
    for (int j = 0; j < 4; ++j) acc[i][j] = zz;

  const size_t a0off = (size_t)(mT + r0) * K1 + q0;
  const size_t a1off = (size_t)(mT + r1) * K1 + q0;
  const size_t b0off = (size_t)(nT + r0) * K1 + q0;
  const size_t b1off = (size_t)(nT + r1) * K1 + q0;

  const int fm = lane & 15;
  const int fq = (lane >> 4) << 3;

  for (int kb = kz; kb < kz + KCHUNK; kb += 32) {
    const uint4 va0 = *(const uint4*)(Ahg + a0off + kb);
    const uint4 va1 = *(const uint4*)(Ahg + a1off + kb);
    const uint4 vl0 = *(const uint4*)(Alg + a0off + kb);
    const uint4 vl1 = *(const uint4*)(Alg + a1off + kb);
    const uint4 vb0 = *(const uint4*)(Bhg + b0off + kb);
    const uint4 vb1 = *(const uint4*)(Bhg + b1off + kb);
    const uint4 vm0 = *(const uint4*)(Blg + b0off + kb);
    const uint4 vm1 = *(const uint4*)(Blg + b1off + kb);
    *(uint4*)(&Ah[r0][q0]) = va0;
    *(uint4*)(&Ah[r1][q0]) = va1;
    *(uint4*)(&Al[r0][q0]) = vl0;
    *(uint4*)(&Al[r1][q0]) = vl1;
    *(uint4*)(&Bh[r0][q0]) = vb0;
    *(uint4*)(&Bh[r1][q0]) = vb1;
    *(uint4*)(&Bl[r0][q0]) = vm0;
    *(uint4*)(&Bl[r1][q0]) = vm1;
    __syncthreads();

    short8 fah[4], fal[4], fbh[4], fbl[4];
#pragma unroll
    for (int t = 0; t < 4; ++t) {
      fah[t] = *(const short8*)(&Ah[wm + t * 16 + fm][fq]);
      fal[t] = *(const short8*)(&Al[wm + t * 16 + fm][fq]);
      fbh[t] = *(const short8*)(&Bh[wn + t * 16 + fm][fq]);
      fbl[t] = *(const short8*)(&Bl[wn + t * 16 + fm][fq]);
    }
#pragma unroll
    for (int ti = 0; ti < 4; ++ti)
#pragma unroll
      for (int tj = 0; tj < 4; ++tj) {
        acc[ti][tj] = __builtin_amdgcn_mfma_f32_16x16x32_bf16(
            fah[ti], fbh[tj], acc[ti][tj], 0, 0, 0);
        acc[ti][tj] = __builtin_amdgcn_mfma_f32_16x16x32_bf16(
            fah[ti], fbl[tj], acc[ti][tj], 0, 0, 0);
        acc[ti][tj] = __builtin_amdgcn_mfma_f32_16x16x32_bf16(
            fal[ti], fbh[tj], acc[ti][tj], 0, 0, 0);
      }
    __syncthreads();
  }

  float* Cp = CP + (size_t)blockIdx.z * ((size_t)NROI * HID);
  const int crow = mT + wm + (lane >> 4) * 4;
  const int ccol = nT + wn + fm;
#pragma unroll
  for (int ti = 0; ti < 4; ++ti)
#pragma unroll
    for (int tj = 0; tj < 4; ++tj)
#pragma unroll
      for (int rr = 0; rr < 4; ++rr)
        Cp[(size_t)(crow + ti * 16 + rr) * HID + ccol + tj * 16] =
            acc[ti][tj][rr];
}

// ------------------------------------------------------- FC1 fallback (fp32)
__global__ __launch_bounds__(256) void gemm1_kernel(
    const float* __restrict__ A, const float* __restrict__ B,
    float* __restrict__ CP) {
  __shared__ float As[16][68];
  __shared__ float Bs[16][68];
  const int tid = threadIdx.x;
  const int mTile = blockIdx.y << 6;
  const int nTile = blockIdx.x << 6;
  const int k0 = blockIdx.z * KCHUNK;
  const int ty = tid >> 4, tx = tid & 15;
  const int ar = tid >> 2, ac = (tid & 3) << 2;
  const int br = tid >> 4, bcl = (tid & 15) << 2;
  float acc[4][4] = {};

  for (int kb = k0; kb < k0 + KCHUNK; kb += 16) {
    const float4 av = *(const float4*)(A + (size_t)(mTile + ar) * K1 + kb + ac);
    const float4 bv = *(const float4*)(B + (size_t)(kb + br) * HID + nTile + bcl);
    As[ac + 0][ar] = av.x; As[ac + 1][ar] = av.y;
    As[ac + 2][ar] = av.z; As[ac + 3][ar] = av.w;
    *(float4*)(&Bs[br][bcl]) = bv;
    __syncthreads();
#pragma unroll
    for (int kk = 0; kk < 16; ++kk) {
      const float4 a4 = *(const float4*)(&As[kk][ty << 2]);
      const float4 b4 = *(const float4*)(&Bs[kk][tx << 2]);
      const float aa[4] = {a4.x, a4.y, a4.z, a4.w};
      const float bb4[4] = {b4.x, b4.y, b4.z, b4.w};
#pragma unroll
      for (int i = 0; i < 4; ++i)
#pragma unroll
        for (int j = 0; j < 4; ++j)
          acc[i][j] = fmaf(aa[i], bb4[j], acc[i][j]);
    }
    __syncthreads();
  }
  float* Cp = CP + (size_t)blockIdx.z * (HID * NROI);
#pragma unroll
  for (int i = 0; i < 4; ++i) {
    *(float4*)(Cp + (size_t)(mTile + (ty << 2) + i) * HID + nTile + (tx << 2)) =
        make_float4(acc[i][0], acc[i][1], acc[i][2], acc[i][3]);
  }
}

// reduce 8 K-partials + bias + relu
__global__ __launch_bounds__(256) void bias_relu_kernel(
    const float* __restrict__ CP, const float* __restrict__ b1,
    float* __restrict__ H1) {
  const int idx = blockIdx.x * 256 + threadIdx.x;
  float v = b1[idx & (HID - 1)];
#pragma unroll
  for (int z = 0; z < ZSPLIT; ++z) v += CP[(size_t)z * (HID * NROI) + idx];
  H1[idx] = fmaxf(v, 0.0f);
}

// ------------------------------------------------------------- FC2 (K=1024)
__global__ __launch_bounds__(256) void gemm2_kernel(
    const float* __restrict__ A, const float* __restrict__ B,
    const float* __restrict__ bias, float* __restrict__ C) {
  __shared__ float As[16][68];
  __shared__ float Bs[16][68];
  const int tid = threadIdx.x;
  const int mTile = blockIdx.y << 6;
  const int nTile = blockIdx.x << 6;
  const int ty = tid >> 4, tx = tid & 15;
  const int ar = tid >> 2, ac = (tid & 3) << 2;
  const int br = tid >> 4, bcl = (tid & 15) << 2;
  float acc[4][4] = {};

  for (int kb = 0; kb < HID; kb += 16) {
    const float4 av = *(const float4*)(A + (size_t)(mTile + ar) * HID + kb + ac);
    const float4 bv = *(const float4*)(B + (size_t)(kb + br) * HID + nTile + bcl);
    As[ac + 0][ar] = av.x; As[ac + 1][ar] = av.y;
    As[ac + 2][ar] = av.z; As[ac + 3][ar] = av.w;
    *(float4*)(&Bs[br][bcl]) = bv;
    __syncthreads();
#pragma unroll
    for (int kk = 0; kk < 16; ++kk) {
      const float4 a4 = *(const float4*)(&As[kk][ty << 2]);
      const float4 b4 = *(const float4*)(&Bs[kk][tx << 2]);
      const float aa[4] = {a4.x, a4.y, a4.z, a4.w};
      const float bb4[4] = {b4.x, b4.y, b4.z, b4.w};
#pragma unroll
      for (int i = 0; i < 4; ++i)
#pragma unroll
        for (int j = 0; j < 4; ++j)
          acc[i][j] = fmaf(aa[i], bb4[j], acc[i][j]);
    }
    __syncthreads();
  }
#pragma unroll
  for (int i = 0; i < 4; ++i) {
#pragma unroll
    for (int j = 0; j < 4; ++j) {
      float v = acc[i][j] + bias[nTile + (tx << 2) + j];
      acc[i][j] = fmaxf(v, 0.0f);
    }
    *(float4*)(C + (size_t)(mTile + (ty << 2) + i) * HID + nTile + (tx << 2)) =
        make_float4(acc[i][0], acc[i][1], acc[i][2], acc[i][3]);
  }
}

// ------------------- heads: cls+box dots, softmax, decode, candidate arrays
// Candidate layout is CLASS-MAJOR: index = n*MCAND + (k-1)*SPROP + s
__global__ __launch_bounds__(128) void heads_kernel(
    const float* __restrict__ H2m, const float* __restrict__ wc,
    const float* __restrict__ bc, const float* __restrict__ wb,
    const float* __restrict__ bb, const float* __restrict__ props,
    float* __restrict__ BX2, float* __restrict__ NB2,
    float* __restrict__ LV2) {
  const int r = blockIdx.x;
  const int tid = threadIdx.x;
  __shared__ float hrow[HID];
  __shared__ float vals[112];
  __shared__ float red[2];

  for (int i = tid; i < HID; i += 128) hrow[i] = H2m[(size_t)r * HID + i];
  __syncthreads();

  if (tid < 105) {
    float acc;
    if (tid < NCLS) {
      acc = bc[tid];
      for (int kk = 0; kk < HID; ++kk) acc = fmaf(hrow[kk], wc[kk * NCLS + tid], acc);
    } else {
      const int j = tid - NCLS;
      acc = bb[j];
      for (int kk = 0; kk < HID; ++kk) acc = fmaf(hrow[kk], wb[kk * (NCLS * 4) + j], acc);
    }
    vals[tid] = acc;
  }
  __syncthreads();

  if (tid == 0) {
    float m = vals[0];
    for (int k = 1; k < NCLS; ++k) m = fmaxf(m, vals[k]);
    float s = 0.0f;
    for (int k = 0; k < NCLS; ++k) s += expf(vals[k] - m);
    red[0] = m;
    red[1] = 1.0f / s;
  }
  __syncthreads();

  if (tid >= 1 && tid <= 20) {
    const int k = tid;
    const float prob = expf(vals[k] - red[0]) * red[1];

    const float px1 = props[r * 4 + 0], py1 = props[r * 4 + 1];
    const float px2 = props[r * 4 + 2], py2 = props[r * 4 + 3];
    const float pw = px2 - px1, ph = py2 - py1;
    const float pcx = px1 + 0.5f * pw, pcy = py1 + 0.5f * ph;

    const float dx = vals[NCLS + k * 4 + 0] / 10.0f;
    const float dy = vals[NCLS + k * 4 + 1] / 10.0f;
    const float dw = fminf(vals[NCLS + k * 4 + 2] / 5.0f, LOGMAX);
    const float dh = fminf(vals[NCLS + k * 4 + 3] / 5.0f, LOGMAX);

    const float cx = dx * pw + pcx, cy = dy * ph + pcy;
    const float w = expf(dw) * pw, h = expf(dh) * ph;
    float b0 = cx - 0.5f * w, b1c = cy - 0.5f * h;
    float b2 = cx + 0.5f * w, b3 = cy + 0.5f * h;
    b0 = fminf(fmaxf(b0, 0.0f), IMGSZ);
    b1c = fminf(fmaxf(b1c, 0.0f), IMGSZ);
    b2 = fminf(fmaxf(b2, 0.0f), IMGSZ);
    b3 = fminf(fmaxf(b3, 0.0f), IMGSZ);

    const float wv = b2 - b0, hv = b3 - b1c;
    const bool valid = (prob > 0.05f) && (wv >= 0.01f) && (hv >= 0.01f);

    const int n = r >> 9, s = r & 511;
    const int cand = (k - 1) * SPROP + s;     // class-major
    const size_t bi = (size_t)n * MCAND + cand;
    const float off = (float)k * (IMGSZ + 1.0f);

    BX2[bi * 4 + 0] = b0; BX2[bi * 4 + 1] = b1c;
    BX2[bi * 4 + 2] = b2; BX2[bi * 4 + 3] = b3;
    NB2[bi * 4 + 0] = b0 + off; NB2[bi * 4 + 1] = b1c + off;
    NB2[bi * 4 + 2] = b2 + off; NB2[bi * 4 + 3] = b3 + off;
    LV2[bi] = valid ? prob : -1.0f;
  }
}

// ---------------------------------------------- per-(image,class) greedy NMS
// Cross-class IoU == 0 (801*k offsets), so the global greedy restricted to a
// class equals the standalone per-class greedy (proved by induction on picks).
// One wave per (n,c): 512 slots in registers, barrier-free serial loop.
template <int CTRL>
__device__ __forceinline__ void red2(float& v, int& ix) {
  const float tv = __int_as_float(__builtin_amdgcn_update_dpp(
      (int)0xC0000000, __float_as_int(v), CTRL, 0xf, 0xf, false));
  const int ti = __builtin_amdgcn_update_dpp(0x7fffffff, ix, CTRL, 0xf, 0xf, false);
  if (tv > v || (tv == v && ti < ix)) { v = tv; ix = ti; }
}
__device__ __forceinline__ void wave_red2(float& v, int& ix) {
  red2<0x111>(v, ix);  // row_shr:1
  red2<0x112>(v, ix);  // row_shr:2
  red2<0x114>(v, ix);  // row_shr:4
  red2<0x118>(v, ix);  // row_shr:8
  red2<0x142>(v, ix);  // row_bcast:15
  red2<0x143>(v, ix);  // row_bcast:31 -> lane 63 holds winner
}

__global__ __launch_bounds__(64) void nms_class_kernel(
    const float* __restrict__ NB2, const float* __restrict__ LV2,
    float* __restrict__ ksg, int* __restrict__ kig, int* __restrict__ cntg) {
  const int bid = blockIdx.x;           // n*20 + c
  const int lane = threadIdx.x;         // 0..63
  __shared__ float4 lbox[SPROP];        // winner-broadcast copy
  const size_t cb = (size_t)bid * SPROP;

  float lv[8], b0[8], b1[8], b2[8], b3[8], ar[8];
#pragma unroll
  for (int j = 0; j < 8; ++j) {
    const int s = lane + j * 64;
    lv[j] = LV2[cb + s];
    const float4 b = *(const float4*)(NB2 + (cb + s) * 4);
    b0[j] = b.x; b1[j] = b.y; b2[j] = b.z; b3[j] = b.w;
    ar[j] = (b.z - b.x) * (b.w - b.y);
    lbox[s] = b;
  }

  int cnt = 0;
  for (int d = 0; d < NDET; ++d) {
    float bv = -2.0f;
    int bix = 0x7fffffff;
#pragma unroll
    for (int j = 0; j < 8; ++j) {     // j asc => slot asc; strict > keeps lowest
      if (lv[j] > bv) { bv = lv[j]; bix = lane + j * 64; }
    }
    wave_red2(bv, bix);
    const float bv2 = __shfl(bv, 63);
    const int bix2 = __shfl(bix, 63);
    if (bv2 <= 0.05f) break;          // all remaining dead; wave-uniform

    if (lane == 0) {
      ksg[bid * NDET + cnt] = bv2;
      kig[bid * NDET + cnt] = bix2;   // slot within class (0..511)
    }
    ++cnt;

    const float4 wb = lbox[bix2];     // same-wave LDS write->read, waitcnt ok
    const float wa = (wb.z - wb.x) * (wb.w - wb.y);
#pragma unroll
    for (int j = 0; j < 8; ++j) {
      const float xx1 = fmaxf(wb.x, b0[j]);
      const float yy1 = fmaxf(wb.y, b1[j]);
      const float xx2 = fminf(wb.z, b2[j]);
      const float yy2 = fminf(wb.w, b3[j]);
      const float inter = fmaxf(xx2 - xx1, 0.0f) * fmaxf(yy2 - yy1, 0.0f);
      const float iou = inter / (wa + ar[j] - inter + 1e-9f);
      if (iou > 0.5f) lv[j] = -1.0f;
    }
  }
  if (lane == 0) cntg[bid] = cnt;
}

// ------------------------------- merge: top-100 by (score desc, flat-idx asc)
// Global greedy order == keeps sorted by packed priority (scores non-increasing
// along greedy; tied keeps are simultaneously live so argmax first-index rule
// = lowest flat idx). Rank-based selection: zero barriers in the hot loop.
__global__ __launch_bounds__(1024) void nms_merge_kernel(
    const float* __restrict__ ksg, const int* __restrict__ kig,
    const int* __restrict__ cntg, const float* __restrict__ BX2,
    float* __restrict__ out) {
  const int n = blockIdx.x;
  const int tid = threadIdx.x;
  __shared__ int cbase[21];
  __shared__ unsigned long long keys[2000];
  __shared__ float ssc[2000];
  __shared__ int sfl[2000];
  __shared__ float svals[NDET];
  __shared__ int sflat[NDET];

  if (tid == 0) {
    int acc = 0;
    for (int c = 0; c < 20; ++c) { cbase[c] = acc; acc += cntg[n * 20 + c]; }
    cbase[20] = acc;
  }
  __syncthreads();
  const int T = cbase[20];     // <= 2000

  for (int idx = tid; idx < 20 * NDET; idx += 1024) {
    const int c = idx / NDET, e = idx - (idx / NDET) * NDET;
    if (e < cntg[n * 20 + c]) {
      const int pos = cbase[c] + e;
      const float s = ksg[(n * 20 + c) * NDET + e];
      const int slot = kig[(n * 20 + c) * NDET + e];
      const int flat = slot * 20 + c;            // original flat candidate idx
      ssc[pos] = s;
      sfl[pos] = flat;
      keys[pos] = ((unsigned long long)__float_as_uint(s) << 32) |
                  (unsigned long long)(0xFFFFFFFFu - (unsigned)flat);
    }
  }
  __syncthreads();

  float msc[2]; int mfl[2]; unsigned long long mk[2]; int rank[2] = {0, 0};
  bool own[2];
#pragma unroll
  for (int e = 0; e < 2; ++e) {
    const int i = tid + e * 1024;
    own[e] = (i < T);
    if (own[e]) { mk[e] = keys[i]; msc[e] = ssc[i]; mfl[e] = sfl[i]; }
  }
  for (int i = 0; i < T; ++i) {        // LDS broadcast read per iteration
    const unsigned long long k = keys[i];
    if (own[0] && k > mk[0]) ++rank[0];
    if (own[1] && k > mk[1]) ++rank[1];
  }
#pragma unroll
  for (int e = 0; e < 2; ++e)
    if (own[e] && rank[e] < NDET) { svals[rank[e]] = msc[e]; sflat[rank[e]] = mfl[e]; }
  __syncthreads();

  if (tid < NDET) {
    const int m = (T < NDET) ? T : NDET;
    const bool keep = tid < m;
    float sv = 0.0f;
    float4 bx4 = make_float4(0.0f, 0.0f, 0.0f, 0.0f);
    float label = 0.0f;
    if (keep) {
      sv = svals[tid];
      const int flat = sflat[tid];
      const int c = flat % 20, s = flat / 20;
      bx4 = *(const float4*)(BX2 + ((size_t)(n * 20 + c) * SPROP + s) * 4);
      label = (float)(c + 1);
    }
    out[(n * NDET + tid) * 4 + 0] = bx4.x;
    out[(n * NDET + tid) * 4 + 1] = bx4.y;
    out[(n * NDET + tid) * 4 + 2] = bx4.z;
    out[(n * NDET + tid) * 4 + 3] = bx4.w;
    out[NIMG * NDET * 4 + n * NDET + tid] = sv;
    out[NIMG * NDET * 4 + NIMG * NDET + n * NDET + tid] = label;
  }
}

// ---------------------------------------------------------------- launcher
extern "C" void kernel_launch(void* const* d_in, const int* in_sizes, int n_in,
                              void* d_out, int out_size, void* d_ws, size_t ws_size,
                              hipStream_t stream) {
  const float* features  = (const float*)d_in[0];
  const float* proposals = (const float*)d_in[1];
  const float* w1 = (const float*)d_in[2];
  const float* b1 = (const float*)d_in[3];
  const float* w2 = (const float*)d_in[4];
  const float* b2 = (const float*)d_in[5];
  const float* wc = (const float*)d_in[6];
  const float* bc = (const float*)d_in[7];
  const float* wb = (const float*)d_in[8];
  const float* bb = (const float*)d_in[9];

  const size_t XE = (size_t)NROI * K1;
  const size_t WE = (size_t)K1 * HID;
  const size_t FLOATS_TAIL =
      (size_t)ZSPLIT * NROI * HID + 2 * (size_t)NROI * HID + (size_t)NIMG * MCAND * 10;
  const size_t NEED = (XE * 2 + WE * 2) * sizeof(u16) + FLOATS_TAIL * sizeof(float);

  if (ws_size >= NEED) {
    u16* Xhi = (u16*)d_ws;
    u16* Xlo = Xhi + XE;
    u16* Wh  = Xlo + XE;
    u16* Wl  = Wh + WE;
    float* CP  = (float*)(Wl + WE);
    float* H1  = CP + (size_t)ZSPLIT * NROI * HID;
    float* H2  = H1 + (size_t)NROI * HID;
    float* BX2 = H2 + (size_t)NROI * HID;
    float* NB2 = BX2 + (size_t)NIMG * MCAND * 4;
    float* LV2 = NB2 + (size_t)NIMG * MCAND * 4;
    float* ksg = LV2 + (size_t)NIMG * MCAND;
    int*   kig = (int*)(ksg + (size_t)NIMG * 20 * NDET);
    int*   cntg = kig + (size_t)NIMG * 20 * NDET;

    convw1_kernel<<<dim3(K1 / 64, HID / 64), 256, 0, stream>>>(w1, Wh, Wl);
    roi_kernel<true><<<NROI, 256, 0, stream>>>(features, proposals, nullptr, Xhi, Xlo);
    gemm1_mfma<<<dim3(8, 8, ZSPLIT), 256, 0, stream>>>(Xhi, Xlo, Wh, Wl, CP);
    bias_relu_kernel<<<(NROI * HID) / 256, 256, 0, stream>>>(CP, b1, H1);
    gemm2_kernel<<<dim3(16, 16), 256, 0, stream>>>(H1, w2, b2, H2);
    heads_kernel<<<NROI, 128, 0, stream>>>(H2, wc, bc, wb, bb, proposals,
                                           BX2, NB2, LV2);
    nms_class_kernel<<<NIMG * 20, 64, 0, stream>>>(NB2, LV2, ksg, kig, cntg);
    nms_merge_kernel<<<NIMG, 1024, 0, stream>>>(ksg, kig, cntg, BX2,
                                                (float*)d_out);
  } else {
    float* ws = (float*)d_ws;
    float* X   = ws;
    float* CP  = X + XE;
    float* H1  = CP + (size_t)ZSPLIT * NROI * HID;
    float* H2  = H1 + (size_t)NROI * HID;
    float* BX2 = H2 + (size_t)NROI * HID;
    float* NB2 = BX2 + (size_t)NIMG * MCAND * 4;
    float* LV2 = NB2 + (size_t)NIMG * MCAND * 4;
    float* ksg = LV2 + (size_t)NIMG * MCAND;
    int*   kig = (int*)(ksg + (size_t)NIMG * 20 * NDET);
    int*   cntg = kig + (size_t)NIMG * 20 * NDET;

    roi_kernel<false><<<NROI, 256, 0, stream>>>(features, proposals, X, nullptr, nullptr);
    gemm1_kernel<<<dim3(16, 16, ZSPLIT), 256, 0, stream>>>(X, w1, CP);
    bias_relu_kernel<<<(NROI * HID) / 256, 256, 0, stream>>>(CP, b1, H1);
    gemm2_kernel<<<dim3(16, 16), 256, 0, stream>>>(H1, w2, b2, H2);
    heads_kernel<<<NROI, 128, 0, stream>>>(H2, wc, bc, wb, bb, proposals,
                                           BX2, NB2, LV2);
    nms_class_kernel<<<NIMG * 20, 64, 0, stream>>>(NB2, LV2, ksg, kig, cntg);
    nms_merge_kernel<<<NIMG, 1024, 0, stream>>>(ksg, kig, cntg, BX2,
                                                (float*)d_out);
  }
}

// Round 8
// 906.581 us; speedup vs baseline: 1.9262x; 1.0002x over previous
//
#include <hip/hip_runtime.h>
#include <cmath>

// Problem constants (N=2, S=512, C=512, H=W=50, OUT=7, RATIO=2)
#define NIMG 2
#define SPROP 512
#define NROI 1024          // NIMG*SPROP
#define CCH 512
#define FH 50
#define FW 50
#define K1 25088           // CCH*7*7
#define HID 1024
#define NCLS 21
#define NDET 100
#define IMGSZ 800.0f
#define LOGMAX 4.135166556742356f   // log(1000/16)
#define MCAND 10240        // SPROP*(NCLS-1)
#define ZSPLIT 8
#define KCHUNK 3136        // K1/ZSPLIT

typedef unsigned short u16;
typedef __attribute__((ext_vector_type(8))) short short8;
typedef __attribute__((ext_vector_type(4))) float f32x4;
typedef __attribute__((ext_vector_type(16))) float f32x16;

__device__ __forceinline__ u16 f2bf(float x) {        // RTNE fp32 -> bf16
  unsigned int u = __float_as_uint(x);
  u += 0x7fffu + ((u >> 16) & 1u);
  return (u16)(u >> 16);
}
__device__ __forceinline__ float bf2f(u16 h) {
  return __uint_as_float(((unsigned int)h) << 16);
}

// ------------------------------------------------------------ ROI align
template <bool BF16OUT>
__global__ __launch_bounds__(256) void roi_kernel(
    const float* __restrict__ feat, const float* __restrict__ props,
    float* __restrict__ X, u16* __restrict__ Xhi, u16* __restrict__ Xlo) {
  const int r = blockIdx.x;
  const int n = r >> 9;
  const int tid = threadIdx.x;
  __shared__ float tile[32][256];   // 32 ch x (16x16 px) = 32 KB
  __shared__ int sy0[14], sy1[14], sx0[14], sx1[14];
  __shared__ float sly[14], slx[14], svy[14], svx[14];

  const float p0 = props[r * 4 + 0] * 0.0625f;
  const float p1 = props[r * 4 + 1] * 0.0625f;
  const float p2 = props[r * 4 + 2] * 0.0625f;
  const float p3 = props[r * 4 + 3] * 0.0625f;
  const float bw = fmaxf(p2 - p0, 1.0f) / 7.0f;
  const float bh = fmaxf(p3 - p1, 1.0f) / 7.0f;

  if (tid < 14) {
    const int j = tid;
    const float g = (float)(j >> 1) + ((float)(j & 1) + 0.5f) * 0.5f;
    float y = p1 + g * bh;
    svy[j] = (y > -1.0f && y < (float)FH) ? 1.0f : 0.0f;
    float yc = fminf(fmaxf(y, 0.0f), (float)(FH - 1));
    int y0 = (int)floorf(yc);
    sy0[j] = y0; sy1[j] = min(y0 + 1, FH - 1); sly[j] = yc - (float)y0;
    float x = p0 + g * bw;
    svx[j] = (x > -1.0f && x < (float)FW) ? 1.0f : 0.0f;
    float xc = fminf(fmaxf(x, 0.0f), (float)(FW - 1));
    int x0 = (int)floorf(xc);
    sx0[j] = x0; sx1[j] = min(x0 + 1, FW - 1); slx[j] = xc - (float)x0;
  }
  __syncthreads();
  const int ymin = sy0[0], xmin = sx0[0];
  const float* fb = feat + (size_t)n * CCH * (FH * FW);

  for (int cc = 0; cc < 16; ++cc) {
    const int c0 = cc * 32;
#pragma unroll
    for (int e = 0; e < 32; ++e) {
      const int idx = tid + e * 256;
      const int c = idx >> 8, p = idx & 255;
      const int gy = min(ymin + (p >> 4), FH - 1);
      const int gx = min(xmin + (p & 15), FW - 1);
      tile[c][p] = fb[(size_t)(c0 + c) * (FH * FW) + gy * FW + gx];
    }
    __syncthreads();
#pragma unroll
    for (int e = 0; e < 7; ++e) {
      const int idx = tid + e * 256;
      if (idx < 1568) {
        const int c = idx / 49;
        const int s = idx - c * 49;
        const int oy = s / 7, ox = s - (s / 7) * 7;
        float acc = 0.0f;
#pragma unroll
        for (int sy = 0; sy < 2; ++sy) {
          const int yj = oy * 2 + sy;
          const int py0 = sy0[yj] - ymin, py1 = sy1[yj] - ymin;
          const float ly = sly[yj], vy = svy[yj];
#pragma unroll
          for (int sx = 0; sx < 2; ++sx) {
            const int xj = ox * 2 + sx;
            const int px0 = sx0[xj] - xmin, px1 = sx1[xj] - xmin;
            const float lx = slx[xj], vx = svx[xj];
            const float f00 = tile[c][py0 * 16 + px0];
            const float f01 = tile[c][py0 * 16 + px1];
            const float f10 = tile[c][py1 * 16 + px0];
            const float f11 = tile[c][py1 * 16 + px1];
            float v = f00 * (1.0f - ly) * (1.0f - lx) + f01 * (1.0f - ly) * lx +
                      f10 * ly * (1.0f - lx) + f11 * ly * lx;
            acc += v * (vy * vx);
          }
        }
        const float v = acc * 0.25f;
        const size_t k = (size_t)r * K1 + (size_t)(c0 + c) * 49 + s;
        if (BF16OUT) {
          const u16 h = f2bf(v);
          Xhi[k] = h;
          Xlo[k] = f2bf(v - bf2f(h));
        } else {
          X[k] = v;
        }
      }
    }
    __syncthreads();
  }
}

// ------------------------- w1 -> hi/lo bf16, transposed to [n][k]
__global__ __launch_bounds__(256) void convw1_kernel(
    const float* __restrict__ w1, u16* __restrict__ Wh, u16* __restrict__ Wl) {
  __shared__ u16 sh[64][65], sl[64][65];
  const int k0 = blockIdx.x * 64;
  const int n0 = blockIdx.y * 64;
  const int t = threadIdx.x;
#pragma unroll
  for (int e = 0; e < 16; ++e) {
    const int idx = t + e * 256;
    const int kl = idx >> 6, nl = idx & 63;
    const float v = w1[(size_t)(k0 + kl) * HID + n0 + nl];
    const u16 h = f2bf(v);
    sh[kl][nl] = h;
    sl[kl][nl] = f2bf(v - bf2f(h));
  }
  __syncthreads();
#pragma unroll
  for (int e = 0; e < 16; ++e) {
    const int idx = t + e * 256;
    const int nl = idx >> 6, kl = idx & 63;
    Wh[(size_t)(n0 + nl) * K1 + k0 + kl] = sh[kl][nl];
    Wl[(size_t)(n0 + nl) * K1 + k0 + kl] = sl[kl][nl];
  }
}

// --------------- FC1: split-bf16 MFMA GEMM (32x32x16), K-split z=8
// v2: mfma_f32_32x32x16_bf16 doubles FLOP per LDS byte vs 16x16x32 —
// round-7 counters showed LDS-BW-bound (MfmaUtil 32%, LDS 1850 cyc vs MFMA
// 1623 cyc per CU-K-step). Wave = 64x64 as 2x2 tiles of 32x32.
// A/B frag: [row = lane&31][k = (lane>>5)*8 + j] (analog of verified 16x16).
// C/D: col = lane&31, row = (reg&3) + 8*(reg>>2) + 4*(lane>>5)  [m74/m101].
__global__ __launch_bounds__(256, 2) void gemm1_mfma(
    const u16* __restrict__ Ahg, const u16* __restrict__ Alg,
    const u16* __restrict__ Bhg, const u16* __restrict__ Blg,
    float* __restrict__ CP) {
  __shared__ u16 Ah[128][40], Al[128][40], Bh[128][40], Bl[128][40];
  const int tid = threadIdx.x;
  const int lane = tid & 63;
  const int wv = tid >> 6;
  const int wm = (wv >> 1) * 64;
  const int wn = (wv & 1) * 64;
  const int mT = blockIdx.y << 7;
  const int nT = blockIdx.x << 7;
  const int kz = blockIdx.z * KCHUNK;

  const int r0 = tid >> 2, q0 = (tid & 3) << 3;
  const int r1 = r0 + 64;

  f32x16 acc[2][2];
#pragma unroll
  for (int i = 0; i < 2; ++i)
#pragma unroll
    for (int j = 0; j < 2; ++j)
#pragma unroll
      for (int e = 0; e < 16; ++e) acc[i][j][e] = 0.0f;

  const size_t a0off = (size_t)(mT + r0) * K1 + q0;
  const size_t a1off = (size_t)(mT + r1) * K1 + q0;
  const size_t b0off = (size_t)(nT + r0) * K1 + q0;
  const size_t b1off = (size_t)(nT + r1) * K1 + q0;

  const int fm = lane & 31;          // row within 32-tile
  const int fq = (lane >> 5) << 3;   // k-subgroup offset (0 or 8)

  for (int kb = kz; kb < kz + KCHUNK; kb += 32) {
    const uint4 va0 = *(const uint4*)(Ahg + a0off + kb);
    const uint4 va1 = *(const uint4*)(Ahg + a1off + kb);
    const uint4 vl0 = *(const uint4*)(Alg + a0off + kb);
    const uint4 vl1 = *(const uint4*)(Alg + a1off + kb);
    const uint4 vb0 = *(const uint4*)(Bhg + b0off + kb);
    const uint4 vb1 = *(const uint4*)(Bhg + b1off + kb);
    const uint4 vm0 = *(const uint4*)(Blg + b0off + kb);
    const uint4 vm1 = *(const uint4*)(Blg + b1off + kb);
    *(uint4*)(&Ah[r0][q0]) = va0;
    *(uint4*)(&Ah[r1][q0]) = va1;
    *(uint4*)(&Al[r0][q0]) = vl0;
    *(uint4*)(&Al[r1][q0]) = vl1;
    *(uint4*)(&Bh[r0][q0]) = vb0;
    *(uint4*)(&Bh[r1][q0]) = vb1;
    *(uint4*)(&Bl[r0][q0]) = vm0;
    *(uint4*)(&Bl[r1][q0]) = vm1;
    __syncthreads();

#pragma unroll
    for (int kh = 0; kh < 2; ++kh) {
      const int ko = kh * 16 + fq;
      short8 fah[2], fal[2], fbh[2], fbl[2];
#pragma unroll
      for (int t = 0; t < 2; ++t) {
        fah[t] = *(const short8*)(&Ah[wm + t * 32 + fm][ko]);
        fal[t] = *(const short8*)(&Al[wm + t * 32 + fm][ko]);
        fbh[t] = *(const short8*)(&Bh[wn + t * 32 + fm][ko]);
        fbl[t] = *(const short8*)(&Bl[wn + t * 32 + fm][ko]);
      }
#pragma unroll
      for (int ti = 0; ti < 2; ++ti)
#pragma unroll
        for (int tj = 0; tj < 2; ++tj) {
          acc[ti][tj] = __builtin_amdgcn_mfma_f32_32x32x16_bf16(
              fah[ti], fbh[tj], acc[ti][tj], 0, 0, 0);
          acc[ti][tj] = __builtin_amdgcn_mfma_f32_32x32x16_bf16(
              fah[ti], fbl[tj], acc[ti][tj], 0, 0, 0);
          acc[ti][tj] = __builtin_amdgcn_mfma_f32_32x32x16_bf16(
              fal[ti], fbh[tj], acc[ti][tj], 0, 0, 0);
        }
    }
    __syncthreads();
  }

  float* Cp = CP + (size_t)blockIdx.z * ((size_t)NROI * HID);
  const int ccol = nT + wn + (lane & 31);
  const int rbase = mT + wm + 4 * (lane >> 5);
#pragma unroll
  for (int ti = 0; ti < 2; ++ti)
#pragma unroll
    for (int tj = 0; tj < 2; ++tj)
#pragma unroll
      for (int rg = 0; rg < 16; ++rg) {
        const int row = rbase + ti * 32 + (rg & 3) + 8 * (rg >> 2);
        Cp[(size_t)row * HID + ccol + tj * 32] = acc[ti][tj][rg];
      }
}

// ------------------------------------------------------- FC1 fallback (fp32)
__global__ __launch_bounds__(256) void gemm1_kernel(
    const float* __restrict__ A, const float* __restrict__ B,
    float* __restrict__ CP) {
  __shared__ float As[16][68];
  __shared__ float Bs[16][68];
  const int tid = threadIdx.x;
  const int mTile = blockIdx.y << 6;
  const int nTile = blockIdx.x << 6;
  const int k0 = blockIdx.z * KCHUNK;
  const int ty = tid >> 4, tx = tid & 15;
  const int ar = tid >> 2, ac = (tid & 3) << 2;
  const int br = tid >> 4, bcl = (tid & 15) << 2;
  float acc[4][4] = {};

  for (int kb = k0; kb < k0 + KCHUNK; kb += 16) {
    const float4 av = *(const float4*)(A + (size_t)(mTile + ar) * K1 + kb + ac);
    const float4 bv = *(const float4*)(B + (size_t)(kb + br) * HID + nTile + bcl);
    As[ac + 0][ar] = av.x; As[ac + 1][ar] = av.y;
    As[ac + 2][ar] = av.z; As[ac + 3][ar] = av.w;
    *(float4*)(&Bs[br][bcl]) = bv;
    __syncthreads();
#pragma unroll
    for (int kk = 0; kk < 16; ++kk) {
      const float4 a4 = *(const float4*)(&As[kk][ty << 2]);
      const float4 b4 = *(const float4*)(&Bs[kk][tx << 2]);
      const float aa[4] = {a4.x, a4.y, a4.z, a4.w};
      const float bb4[4] = {b4.x, b4.y, b4.z, b4.w};
#pragma unroll
      for (int i = 0; i < 4; ++i)
#pragma unroll
        for (int j = 0; j < 4; ++j)
          acc[i][j] = fmaf(aa[i], bb4[j], acc[i][j]);
    }
    __syncthreads();
  }
  float* Cp = CP + (size_t)blockIdx.z * (HID * NROI);
#pragma unroll
  for (int i = 0; i < 4; ++i) {
    *(float4*)(Cp + (size_t)(mTile + (ty << 2) + i) * HID + nTile + (tx << 2)) =
        make_float4(acc[i][0], acc[i][1], acc[i][2], acc[i][3]);
  }
}

// reduce 8 K-partials + bias + relu
__global__ __launch_bounds__(256) void bias_relu_kernel(
    const float* __restrict__ CP, const float* __restrict__ b1,
    float* __restrict__ H1) {
  const int idx = blockIdx.x * 256 + threadIdx.x;
  float v = b1[idx & (HID - 1)];
#pragma unroll
  for (int z = 0; z < ZSPLIT; ++z) v += CP[(size_t)z * (HID * NROI) + idx];
  H1[idx] = fmaxf(v, 0.0f);
}

// ------------------------------------------------------------- FC2 (K=1024)
__global__ __launch_bounds__(256) void gemm2_kernel(
    const float* __restrict__ A, const float* __restrict__ B,
    const float* __restrict__ bias, float* __restrict__ C) {
  __shared__ float As[16][68];
  __shared__ float Bs[16][68];
  const int tid = threadIdx.x;
  const int mTile = blockIdx.y << 6;
  const int nTile = blockIdx.x << 6;
  const int ty = tid >> 4, tx = tid & 15;
  const int ar = tid >> 2, ac = (tid & 3) << 2;
  const int br = tid >> 4, bcl = (tid & 15) << 2;
  float acc[4][4] = {};

  for (int kb = 0; kb < HID; kb += 16) {
    const float4 av = *(const float4*)(A + (size_t)(mTile + ar) * HID + kb + ac);
    const float4 bv = *(const float4*)(B + (size_t)(kb + br) * HID + nTile + bcl);
    As[ac + 0][ar] = av.x; As[ac + 1][ar] = av.y;
    As[ac + 2][ar] = av.z; As[ac + 3][ar] = av.w;
    *(float4*)(&Bs[br][bcl]) = bv;
    __syncthreads();
#pragma unroll
    for (int kk = 0; kk < 16; ++kk) {
      const float4 a4 = *(const float4*)(&As[kk][ty << 2]);
      const float4 b4 = *(const float4*)(&Bs[kk][tx << 2]);
      const float aa[4] = {a4.x, a4.y, a4.z, a4.w};
      const float bb4[4] = {b4.x, b4.y, b4.z, b4.w};
#pragma unroll
      for (int i = 0; i < 4; ++i)
#pragma unroll
        for (int j = 0; j < 4; ++j)
          acc[i][j] = fmaf(aa[i], bb4[j], acc[i][j]);
    }
    __syncthreads();
  }
#pragma unroll
  for (int i = 0; i < 4; ++i) {
#pragma unroll
    for (int j = 0; j < 4; ++j) {
      float v = acc[i][j] + bias[nTile + (tx << 2) + j];
      acc[i][j] = fmaxf(v, 0.0f);
    }
    *(float4*)(C + (size_t)(mTile + (ty << 2) + i) * HID + nTile + (tx << 2)) =
        make_float4(acc[i][0], acc[i][1], acc[i][2], acc[i][3]);
  }
}

// ------------------- heads: cls+box dots, softmax, decode, candidate arrays
// Candidate layout is CLASS-MAJOR: index = n*MCAND + (k-1)*SPROP + s
__global__ __launch_bounds__(128) void heads_kernel(
    const float* __restrict__ H2m, const float* __restrict__ wc,
    const float* __restrict__ bc, const float* __restrict__ wb,
    const float* __restrict__ bb, const float* __restrict__ props,
    float* __restrict__ BX2, float* __restrict__ NB2,
    float* __restrict__ LV2) {
  const int r = blockIdx.x;
  const int tid = threadIdx.x;
  __shared__ float hrow[HID];
  __shared__ float vals[112];
  __shared__ float red[2];

  for (int i = tid; i < HID; i += 128) hrow[i] = H2m[(size_t)r * HID + i];
  __syncthreads();

  if (tid < 105) {
    float acc;
    if (tid < NCLS) {
      acc = bc[tid];
      for (int kk = 0; kk < HID; ++kk) acc = fmaf(hrow[kk], wc[kk * NCLS + tid], acc);
    } else {
      const int j = tid - NCLS;
      acc = bb[j];
      for (int kk = 0; kk < HID; ++kk) acc = fmaf(hrow[kk], wb[kk * (NCLS * 4) + j], acc);
    }
    vals[tid] = acc;
  }
  __syncthreads();

  if (tid == 0) {
    float m = vals[0];
    for (int k = 1; k < NCLS; ++k) m = fmaxf(m, vals[k]);
    float s = 0.0f;
    for (int k = 0; k < NCLS; ++k) s += expf(vals[k] - m);
    red[0] = m;
    red[1] = 1.0f / s;
  }
  __syncthreads();

  if (tid >= 1 && tid <= 20) {
    const int k = tid;
    const float prob = expf(vals[k] - red[0]) * red[1];

    const float px1 = props[r * 4 + 0], py1 = props[r * 4 + 1];
    const float px2 = props[r * 4 + 2], py2 = props[r * 4 + 3];
    const float pw = px2 - px1, ph = py2 - py1;
    const float pcx = px1 + 0.5f * pw, pcy = py1 + 0.5f * ph;

    const float dx = vals[NCLS + k * 4 + 0] / 10.0f;
    const float dy = vals[NCLS + k * 4 + 1] / 10.0f;
    const float dw = fminf(vals[NCLS + k * 4 + 2] / 5.0f, LOGMAX);
    const float dh = fminf(vals[NCLS + k * 4 + 3] / 5.0f, LOGMAX);

    const float cx = dx * pw + pcx, cy = dy * ph + pcy;
    const float w = expf(dw) * pw, h = expf(dh) * ph;
    float b0 = cx - 0.5f * w, b1c = cy - 0.5f * h;
    float b2 = cx + 0.5f * w, b3 = cy + 0.5f * h;
    b0 = fminf(fmaxf(b0, 0.0f), IMGSZ);
    b1c = fminf(fmaxf(b1c, 0.0f), IMGSZ);
    b2 = fminf(fmaxf(b2, 0.0f), IMGSZ);
    b3 = fminf(fmaxf(b3, 0.0f), IMGSZ);

    const float wv = b2 - b0, hv = b3 - b1c;
    const bool valid = (prob > 0.05f) && (wv >= 0.01f) && (hv >= 0.01f);

    const int n = r >> 9, s = r & 511;
    const int cand = (k - 1) * SPROP + s;     // class-major
    const size_t bi = (size_t)n * MCAND + cand;
    const float off = (float)k * (IMGSZ + 1.0f);

    BX2[bi * 4 + 0] = b0; BX2[bi * 4 + 1] = b1c;
    BX2[bi * 4 + 2] = b2; BX2[bi * 4 + 3] = b3;
    NB2[bi * 4 + 0] = b0 + off; NB2[bi * 4 + 1] = b1c + off;
    NB2[bi * 4 + 2] = b2 + off; NB2[bi * 4 + 3] = b3 + off;
    LV2[bi] = valid ? prob : -1.0f;
  }
}

// ---------------------------------------------- per-(image,class) greedy NMS
// Cross-class IoU == 0 (801*k offsets), so the global greedy restricted to a
// class equals the standalone per-class greedy (proved by induction on picks).
// One wave per (n,c): 512 slots in registers, barrier-free serial loop.
template <int CTRL>
__device__ __forceinline__ void red2(float& v, int& ix) {
  const float tv = __int_as_float(__builtin_amdgcn_update_dpp(
      (int)0xC0000000, __float_as_int(v), CTRL, 0xf, 0xf, false));
  const int ti = __builtin_amdgcn_update_dpp(0x7fffffff, ix, CTRL, 0xf, 0xf, false);
  if (tv > v || (tv == v && ti < ix)) { v = tv; ix = ti; }
}
__device__ __forceinline__ void wave_red2(float& v, int& ix) {
  red2<0x111>(v, ix);  // row_shr:1
  red2<0x112>(v, ix);  // row_shr:2
  red2<0x114>(v, ix);  // row_shr:4
  red2<0x118>(v, ix);  // row_shr:8
  red2<0x142>(v, ix);  // row_bcast:15
  red2<0x143>(v, ix);  // row_bcast:31 -> lane 63 holds winner
}

__global__ __launch_bounds__(64) void nms_class_kernel(
    const float* __restrict__ NB2, const float* __restrict__ LV2,
    float* __restrict__ ksg, int* __restrict__ kig, int* __restrict__ cntg) {
  const int bid = blockIdx.x;           // n*20 + c
  const int lane = threadIdx.x;         // 0..63
  __shared__ float4 lbox[SPROP];        // winner-broadcast copy
  const size_t cb = (size_t)bid * SPROP;

  float lv[8], b0[8], b1[8], b2[8], b3[8], ar[8];
#pragma unroll
  for (int j = 0; j < 8; ++j) {
    const int s = lane + j * 64;
    lv[j] = LV2[cb + s];
    const float4 b = *(const float4*)(NB2 + (cb + s) * 4);
    b0[j] = b.x; b1[j] = b.y; b2[j] = b.z; b3[j] = b.w;
    ar[j] = (b.z - b.x) * (b.w - b.y);
    lbox[s] = b;
  }

  int cnt = 0;
  for (int d = 0; d < NDET; ++d) {
    float bv = -2.0f;
    int bix = 0x7fffffff;
#pragma unroll
    for (int j = 0; j < 8; ++j) {     // j asc => slot asc; strict > keeps lowest
      if (lv[j] > bv) { bv = lv[j]; bix = lane + j * 64; }
    }
    wave_red2(bv, bix);
    const float bv2 = __shfl(bv, 63);
    const int bix2 = __shfl(bix, 63);
    if (bv2 <= 0.05f) break;          // all remaining dead; wave-uniform

    if (lane == 0) {
      ksg[bid * NDET + cnt] = bv2;
      kig[bid * NDET + cnt] = bix2;   // slot within class (0..511)
    }
    ++cnt;

    const float4 wb = lbox[bix2];     // same-wave LDS write->read, waitcnt ok
    const float wa = (wb.z - wb.x) * (wb.w - wb.y);
#pragma unroll
    for (int j = 0; j < 8; ++j) {
      const float xx1 = fmaxf(wb.x, b0[j]);
      const float yy1 = fmaxf(wb.y, b1[j]);
      const float xx2 = fminf(wb.z, b2[j]);
      const float yy2 = fminf(wb.w, b3[j]);
      const float inter = fmaxf(xx2 - xx1, 0.0f) * fmaxf(yy2 - yy1, 0.0f);
      const float iou = inter / (wa + ar[j] - inter + 1e-9f);
      if (iou > 0.5f) lv[j] = -1.0f;
    }
  }
  if (lane == 0) cntg[bid] = cnt;
}

// ------------------------------- merge: top-100 by (score desc, flat-idx asc)
// Global greedy order == keeps sorted by packed priority (scores non-increasing
// along greedy; tied keeps are simultaneously live so argmax first-index rule
// = lowest flat idx). Rank-based selection: zero barriers in the hot loop.
__global__ __launch_bounds__(1024) void nms_merge_kernel(
    const float* __restrict__ ksg, const int* __restrict__ kig,
    const int* __restrict__ cntg, const float* __restrict__ BX2,
    float* __restrict__ out) {
  const int n = blockIdx.x;
  const int tid = threadIdx.x;
  __shared__ int cbase[21];
  __shared__ unsigned long long keys[2000];
  __shared__ float ssc[2000];
  __shared__ int sfl[2000];
  __shared__ float svals[NDET];
  __shared__ int sflat[NDET];

  if (tid == 0) {
    int acc = 0;
    for (int c = 0; c < 20; ++c) { cbase[c] = acc; acc += cntg[n * 20 + c]; }
    cbase[20] = acc;
  }
  __syncthreads();
  const int T = cbase[20];     // <= 2000

  for (int idx = tid; idx < 20 * NDET; idx += 1024) {
    const int c = idx / NDET, e = idx - (idx / NDET) * NDET;
    if (e < cntg[n * 20 + c]) {
      const int pos = cbase[c] + e;
      const float s = ksg[(n * 20 + c) * NDET + e];
      const int slot = kig[(n * 20 + c) * NDET + e];
      const int flat = slot * 20 + c;            // original flat candidate idx
      ssc[pos] = s;
      sfl[pos] = flat;
      keys[pos] = ((unsigned long long)__float_as_uint(s) << 32) |
                  (unsigned long long)(0xFFFFFFFFu - (unsigned)flat);
    }
  }
  __syncthreads();

  float msc[2]; int mfl[2]; unsigned long long mk[2]; int rank[2] = {0, 0};
  bool own[2];
#pragma unroll
  for (int e = 0; e < 2; ++e) {
    const int i = tid + e * 1024;
    own[e] = (i < T);
    if (own[e]) { mk[e] = keys[i]; msc[e] = ssc[i]; mfl[e] = sfl[i]; }
  }
  for (int i = 0; i < T; ++i) {        // LDS broadcast read per iteration
    const unsigned long long k = keys[i];
    if (own[0] && k > mk[0]) ++rank[0];
    if (own[1] && k > mk[1]) ++rank[1];
  }
#pragma unroll
  for (int e = 0; e < 2; ++e)
    if (own[e] && rank[e] < NDET) { svals[rank[e]] = msc[e]; sflat[rank[e]] = mfl[e]; }
  __syncthreads();

  if (tid < NDET) {
    const int m = (T < NDET) ? T : NDET;
    const bool keep = tid < m;
    float sv = 0.0f;
    float4 bx4 = make_float4(0.0f, 0.0f, 0.0f, 0.0f);
    float label = 0.0f;
    if (keep) {
      sv = svals[tid];
      const int flat = sflat[tid];
      const int c = flat % 20, s = flat / 20;
      bx4 = *(const float4*)(BX2 + ((size_t)(n * 20 + c) * SPROP + s) * 4);
      label = (float)(c + 1);
    }
    out[(n * NDET + tid) * 4 + 0] = bx4.x;
    out[(n * NDET + tid) * 4 + 1] = bx4.y;
    out[(n * NDET + tid) * 4 + 2] = bx4.z;
    out[(n * NDET + tid) * 4 + 3] = bx4.w;
    out[NIMG * NDET * 4 + n * NDET + tid] = sv;
    out[NIMG * NDET * 4 + NIMG * NDET + n * NDET + tid] = label;
  }
}

// ---------------------------------------------------------------- launcher
extern "C" void kernel_launch(void* const* d_in, const int* in_sizes, int n_in,
                              void* d_out, int out_size, void* d_ws, size_t ws_size,
                              hipStream_t stream) {
  const float* features  = (const float*)d_in[0];
  const float* proposals = (const float*)d_in[1];
  const float* w1 = (const float*)d_in[2];
  const float* b1 = (const float*)d_in[3];
  const float* w2 = (const float*)d_in[4];
  const float* b2 = (const float*)d_in[5];
  const float* wc = (const float*)d_in[6];
  const float* bc = (const float*)d_in[7];
  const float* wb = (const float*)d_in[8];
  const float* bb = (const float*)d_in[9];

  const size_t XE = (size_t)NROI * K1;
  const size_t WE = (size_t)K1 * HID;
  const size_t FLOATS_TAIL =
      (size_t)ZSPLIT * NROI * HID + 2 * (size_t)NROI * HID + (size_t)NIMG * MCAND * 10;
  const size_t NEED = (XE * 2 + WE * 2) * sizeof(u16) + FLOATS_TAIL * sizeof(float);

  if (ws_size >= NEED) {
    u16* Xhi = (u16*)d_ws;
    u16* Xlo = Xhi + XE;
    u16* Wh  = Xlo + XE;
    u16* Wl  = Wh + WE;
    float* CP  = (float*)(Wl + WE);
    float* H1  = CP + (size_t)ZSPLIT * NROI * HID;
    float* H2  = H1 + (size_t)NROI * HID;
    float* BX2 = H2 + (size_t)NROI * HID;
    float* NB2 = BX2 + (size_t)NIMG * MCAND * 4;
    float* LV2 = NB2 + (size_t)NIMG * MCAND * 4;
    float* ksg = LV2 + (size_t)NIMG * MCAND;
    int*   kig = (int*)(ksg + (size_t)NIMG * 20 * NDET);
    int*   cntg = kig + (size_t)NIMG * 20 * NDET;

    convw1_kernel<<<dim3(K1 / 64, HID / 64), 256, 0, stream>>>(w1, Wh, Wl);
    roi_kernel<true><<<NROI, 256, 0, stream>>>(features, proposals, nullptr, Xhi, Xlo);
    gemm1_mfma<<<dim3(8, 8, ZSPLIT), 256, 0, stream>>>(Xhi, Xlo, Wh, Wl, CP);
    bias_relu_kernel<<<(NROI * HID) / 256, 256, 0, stream>>>(CP, b1, H1);
    gemm2_kernel<<<dim3(16, 16), 256, 0, stream>>>(H1, w2, b2, H2);
    heads_kernel<<<NROI, 128, 0, stream>>>(H2, wc, bc, wb, bb, proposals,
                                           BX2, NB2, LV2);
    nms_class_kernel<<<NIMG * 20, 64, 0, stream>>>(NB2, LV2, ksg, kig, cntg);
    nms_merge_kernel<<<NIMG, 1024, 0, stream>>>(ksg, kig, cntg, BX2,
                                                (float*)d_out);
  } else {
    float* ws = (float*)d_ws;
    float* X   = ws;
    float* CP  = X + XE;
    float* H1  = CP + (size_t)ZSPLIT * NROI * HID;
    float* H2  = H1 + (size_t)NROI * HID;
    float* BX2 = H2 + (size_t)NROI * HID;
    float* NB2 = BX2 + (size_t)NIMG * MCAND * 4;
    float* LV2 = NB2 + (size_t)NIMG * MCAND * 4;
    float* ksg = LV2 + (size_t)NIMG * MCAND;
    int*   kig = (int*)(ksg + (size_t)NIMG * 20 * NDET);
    int*   cntg = kig + (size_t)NIMG * 20 * NDET;

    roi_kernel<false><<<NROI, 256, 0, stream>>>(features, proposals, X, nullptr, nullptr);
    gemm1_kernel<<<dim3(16, 16, ZSPLIT), 256, 0, stream>>>(X, w1, CP);
    bias_relu_kernel<<<(NROI * HID) / 256, 256, 0, stream>>>(CP, b1, H1);
    gemm2_kernel<<<dim3(16, 16), 256, 0, stream>>>(H1, w2, b2, H2);
    heads_kernel<<<NROI, 128, 0, stream>>>(H2, wc, bc, wb, bb, proposals,
                                           BX2, NB2, LV2);
    nms_class_kernel<<<NIMG * 20, 64, 0, stream>>>(NB2, LV2, ksg, kig, cntg);
    nms_merge_kernel<<<NIMG, 1024, 0, stream>>>(ksg, kig, cntg, BX2,
                                                (float*)d_out);
  }
}